// Round 10
// baseline (867.490 us; speedup 1.0000x reference)
//
#include <hip/hip_runtime.h>
#include <cstdint>
#include <cstddef>

#define DIM     1024
#define SEQ     2048
#define BATCH   2
#define DEPTH   2
#define D_INNER 2048
#define D_STATE 16
#define D_CONV  4
#define DT_RANK 64
#define FF      4096
#define ROWS    (BATCH*SEQ)   // 4096
#define EPS     1e-5f

#define CS      16            // scan chunk size
#define NC      (SEQ/CS)      // 128 chunks
#define NC_LOG  7

#define XP_KS    8            // x_proj k-split
#define XP_KSTEP (D_INNER/XP_KS)  // 256

#define LOG2E 1.44269504088896f

typedef unsigned short ushort_t;
typedef short bf16x8 __attribute__((ext_vector_type(8)));
typedef float f32x4  __attribute__((ext_vector_type(4)));

__device__ __forceinline__ float sigmoidf_(float x) { return 1.f / (1.f + __expf(-x)); }

// bf16 <-> fp32
__device__ __forceinline__ ushort_t f2bf(float x) {
  unsigned int u = __float_as_uint(x);
  u += 0x7fffu + ((u >> 16) & 1u);
  return (ushort_t)(u >> 16);
}
__device__ __forceinline__ float bf2f(ushort_t u) {
  return __uint_as_float((unsigned)u << 16);
}

// async global->LDS 16B (wave-uniform LDS base + lane*16)
__device__ __forceinline__ void async_cp16(const void* g, void* lds) {
  __builtin_amdgcn_global_load_lds(
      (const __attribute__((address_space(1))) unsigned int*)g,
      (__attribute__((address_space(3))) unsigned int*)lds, 16, 0, 0);
}

// ---------------- block-wide reduction ----------------
__device__ __forceinline__ float2 block_sum2(float a, float b) {
#pragma unroll
  for (int off = 32; off > 0; off >>= 1) {
    a += __shfl_down(a, off, 64);
    b += __shfl_down(b, off, 64);
  }
  __shared__ float sa[4], sb[4];
  __syncthreads();
  if ((threadIdx.x & 63) == 0) { int w = threadIdx.x >> 6; sa[w] = a; sb[w] = b; }
  __syncthreads();
  return make_float2(sa[0] + sa[1] + sa[2] + sa[3], sb[0] + sb[1] + sb[2] + sb[3]);
}

// ---------------- residual add + RMSNorm (bf16 normed out) ----------------
__global__ __launch_bounds__(256) void res_rms_kernel(
    const float* __restrict__ xin, const float* __restrict__ hadd,
    float* __restrict__ res, ushort_t* __restrict__ nrm, const float* __restrict__ w) {
  int row = blockIdx.x;
  const float* xr = xin + (size_t)row * DIM;
  const float* hr = hadd ? hadd + (size_t)row * DIM : nullptr;
  float* rr = res + (size_t)row * DIM;
  ushort_t* nr = nrm + (size_t)row * DIM;
  float v[4]; float ss = 0.f;
#pragma unroll
  for (int i = 0; i < 4; ++i) {
    int j = threadIdx.x + i * 256;
    float t = xr[j];
    if (hr) t += hr[j];
    v[i] = t; rr[j] = t; ss += t * t;
  }
  float2 s = block_sum2(ss, 0.f);
  float rstd = rsqrtf(s.x * (1.f / DIM) + EPS);
#pragma unroll
  for (int i = 0; i < 4; ++i) {
    int j = threadIdx.x + i * 256;
    nr[j] = f2bf(v[i] * rstd * w[j]);
  }
}

// ---------------- LayerNorm (fp32 + bf16 out) ----------------
__global__ __launch_bounds__(256) void layernorm_kernel(
    const float* __restrict__ in, float* __restrict__ out, ushort_t* __restrict__ outb,
    const float* __restrict__ w, const float* __restrict__ b) {
  int row = blockIdx.x;
  const float* xr = in + (size_t)row * DIM;
  float* orow = out + (size_t)row * DIM;
  ushort_t* obrow = outb + (size_t)row * DIM;
  float v[4]; float s1 = 0.f, s2 = 0.f;
#pragma unroll
  for (int i = 0; i < 4; ++i) {
    int j = threadIdx.x + i * 256;
    float t = xr[j];
    v[i] = t; s1 += t; s2 += t * t;
  }
  float2 s = block_sum2(s1, s2);
  float mean = s.x * (1.f / DIM);
  float var = s.y * (1.f / DIM) - mean * mean;
  float rstd = rsqrtf(var + EPS);
#pragma unroll
  for (int i = 0; i < 4; ++i) {
    int j = threadIdx.x + i * 256;
    float o = (v[i] - mean) * rstd * w[j] + b[j];
    orow[j] = o;
    obrow[j] = f2bf(o);
  }
}

// ---------------- fp32 -> bf16 converter (weights) ----------------
__global__ __launch_bounds__(256) void f2b_kernel(
    const float* __restrict__ s, ushort_t* __restrict__ d, int n) {
  int i = (blockIdx.x * 256 + threadIdx.x) * 4;
  if (i >= n) return;
  float4 v = *reinterpret_cast<const float4*>(s + i);
  d[i + 0] = f2bf(v.x); d[i + 1] = f2bf(v.y);
  d[i + 2] = f2bf(v.z); d[i + 3] = f2bf(v.w);
}

// ---------------- bf16 MFMA NT GEMM: C = A[M,K] * B[N,K]^T (+bias) ----------------
// Tile 128 x (BNT*32), BK=64, 4 waves (2x2), 16x16x32 MFMA, single-buffer LDS.
// BNT=4 -> 128x128 tile; BNT=2 -> 128x64 (for N=1024 GEMMs: 2x the blocks).
// Block mapping: XCD-chunk swizzle (T1) then CUTLASS-style grouped supertile.
template <int BNT>
__global__ __launch_bounds__(256) void gemm_bf16_nt(
    const ushort_t* __restrict__ A,
    const ushort_t* __restrict__ B,
    float* __restrict__ C,
    ushort_t* __restrict__ Cb,
    int N, int K,
    const float* __restrict__ bias, int grp) {
  __shared__ ushort_t As[128 * 64];
  __shared__ ushort_t Bs[BNT * 32 * 64];
  const int tid = threadIdx.x;
  const int l = tid & 63;
  const int w = tid >> 6;

  const unsigned nwgx = gridDim.x;
  const unsigned nwg = nwgx * gridDim.y;
  const unsigned bid = blockIdx.y * nwgx + blockIdx.x;
  const unsigned cpx = nwg >> 3;
  const unsigned s = (bid & 7u) * cpx + (bid >> 3);
  const unsigned bandw = (unsigned)grp * nwgx;
  const unsigned band = s / bandw;
  const unsigned rem = s % bandw;
  const int m0 = (int)(band * grp + (rem % grp)) * 128;
  const int n0 = (int)(rem / grp) * (BNT * 32);

  const int wm = (w >> 1) * 64;
  const int wn = (w & 1) * (BNT * 16);

  const int srow = l >> 3;                      // 0..7 (row within 8-row chunk)
  const int ksrc = 8 * ((l & 7) ^ srow);        // swizzled source k-offset (elements)
  const int kg = l >> 4;                        // 0..3
  const int lr = l & 15;

  f32x4 acc[4][BNT];
#pragma unroll
  for (int mi = 0; mi < 4; ++mi)
#pragma unroll
    for (int ni = 0; ni < BNT; ++ni) acc[mi][ni] = (f32x4)0.f;

  for (int k0 = 0; k0 < K; k0 += 64) {
#pragma unroll
    for (int j = 0; j < 4; ++j) {
      int c = j * 4 + w;                        // A chunks 0..15 (8 rows each)
      int r = c * 8 + srow;
      async_cp16(&A[(size_t)(m0 + r) * K + k0 + ksrc], &As[c * 512]);
    }
#pragma unroll
    for (int j = 0; j < BNT; ++j) {
      int c = j * 4 + w;                        // B chunks 0..BNT*4-1
      int r = c * 8 + srow;
      async_cp16(&B[(size_t)(n0 + r) * K + k0 + ksrc], &Bs[c * 512]);
    }
    __syncthreads();   // compiler drains vmcnt before barrier
#pragma unroll
    for (int ks = 0; ks < 2; ++ks) {
      bf16x8 af[4], bfr[BNT];
#pragma unroll
      for (int mi = 0; mi < 4; ++mi) {
        int r = wm + mi * 16 + lr;
        int boff = r * 128 + ((ks * 64 + kg * 16) ^ ((r & 7) << 4));
        af[mi] = *reinterpret_cast<const bf16x8*>(reinterpret_cast<const char*>(As) + boff);
      }
#pragma unroll
      for (int ni = 0; ni < BNT; ++ni) {
        int r = wn + ni * 16 + lr;
        int boff = r * 128 + ((ks * 64 + kg * 16) ^ ((r & 7) << 4));
        bfr[ni] = *reinterpret_cast<const bf16x8*>(reinterpret_cast<const char*>(Bs) + boff);
      }
#pragma unroll
      for (int mi = 0; mi < 4; ++mi)
#pragma unroll
        for (int ni = 0; ni < BNT; ++ni)
          acc[mi][ni] = __builtin_amdgcn_mfma_f32_16x16x32_bf16(af[mi], bfr[ni], acc[mi][ni], 0, 0, 0);
    }
    __syncthreads();
  }

  const int crow0 = (l >> 4) * 4;
  const int ccol = l & 15;
#pragma unroll
  for (int mi = 0; mi < 4; ++mi) {
#pragma unroll
    for (int ni = 0; ni < BNT; ++ni) {
      int col = n0 + wn + ni * 16 + ccol;
      float bv = bias ? bias[col] : 0.f;
#pragma unroll
      for (int j = 0; j < 4; ++j) {
        int row = m0 + wm + mi * 16 + crow0 + j;
        float v = acc[mi][ni][j] + bv;
        if (Cb) Cb[(size_t)row * N + col] = f2bf(v);
        else    C[(size_t)row * N + col] = v;
      }
    }
  }
}

// ---------------- fp32 NT GEMM (dt_proj) ----------------
__global__ __launch_bounds__(256) void gemm_nt(
    const float* __restrict__ A, int lda,
    const float* __restrict__ B, int ldb,
    float* __restrict__ C, int ldc,
    int N, int K,
    const float* __restrict__ bias, int act) {
  __shared__ __align__(16) float Asf[16][68];
  __shared__ __align__(16) float Bsf[16][68];
  const int tx = threadIdx.x;
  const int ty = threadIdx.y;
  const int tid = ty * 16 + tx;
  const int m0 = blockIdx.y * 64;
  const int n0 = blockIdx.x * 64;
  const int lrow = tid >> 2;
  const int lk = (tid & 3) * 4;

  float acc[4][4] = {{0.f}};

  for (int k0 = 0; k0 < K; k0 += 16) {
    float4 av, bv;
    {
      const float* ap = A + (size_t)(m0 + lrow) * lda + k0 + lk;
      av = *reinterpret_cast<const float4*>(ap);
    }
    int brow = n0 + lrow;
    if (brow < N) {
      const float* bp = B + (size_t)brow * ldb + k0 + lk;
      bv = *reinterpret_cast<const float4*>(bp);
    } else {
      bv = make_float4(0.f, 0.f, 0.f, 0.f);
    }
    __syncthreads();
    Asf[lk + 0][lrow] = av.x; Asf[lk + 1][lrow] = av.y;
    Asf[lk + 2][lrow] = av.z; Asf[lk + 3][lrow] = av.w;
    Bsf[lk + 0][lrow] = bv.x; Bsf[lk + 1][lrow] = bv.y;
    Bsf[lk + 2][lrow] = bv.z; Bsf[lk + 3][lrow] = bv.w;
    __syncthreads();
#pragma unroll
    for (int k = 0; k < 16; ++k) {
      const float4 a4 = *reinterpret_cast<const float4*>(&Asf[k][ty * 4]);
      const float4 b4 = *reinterpret_cast<const float4*>(&Bsf[k][tx * 4]);
      float a[4] = {a4.x, a4.y, a4.z, a4.w};
      float bb[4] = {b4.x, b4.y, b4.z, b4.w};
#pragma unroll
      for (int i = 0; i < 4; ++i)
#pragma unroll
        for (int j = 0; j < 4; ++j)
          acc[i][j] = fmaf(a[i], bb[j], acc[i][j]);
    }
  }

#pragma unroll
  for (int i = 0; i < 4; ++i) {
    int m = m0 + ty * 4 + i;
#pragma unroll
    for (int j = 0; j < 4; ++j) {
      int n = n0 + tx * 4 + j;
      if (n < N) {
        float v = acc[i][j];
        if (bias) v += bias[n];
        if (act == 1) v = (v > 20.f) ? v : log1pf(__expf(v));
        C[(size_t)m * ldc + n] = v;
      }
    }
  }
}

// ---------------- x_proj split-K stage 1 ----------------
__global__ __launch_bounds__(256) void xproj_partial(
    const float* __restrict__ A,   // xc [4096, 2048]
    const float* __restrict__ W,   // [96, 2048]
    float* __restrict__ pbuf) {    // [XP_KS, 4096, 96]
  __shared__ __align__(16) float As[64][68];
  __shared__ __align__(16) float Wsd[96][68];
  const int ks = blockIdx.x;
  const int mb = blockIdx.y;
  const int tid = threadIdx.x;
  const int r0 = (tid >> 4) * 4;        // 0..60
  const int c0 = (tid & 15) * 6;        // 0..90

  float acc[4][6];
#pragma unroll
  for (int i = 0; i < 4; ++i)
#pragma unroll
    for (int j = 0; j < 6; ++j) acc[i][j] = 0.f;

  for (int k0 = 0; k0 < XP_KSTEP; k0 += 64) {
    const int kbase = ks * XP_KSTEP + k0;
    __syncthreads();
    {
      int r = tid >> 2, c = (tid & 3) * 16;
      const float* src = A + (size_t)(mb * 64 + r) * D_INNER + kbase + c;
#pragma unroll
      for (int q = 0; q < 4; ++q)
        *reinterpret_cast<float4*>(&As[r][c + q * 4]) =
            *reinterpret_cast<const float4*>(src + q * 4);
    }
#pragma unroll
    for (int q = 0; q < 6; ++q) {
      int f = q * 256 + tid;
      int wr = f >> 4;
      int wc = (f & 15) * 4;
      *reinterpret_cast<float4*>(&Wsd[wr][wc]) =
          *reinterpret_cast<const float4*>(&W[(size_t)wr * D_INNER + kbase + wc]);
    }
    __syncthreads();
#pragma unroll 16
    for (int k = 0; k < 64; ++k) {
      float a[4], wv[6];
#pragma unroll
      for (int i = 0; i < 4; ++i) a[i] = As[r0 + i][k];
#pragma unroll
      for (int j = 0; j < 6; ++j) wv[j] = Wsd[c0 + j][k];
#pragma unroll
      for (int i = 0; i < 4; ++i)
#pragma unroll
        for (int j = 0; j < 6; ++j)
          acc[i][j] = fmaf(a[i], wv[j], acc[i][j]);
    }
  }

  float* dst = pbuf + ((size_t)ks * ROWS + mb * 64) * 96;
#pragma unroll
  for (int i = 0; i < 4; ++i)
#pragma unroll
    for (int j = 0; j < 6; ++j)
      dst[(size_t)(r0 + i) * 96 + c0 + j] = acc[i][j];
}

// ---------------- x_proj split-K stage 2: reduce ----------------
__global__ __launch_bounds__(256) void xproj_reduce(
    const float* __restrict__ pbuf, float* __restrict__ xdbl) {
  int i = blockIdx.x * 256 + threadIdx.x;   // 0 .. ROWS*96-1
  float s = 0.f;
#pragma unroll
  for (int ks = 0; ks < XP_KS; ++ks)
    s += pbuf[(size_t)ks * (ROWS * 96) + i];
  xdbl[i] = s;
}

// ---------------- causal depthwise conv (k=4) + SiLU, bf16 in / fp32 out ----------------
__global__ __launch_bounds__(256) void conv_silu_kernel(
    const ushort_t* __restrict__ xzb, float* __restrict__ xc,
    const float* __restrict__ cw, const float* __restrict__ cb) {
  int t = (blockIdx.x * 256 + threadIdx.x) * 4;
  if (t >= ROWS * D_INNER) return;
  int d = t & (D_INNER - 1);
  int row = t >> 11;
  int l = row & (SEQ - 1);
  float acc[4];
#pragma unroll
  for (int q = 0; q < 4; ++q) acc[q] = cb[d + q];
#pragma unroll
  for (int j = 0; j < 4; ++j) {
    int ls = l - 3 + j;
    if (ls >= 0) {
      ushort4 uv = *reinterpret_cast<const ushort4*>(
          xzb + (size_t)(row - 3 + j) * (2 * D_INNER) + d);
      acc[0] = fmaf(cw[(d + 0) * 4 + j], bf2f(uv.x), acc[0]);
      acc[1] = fmaf(cw[(d + 1) * 4 + j], bf2f(uv.y), acc[1]);
      acc[2] = fmaf(cw[(d + 2) * 4 + j], bf2f(uv.z), acc[2]);
      acc[3] = fmaf(cw[(d + 3) * 4 + j], bf2f(uv.w), acc[3]);
    }
  }
  float4 o;
  o.x = acc[0] * sigmoidf_(acc[0]);
  o.y = acc[1] * sigmoidf_(acc[1]);
  o.z = acc[2] * sigmoidf_(acc[2]);
  o.w = acc[3] * sigmoidf_(acc[3]);
  *reinterpret_cast<float4*>(xc + t) = o;
}

// ================= chunked selective scan (CS=16, prefetched) =================
// pass1: local scan (h0=0) -> hend into harr, dtsum
__global__ __launch_bounds__(256) void scan_pass1(
    const float* __restrict__ delta,
    const float* __restrict__ xc,
    const float* __restrict__ xdbl,
    const float* __restrict__ A_log,
    float* __restrict__ harr,
    float* __restrict__ dtsum) {
  int gid = blockIdx.x * 256 + threadIdx.x;
  int d = gid & (D_INNER - 1);
  int bc = gid >> 11;
  int c = bc & (NC - 1);
  int b = bc >> NC_LOG;

  float Av2[D_STATE];
#pragma unroll
  for (int n = 0; n < D_STATE; ++n)
    Av2[n] = -__expf(A_log[(size_t)d * D_STATE + n]) * LOG2E;
  float h[D_STATE];
#pragma unroll
  for (int n = 0; n < D_STATE; ++n) h[n] = 0.f;
  float dts = 0.f;

  const size_t r0 = (size_t)b * SEQ + (size_t)c * CS;
  const float* drow = delta + r0 * D_INNER + d;
  const float* urow = xc + r0 * D_INNER + d;
  const float* brow = xdbl + r0 * 96 + 64;

  float dt = *drow;
  float u = *urow;
  f32x4 Bv0 = *reinterpret_cast<const f32x4*>(brow);
  f32x4 Bv1 = *reinterpret_cast<const f32x4*>(brow + 4);
  f32x4 Bv2 = *reinterpret_cast<const f32x4*>(brow + 8);
  f32x4 Bv3 = *reinterpret_cast<const f32x4*>(brow + 12);

  for (int l = 0; l < CS; ++l) {
    float dtc = dt, uc = u;
    f32x4 B0 = Bv0, B1 = Bv1, B2 = Bv2, B3 = Bv3;
    if (l + 1 < CS) {
      dt = drow[(size_t)(l + 1) * D_INNER];
      u  = urow[(size_t)(l + 1) * D_INNER];
      const float* bn = brow + (size_t)(l + 1) * 96;
      Bv0 = *reinterpret_cast<const f32x4*>(bn);
      Bv1 = *reinterpret_cast<const f32x4*>(bn + 4);
      Bv2 = *reinterpret_cast<const f32x4*>(bn + 8);
      Bv3 = *reinterpret_cast<const f32x4*>(bn + 12);
    }
    float du = dtc * uc;
    dts += dtc;
    float Bs[D_STATE] = {B0[0],B0[1],B0[2],B0[3], B1[0],B1[1],B1[2],B1[3],
                         B2[0],B2[1],B2[2],B2[3], B3[0],B3[1],B3[2],B3[3]};
#pragma unroll
    for (int n = 0; n < D_STATE; ++n) {
      float dA = __builtin_amdgcn_exp2f(dtc * Av2[n]);
      h[n] = dA * h[n] + du * Bs[n];
    }
  }
#pragma unroll
  for (int n = 0; n < D_STATE; ++n)
    harr[((size_t)bc * D_STATE + n) * D_INNER + d] = h[n];
  dtsum[(size_t)bc * D_INNER + d] = dts;
}

// pass2: sequential combine over NC chunks; IN-PLACE: harr[c] := h0 for chunk c
__global__ __launch_bounds__(256) void scan_pass2(
    float* __restrict__ harr,
    const float* __restrict__ dtsum,
    const float* __restrict__ A_log) {
  int gid = blockIdx.x * 256 + threadIdx.x;
  int d = gid & (D_INNER - 1);
  int bn = gid >> 11;
  int n = bn & (D_STATE - 1);
  int b = bn >> 4;
  float Av2 = -__expf(A_log[(size_t)d * D_STATE + n]) * LOG2E;
  float h = 0.f;
  for (int c = 0; c < NC; ++c) {
    size_t bc = (size_t)b * NC + c;
    size_t idx = (bc * D_STATE + n) * D_INNER + d;
    float he = harr[idx];
    harr[idx] = h;
    float P = __builtin_amdgcn_exp2f(Av2 * dtsum[bc * D_INNER + d]);
    h = P * h + he;
  }
}

// pass3: rescan with true h0, y = h·C + u*D, gate silu(z) -> bf16
__global__ __launch_bounds__(256) void scan_pass3(
    const float* __restrict__ delta,
    const float* __restrict__ xc,
    ushort_t* __restrict__ ybf,
    const float* __restrict__ xdbl,
    const ushort_t* __restrict__ xzb,
    const float* __restrict__ A_log,
    const float* __restrict__ Dp,
    const float* __restrict__ harr) {
  int gid = blockIdx.x * 256 + threadIdx.x;
  int d = gid & (D_INNER - 1);
  int bc = gid >> 11;
  int c = bc & (NC - 1);
  int b = bc >> NC_LOG;

  float Av2[D_STATE];
#pragma unroll
  for (int n = 0; n < D_STATE; ++n)
    Av2[n] = -__expf(A_log[(size_t)d * D_STATE + n]) * LOG2E;
  const float Dd = Dp[d];
  float h[D_STATE];
#pragma unroll
  for (int n = 0; n < D_STATE; ++n)
    h[n] = harr[((size_t)bc * D_STATE + n) * D_INNER + d];

  const size_t r0 = (size_t)b * SEQ + (size_t)c * CS;
  const float* drow = delta + r0 * D_INNER + d;
  const float* urow = xc + r0 * D_INNER + d;
  const float* brow = xdbl + r0 * 96 + 64;   // B at +0, C at +16 floats
  const ushort_t* zrow = xzb + r0 * (2 * D_INNER) + D_INNER + d;
  ushort_t* yrow = ybf + r0 * D_INNER + d;

  float dt = *drow;
  float u = *urow;
  float z = bf2f(*zrow);
  f32x4 Bv0 = *reinterpret_cast<const f32x4*>(brow);
  f32x4 Bv1 = *reinterpret_cast<const f32x4*>(brow + 4);
  f32x4 Bv2 = *reinterpret_cast<const f32x4*>(brow + 8);
  f32x4 Bv3 = *reinterpret_cast<const f32x4*>(brow + 12);
  f32x4 Cv0 = *reinterpret_cast<const f32x4*>(brow + 16);
  f32x4 Cv1 = *reinterpret_cast<const f32x4*>(brow + 20);
  f32x4 Cv2 = *reinterpret_cast<const f32x4*>(brow + 24);
  f32x4 Cv3 = *reinterpret_cast<const f32x4*>(brow + 28);

  for (int l = 0; l < CS; ++l) {
    float dtc = dt, uc = u, zc = z;
    f32x4 B0 = Bv0, B1 = Bv1, B2 = Bv2, B3 = Bv3;
    f32x4 C0 = Cv0, C1 = Cv1, C2 = Cv2, C3 = Cv3;
    if (l + 1 < CS) {
      dt = drow[(size_t)(l + 1) * D_INNER];
      u  = urow[(size_t)(l + 1) * D_INNER];
      z  = bf2f(zrow[(size_t)(l + 1) * (2 * D_INNER)]);
      const float* bn = brow + (size_t)(l + 1) * 96;
      Bv0 = *reinterpret_cast<const f32x4*>(bn);
      Bv1 = *reinterpret_cast<const f32x4*>(bn + 4);
      Bv2 = *reinterpret_cast<const f32x4*>(bn + 8);
      Bv3 = *reinterpret_cast<const f32x4*>(bn + 12);
      Cv0 = *reinterpret_cast<const f32x4*>(bn + 16);
      Cv1 = *reinterpret_cast<const f32x4*>(bn + 20);
      Cv2 = *reinterpret_cast<const f32x4*>(bn + 24);
      Cv3 = *reinterpret_cast<const f32x4*>(bn + 28);
    }
    float du = dtc * uc;
    float Bs[D_STATE] = {B0[0],B0[1],B0[2],B0[3], B1[0],B1[1],B1[2],B1[3],
                         B2[0],B2[1],B2[2],B2[3], B3[0],B3[1],B3[2],B3[3]};
    float Cs[D_STATE] = {C0[0],C0[1],C0[2],C0[3], C1[0],C1[1],C1[2],C1[3],
                         C2[0],C2[1],C2[2],C2[3], C3[0],C3[1],C3[2],C3[3]};
    float y = 0.f;
#pragma unroll
    for (int n = 0; n < D_STATE; ++n) {
      float dA = __builtin_amdgcn_exp2f(dtc * Av2[n]);
      h[n] = dA * h[n] + du * Bs[n];
      y = fmaf(h[n], Cs[n], y);
    }
    y = fmaf(uc, Dd, y);
    yrow[(size_t)l * D_INNER] = f2bf(y * (zc * sigmoidf_(zc)));
  }
}

// ---------------- GEGLU: bf16 in, bf16 out ----------------
__global__ __launch_bounds__(256) void glu_kernel(
    const ushort_t* __restrict__ u, ushort_t* __restrict__ o) {
  int i = blockIdx.x * 256 + threadIdx.x;   // 8 f's per thread
  int m = i >> 9;                           // / (FF/8)
  int f0 = (i & 511) * 8;
  bf16x8 av = *reinterpret_cast<const bf16x8*>(u + (size_t)m * (2 * FF) + f0);
  bf16x8 gv = *reinterpret_cast<const bf16x8*>(u + (size_t)m * (2 * FF) + FF + f0);
  bf16x8 ov;
#pragma unroll
  for (int e = 0; e < 8; ++e) {
    float a = bf2f((ushort_t)av[e]);
    float g = bf2f((ushort_t)gv[e]);
    float ge = 0.5f * g * (1.f + erff(g * 0.70710678118654752f));
    ov[e] = (short)f2bf(a * ge);
  }
  *reinterpret_cast<bf16x8*>(o + (size_t)m * FF + f0) = ov;
}

extern "C" void kernel_launch(void* const* d_in, const int* in_sizes, int n_in,
                              void* d_out, int out_size, void* d_ws, size_t ws_size,
                              hipStream_t stream) {
  const float* x         = (const float*)d_in[0];
  const float* in_proj_w = (const float*)d_in[1];
  const float* conv_w    = (const float*)d_in[2];
  const float* conv_b    = (const float*)d_in[3];
  const float* x_proj_w  = (const float*)d_in[4];
  const float* dt_proj_w = (const float*)d_in[5];
  const float* dt_proj_b = (const float*)d_in[6];
  const float* A_log     = (const float*)d_in[7];
  const float* Dp        = (const float*)d_in[8];
  const float* out_proj_w= (const float*)d_in[9];
  const float* rms_w     = (const float*)d_in[10];
  const float* ln_w      = (const float*)d_in[11];
  const float* ln_b      = (const float*)d_in[12];
  const float* ff_w1     = (const float*)d_in[13];
  const float* ff_b1     = (const float*)d_in[14];
  const float* ff_w2     = (const float*)d_in[15];
  const float* ff_b2     = (const float*)d_in[16];
  float* out = (float*)d_out;

  float* ws = (float*)d_ws;
  // ---- layout (float-word offsets); total end = 65,536,000 w = 250.0 MiB ----
  float* res     = ws;                              // [0, 4194304)
  float* hbuf    = ws + 4194304;                    // [4194304, 8388608)
  float* xdbl    = ws + 8388608;                    // [8388608, 8781824)
  // dtsum overlays hbuf (dead between res_rms consume and layernorm write):
  float* dtsum   = ws + 4194304;                    // B*NC*D_INNER = 524,288 w
  ushort_t* hbuf_bf = (ushort_t*)(ws + 8912896);    // 4M ushorts [8912896, 11010048)
  float*    pbuf    = ws + 11010048;                // x_proj partials 3.1M w
  ushort_t* y_bf    = (ushort_t*)(ws + 15204352);   // 8M ushorts [15204352, 19398656)
  ushort_t* glu_bf  = (ushort_t*)(ws + 11010048);   // overlays pbuf (FFN phase)
  float* big   = ws + 19398656;                     // [19398656, 52953088)
  ushort_t* xz_bf = (ushort_t*)big;                 // 16.7M ushorts = 8,388,608 w (layer phase)
  float* xc    = big + 8388608;                     // 8,388,608 w
  float* delta = big + 16777216;                    // 8,388,608 w
  float* harr  = big + 25165824;                    // B*NC*16*D_INNER = 8,388,608 w ✓
  ushort_t* ffu_bf = (ushort_t*)big;                // 33.5M ushorts (FFN phase)
  float* op_out= big;                               // 4M w (overlays xz_bf after scan)
  ushort_t* nrm_bf = (ushort_t*)delta;              // 4M ushorts (dead before dt_proj writes)
  ushort_t* in_w_bf  = (ushort_t*)(ws + 52953088);  // 8M ushorts [52953088, 57147392)
  ushort_t* out_w_bf = (ushort_t*)(ws + 57147392);  // 4M ushorts [57147392, 59244544)
  ushort_t* ff1_bf   = (ushort_t*)(ws + 59244544);  // 8M ushorts [59244544, 63438848)
  ushort_t* ff2_bf   = (ushort_t*)(ws + 63438848);  // 4M ushorts [63438848, 65536000)

  dim3 tb(16, 16);

  // weight conversions (every call; deterministic)
  f2b_kernel<<<8192, 256, 0, stream>>>(in_proj_w, in_w_bf, 8388608);
  f2b_kernel<<<4096, 256, 0, stream>>>(out_proj_w, out_w_bf, 4194304);
  f2b_kernel<<<8192, 256, 0, stream>>>(ff_w1, ff1_bf, 8388608);
  f2b_kernel<<<4096, 256, 0, stream>>>(ff_w2, ff2_bf, 4194304);

  for (int i = 0; i < DEPTH; ++i) {
    const float* cw    = conv_w + (size_t)i * D_INNER * D_CONV;
    const float* cb    = conv_b + (size_t)i * D_INNER;
    const float* xp_w  = x_proj_w + (size_t)i * 96 * D_INNER;
    const float* dtp_w = dt_proj_w + (size_t)i * D_INNER * DT_RANK;
    const float* dtp_b = dt_proj_b + (size_t)i * D_INNER;
    const float* Alg   = A_log + (size_t)i * D_INNER * D_STATE;
    const float* Di    = Dp + (size_t)i * D_INNER;

    res_rms_kernel<<<ROWS, 256, 0, stream>>>(i == 0 ? x : res, i == 0 ? nullptr : hbuf,
                                             res, nrm_bf, rms_w + (size_t)i * DIM);
    // in_proj: xz_bf[4096,4096] = nrm * in_w^T  (bf16 MFMA, bf16 out)
    gemm_bf16_nt<4><<<dim3(32, 32), 256, 0, stream>>>(
        nrm_bf, in_w_bf + (size_t)i * 4194304, nullptr, xz_bf, 2 * D_INNER, DIM,
        nullptr, 16);
    conv_silu_kernel<<<(ROWS * D_INNER / 4) / 256, 256, 0, stream>>>(xz_bf, xc, cw, cb);
    // x_proj: split-K two-stage
    xproj_partial<<<dim3(XP_KS, 64), 256, 0, stream>>>(xc, xp_w, pbuf);
    xproj_reduce<<<(ROWS * 96) / 256, 256, 0, stream>>>(pbuf, xdbl);
    gemm_nt<<<dim3(32, 64), tb, 0, stream>>>(xdbl, 96, dtp_w, DT_RANK, delta, D_INNER,
                                             D_INNER, DT_RANK, dtp_b, 1);
    scan_pass1<<<(BATCH * NC * D_INNER) / 256, 256, 0, stream>>>(delta, xc, xdbl, Alg,
                                                                 harr, dtsum);
    scan_pass2<<<(BATCH * D_STATE * D_INNER) / 256, 256, 0, stream>>>(harr, dtsum, Alg);
    scan_pass3<<<(BATCH * NC * D_INNER) / 256, 256, 0, stream>>>(delta, xc, y_bf, xdbl,
                                                                 xz_bf, Alg, Di, harr);
    // out_proj: op_out[4096,1024] = y * o_w^T  (bf16 MFMA BN=64, fp32 out); xz dead now
    gemm_bf16_nt<2><<<dim3(16, 32), 256, 0, stream>>>(
        y_bf, out_w_bf + (size_t)i * 2097152, op_out, nullptr, DIM, D_INNER,
        nullptr, 8);
    layernorm_kernel<<<ROWS, 256, 0, stream>>>(op_out, hbuf, hbuf_bf,
                                               ln_w + (size_t)i * DIM, ln_b + (size_t)i * DIM);
  }

  // FFN1: ffu_bf[4096,8192] = hbuf * ff_w1^T + b1  (bf16 MFMA, bf16 out)
  gemm_bf16_nt<4><<<dim3(64, 32), 256, 0, stream>>>(hbuf_bf, ff1_bf, nullptr, ffu_bf,
                                                    2 * FF, DIM, ff_b1, 16);
  glu_kernel<<<(ROWS * FF / 8) / 256, 256, 0, stream>>>(ffu_bf, glu_bf);
  // FFN2: out = glu * ff_w2^T + b2  (bf16 MFMA BN=64, fp32 out)
  gemm_bf16_nt<2><<<dim3(16, 32), 256, 0, stream>>>(glu_bf, ff2_bf, out, nullptr, DIM, FF,
                                                    ff_b2, 8);
}

// Round 11
// 857.137 us; speedup vs baseline: 1.0121x; 1.0121x over previous
//
#include <hip/hip_runtime.h>
#include <cstdint>
#include <cstddef>

#define DIM     1024
#define SEQ     2048
#define BATCH   2
#define DEPTH   2
#define D_INNER 2048
#define D_STATE 16
#define D_CONV  4
#define DT_RANK 64
#define FF      4096
#define ROWS    (BATCH*SEQ)   // 4096
#define EPS     1e-5f

#define CS      32            // scan chunk size
#define NC      (SEQ/CS)      // 64 chunks
#define NC_LOG  6

#define XP_KS    8            // x_proj k-split
#define XP_KSTEP (D_INNER/XP_KS)  // 256

#define LOG2E 1.44269504088896f

typedef unsigned short ushort_t;
typedef short bf16x8 __attribute__((ext_vector_type(8)));
typedef float f32x4  __attribute__((ext_vector_type(4)));

__device__ __forceinline__ float sigmoidf_(float x) { return 1.f / (1.f + __expf(-x)); }

// bf16 <-> fp32
__device__ __forceinline__ ushort_t f2bf(float x) {
  unsigned int u = __float_as_uint(x);
  u += 0x7fffu + ((u >> 16) & 1u);
  return (ushort_t)(u >> 16);
}
__device__ __forceinline__ float bf2f(ushort_t u) {
  return __uint_as_float((unsigned)u << 16);
}

// async global->LDS 16B (wave-uniform LDS base + lane*16)
__device__ __forceinline__ void async_cp16(const void* g, void* lds) {
  __builtin_amdgcn_global_load_lds(
      (const __attribute__((address_space(1))) unsigned int*)g,
      (__attribute__((address_space(3))) unsigned int*)lds, 16, 0, 0);
}

// ---------------- block-wide reduction ----------------
__device__ __forceinline__ float2 block_sum2(float a, float b) {
#pragma unroll
  for (int off = 32; off > 0; off >>= 1) {
    a += __shfl_down(a, off, 64);
    b += __shfl_down(b, off, 64);
  }
  __shared__ float sa[4], sb[4];
  __syncthreads();
  if ((threadIdx.x & 63) == 0) { int w = threadIdx.x >> 6; sa[w] = a; sb[w] = b; }
  __syncthreads();
  return make_float2(sa[0] + sa[1] + sa[2] + sa[3], sb[0] + sb[1] + sb[2] + sb[3]);
}

// ---------------- residual add + RMSNorm (bf16 normed out) ----------------
__global__ __launch_bounds__(256) void res_rms_kernel(
    const float* __restrict__ xin, const float* __restrict__ hadd,
    float* __restrict__ res, ushort_t* __restrict__ nrm, const float* __restrict__ w) {
  int row = blockIdx.x;
  const float* xr = xin + (size_t)row * DIM;
  const float* hr = hadd ? hadd + (size_t)row * DIM : nullptr;
  float* rr = res + (size_t)row * DIM;
  ushort_t* nr = nrm + (size_t)row * DIM;
  float v[4]; float ss = 0.f;
#pragma unroll
  for (int i = 0; i < 4; ++i) {
    int j = threadIdx.x + i * 256;
    float t = xr[j];
    if (hr) t += hr[j];
    v[i] = t; rr[j] = t; ss += t * t;
  }
  float2 s = block_sum2(ss, 0.f);
  float rstd = rsqrtf(s.x * (1.f / DIM) + EPS);
#pragma unroll
  for (int i = 0; i < 4; ++i) {
    int j = threadIdx.x + i * 256;
    nr[j] = f2bf(v[i] * rstd * w[j]);
  }
}

// ---------------- LayerNorm (fp32 + bf16 out) ----------------
__global__ __launch_bounds__(256) void layernorm_kernel(
    const float* __restrict__ in, float* __restrict__ out, ushort_t* __restrict__ outb,
    const float* __restrict__ w, const float* __restrict__ b) {
  int row = blockIdx.x;
  const float* xr = in + (size_t)row * DIM;
  float* orow = out + (size_t)row * DIM;
  ushort_t* obrow = outb + (size_t)row * DIM;
  float v[4]; float s1 = 0.f, s2 = 0.f;
#pragma unroll
  for (int i = 0; i < 4; ++i) {
    int j = threadIdx.x + i * 256;
    float t = xr[j];
    v[i] = t; s1 += t; s2 += t * t;
  }
  float2 s = block_sum2(s1, s2);
  float mean = s.x * (1.f / DIM);
  float var = s.y * (1.f / DIM) - mean * mean;
  float rstd = rsqrtf(var + EPS);
#pragma unroll
  for (int i = 0; i < 4; ++i) {
    int j = threadIdx.x + i * 256;
    float o = (v[i] - mean) * rstd * w[j] + b[j];
    orow[j] = o;
    obrow[j] = f2bf(o);
  }
}

// ---------------- fp32 -> bf16 converter (weights) ----------------
__global__ __launch_bounds__(256) void f2b_kernel(
    const float* __restrict__ s, ushort_t* __restrict__ d, int n) {
  int i = (blockIdx.x * 256 + threadIdx.x) * 4;
  if (i >= n) return;
  float4 v = *reinterpret_cast<const float4*>(s + i);
  d[i + 0] = f2bf(v.x); d[i + 1] = f2bf(v.y);
  d[i + 2] = f2bf(v.z); d[i + 3] = f2bf(v.w);
}

// ---------------- bf16 MFMA NT GEMM: C = A[M,K] * B[N,K]^T (+bias) ----------------
// Tile 128 x (BNT*32), BK=64, 4 waves (2x2), 16x16x32 MFMA, single-buffer LDS.
// Block mapping: XCD-chunk swizzle (T1) then CUTLASS-style grouped supertile.
template <int BNT>
__global__ __launch_bounds__(256) void gemm_bf16_nt(
    const ushort_t* __restrict__ A,
    const ushort_t* __restrict__ B,
    float* __restrict__ C,
    ushort_t* __restrict__ Cb,
    int N, int K,
    const float* __restrict__ bias, int grp) {
  __shared__ ushort_t As[128 * 64];
  __shared__ ushort_t Bs[BNT * 32 * 64];
  const int tid = threadIdx.x;
  const int l = tid & 63;
  const int w = tid >> 6;

  const unsigned nwgx = gridDim.x;
  const unsigned nwg = nwgx * gridDim.y;
  const unsigned bid = blockIdx.y * nwgx + blockIdx.x;
  const unsigned cpx = nwg >> 3;
  const unsigned s = (bid & 7u) * cpx + (bid >> 3);
  const unsigned bandw = (unsigned)grp * nwgx;
  const unsigned band = s / bandw;
  const unsigned rem = s % bandw;
  const int m0 = (int)(band * grp + (rem % grp)) * 128;
  const int n0 = (int)(rem / grp) * (BNT * 32);

  const int wm = (w >> 1) * 64;
  const int wn = (w & 1) * (BNT * 16);

  const int srow = l >> 3;                      // 0..7 (row within 8-row chunk)
  const int ksrc = 8 * ((l & 7) ^ srow);        // swizzled source k-offset (elements)
  const int kg = l >> 4;                        // 0..3
  const int lr = l & 15;

  f32x4 acc[4][BNT];
#pragma unroll
  for (int mi = 0; mi < 4; ++mi)
#pragma unroll
    for (int ni = 0; ni < BNT; ++ni) acc[mi][ni] = (f32x4)0.f;

  for (int k0 = 0; k0 < K; k0 += 64) {
#pragma unroll
    for (int j = 0; j < 4; ++j) {
      int c = j * 4 + w;                        // A chunks 0..15 (8 rows each)
      int r = c * 8 + srow;
      async_cp16(&A[(size_t)(m0 + r) * K + k0 + ksrc], &As[c * 512]);
    }
#pragma unroll
    for (int j = 0; j < BNT; ++j) {
      int c = j * 4 + w;                        // B chunks 0..BNT*4-1
      int r = c * 8 + srow;
      async_cp16(&B[(size_t)(n0 + r) * K + k0 + ksrc], &Bs[c * 512]);
    }
    __syncthreads();   // compiler drains vmcnt before barrier
#pragma unroll
    for (int ks = 0; ks < 2; ++ks) {
      bf16x8 af[4], bfr[BNT];
#pragma unroll
      for (int mi = 0; mi < 4; ++mi) {
        int r = wm + mi * 16 + lr;
        int boff = r * 128 + ((ks * 64 + kg * 16) ^ ((r & 7) << 4));
        af[mi] = *reinterpret_cast<const bf16x8*>(reinterpret_cast<const char*>(As) + boff);
      }
#pragma unroll
      for (int ni = 0; ni < BNT; ++ni) {
        int r = wn + ni * 16 + lr;
        int boff = r * 128 + ((ks * 64 + kg * 16) ^ ((r & 7) << 4));
        bfr[ni] = *reinterpret_cast<const bf16x8*>(reinterpret_cast<const char*>(Bs) + boff);
      }
#pragma unroll
      for (int mi = 0; mi < 4; ++mi)
#pragma unroll
        for (int ni = 0; ni < BNT; ++ni)
          acc[mi][ni] = __builtin_amdgcn_mfma_f32_16x16x32_bf16(af[mi], bfr[ni], acc[mi][ni], 0, 0, 0);
    }
    __syncthreads();
  }

  const int crow0 = (l >> 4) * 4;
  const int ccol = l & 15;
#pragma unroll
  for (int mi = 0; mi < 4; ++mi) {
#pragma unroll
    for (int ni = 0; ni < BNT; ++ni) {
      int col = n0 + wn + ni * 16 + ccol;
      float bv = bias ? bias[col] : 0.f;
#pragma unroll
      for (int j = 0; j < 4; ++j) {
        int row = m0 + wm + mi * 16 + crow0 + j;
        float v = acc[mi][ni][j] + bv;
        if (Cb) Cb[(size_t)row * N + col] = f2bf(v);
        else    C[(size_t)row * N + col] = v;
      }
    }
  }
}

// ---------------- fp32 NT GEMM (dt_proj) ----------------
__global__ __launch_bounds__(256) void gemm_nt(
    const float* __restrict__ A, int lda,
    const float* __restrict__ B, int ldb,
    float* __restrict__ C, int ldc,
    int N, int K,
    const float* __restrict__ bias, int act) {
  __shared__ __align__(16) float Asf[16][68];
  __shared__ __align__(16) float Bsf[16][68];
  const int tx = threadIdx.x;
  const int ty = threadIdx.y;
  const int tid = ty * 16 + tx;
  const int m0 = blockIdx.y * 64;
  const int n0 = blockIdx.x * 64;
  const int lrow = tid >> 2;
  const int lk = (tid & 3) * 4;

  float acc[4][4] = {{0.f}};

  for (int k0 = 0; k0 < K; k0 += 16) {
    float4 av, bv;
    {
      const float* ap = A + (size_t)(m0 + lrow) * lda + k0 + lk;
      av = *reinterpret_cast<const float4*>(ap);
    }
    int brow = n0 + lrow;
    if (brow < N) {
      const float* bp = B + (size_t)brow * ldb + k0 + lk;
      bv = *reinterpret_cast<const float4*>(bp);
    } else {
      bv = make_float4(0.f, 0.f, 0.f, 0.f);
    }
    __syncthreads();
    Asf[lk + 0][lrow] = av.x; Asf[lk + 1][lrow] = av.y;
    Asf[lk + 2][lrow] = av.z; Asf[lk + 3][lrow] = av.w;
    Bsf[lk + 0][lrow] = bv.x; Bsf[lk + 1][lrow] = bv.y;
    Bsf[lk + 2][lrow] = bv.z; Bsf[lk + 3][lrow] = bv.w;
    __syncthreads();
#pragma unroll
    for (int k = 0; k < 16; ++k) {
      const float4 a4 = *reinterpret_cast<const float4*>(&Asf[k][ty * 4]);
      const float4 b4 = *reinterpret_cast<const float4*>(&Bsf[k][tx * 4]);
      float a[4] = {a4.x, a4.y, a4.z, a4.w};
      float bb[4] = {b4.x, b4.y, b4.z, b4.w};
#pragma unroll
      for (int i = 0; i < 4; ++i)
#pragma unroll
        for (int j = 0; j < 4; ++j)
          acc[i][j] = fmaf(a[i], bb[j], acc[i][j]);
    }
  }

#pragma unroll
  for (int i = 0; i < 4; ++i) {
    int m = m0 + ty * 4 + i;
#pragma unroll
    for (int j = 0; j < 4; ++j) {
      int n = n0 + tx * 4 + j;
      if (n < N) {
        float v = acc[i][j];
        if (bias) v += bias[n];
        if (act == 1) v = (v > 20.f) ? v : log1pf(__expf(v));
        C[(size_t)m * ldc + n] = v;
      }
    }
  }
}

// ---------------- x_proj split-K stage 1 ----------------
__global__ __launch_bounds__(256) void xproj_partial(
    const float* __restrict__ A,   // xc [4096, 2048]
    const float* __restrict__ W,   // [96, 2048]
    float* __restrict__ pbuf) {    // [XP_KS, 4096, 96]
  __shared__ __align__(16) float As[64][68];
  __shared__ __align__(16) float Wsd[96][68];
  const int ks = blockIdx.x;
  const int mb = blockIdx.y;
  const int tid = threadIdx.x;
  const int r0 = (tid >> 4) * 4;        // 0..60
  const int c0 = (tid & 15) * 6;        // 0..90

  float acc[4][6];
#pragma unroll
  for (int i = 0; i < 4; ++i)
#pragma unroll
    for (int j = 0; j < 6; ++j) acc[i][j] = 0.f;

  for (int k0 = 0; k0 < XP_KSTEP; k0 += 64) {
    const int kbase = ks * XP_KSTEP + k0;
    __syncthreads();
    {
      int r = tid >> 2, c = (tid & 3) * 16;
      const float* src = A + (size_t)(mb * 64 + r) * D_INNER + kbase + c;
#pragma unroll
      for (int q = 0; q < 4; ++q)
        *reinterpret_cast<float4*>(&As[r][c + q * 4]) =
            *reinterpret_cast<const float4*>(src + q * 4);
    }
#pragma unroll
    for (int q = 0; q < 6; ++q) {
      int f = q * 256 + tid;
      int wr = f >> 4;
      int wc = (f & 15) * 4;
      *reinterpret_cast<float4*>(&Wsd[wr][wc]) =
          *reinterpret_cast<const float4*>(&W[(size_t)wr * D_INNER + kbase + wc]);
    }
    __syncthreads();
#pragma unroll 16
    for (int k = 0; k < 64; ++k) {
      float a[4], wv[6];
#pragma unroll
      for (int i = 0; i < 4; ++i) a[i] = As[r0 + i][k];
#pragma unroll
      for (int j = 0; j < 6; ++j) wv[j] = Wsd[c0 + j][k];
#pragma unroll
      for (int i = 0; i < 4; ++i)
#pragma unroll
        for (int j = 0; j < 6; ++j)
          acc[i][j] = fmaf(a[i], wv[j], acc[i][j]);
    }
  }

  float* dst = pbuf + ((size_t)ks * ROWS + mb * 64) * 96;
#pragma unroll
  for (int i = 0; i < 4; ++i)
#pragma unroll
    for (int j = 0; j < 6; ++j)
      dst[(size_t)(r0 + i) * 96 + c0 + j] = acc[i][j];
}

// ---------------- x_proj split-K stage 2: reduce ----------------
__global__ __launch_bounds__(256) void xproj_reduce(
    const float* __restrict__ pbuf, float* __restrict__ xdbl) {
  int i = blockIdx.x * 256 + threadIdx.x;   // 0 .. ROWS*96-1
  float s = 0.f;
#pragma unroll
  for (int ks = 0; ks < XP_KS; ++ks)
    s += pbuf[(size_t)ks * (ROWS * 96) + i];
  xdbl[i] = s;
}

// ---------------- causal depthwise conv (k=4) + SiLU, bf16 in / fp32 out ----------------
__global__ __launch_bounds__(256) void conv_silu_kernel(
    const ushort_t* __restrict__ xzb, float* __restrict__ xc,
    const float* __restrict__ cw, const float* __restrict__ cb) {
  int t = (blockIdx.x * 256 + threadIdx.x) * 4;
  if (t >= ROWS * D_INNER) return;
  int d = t & (D_INNER - 1);
  int row = t >> 11;
  int l = row & (SEQ - 1);
  float acc[4];
#pragma unroll
  for (int q = 0; q < 4; ++q) acc[q] = cb[d + q];
#pragma unroll
  for (int j = 0; j < 4; ++j) {
    int ls = l - 3 + j;
    if (ls >= 0) {
      ushort4 uv = *reinterpret_cast<const ushort4*>(
          xzb + (size_t)(row - 3 + j) * (2 * D_INNER) + d);
      acc[0] = fmaf(cw[(d + 0) * 4 + j], bf2f(uv.x), acc[0]);
      acc[1] = fmaf(cw[(d + 1) * 4 + j], bf2f(uv.y), acc[1]);
      acc[2] = fmaf(cw[(d + 2) * 4 + j], bf2f(uv.z), acc[2]);
      acc[3] = fmaf(cw[(d + 3) * 4 + j], bf2f(uv.w), acc[3]);
    }
  }
  float4 o;
  o.x = acc[0] * sigmoidf_(acc[0]);
  o.y = acc[1] * sigmoidf_(acc[1]);
  o.z = acc[2] * sigmoidf_(acc[2]);
  o.w = acc[3] * sigmoidf_(acc[3]);
  *reinterpret_cast<float4*>(xc + t) = o;
}

// ================= chunked selective scan (CS=32, LDS-staged B/C) =================
// All 256 threads of a block share one (b,chunk); B/C rows staged once into LDS.
// pass1: local scan (h0=0) -> hend into harr, dtsum
__global__ __launch_bounds__(256) void scan_pass1(
    const float* __restrict__ delta,
    const float* __restrict__ xc,
    const float* __restrict__ xdbl,
    const float* __restrict__ A_log,
    float* __restrict__ harr,
    float* __restrict__ dtsum) {
  __shared__ __align__(16) float Bls[CS][16];
  int gid = blockIdx.x * 256 + threadIdx.x;
  int d = gid & (D_INNER - 1);
  int bc = gid >> 11;
  int c = bc & (NC - 1);
  int b = bc >> NC_LOG;
  const size_t r0 = (size_t)b * SEQ + (size_t)c * CS;

  // stage B rows [CS][16] (one coalesced burst; 128 threads)
  if (threadIdx.x < CS * 4) {
    int sl = threadIdx.x >> 2, sf = (threadIdx.x & 3) * 4;
    *reinterpret_cast<f32x4*>(&Bls[sl][sf]) =
        *reinterpret_cast<const f32x4*>(xdbl + (r0 + sl) * 96 + 64 + sf);
  }

  float Av2[D_STATE];
#pragma unroll
  for (int n = 0; n < D_STATE; ++n)
    Av2[n] = -__expf(A_log[(size_t)d * D_STATE + n]) * LOG2E;
  float h[D_STATE];
#pragma unroll
  for (int n = 0; n < D_STATE; ++n) h[n] = 0.f;
  float dts = 0.f;

  const float* drow = delta + r0 * D_INNER + d;
  const float* urow = xc + r0 * D_INNER + d;
  float dt = *drow;
  float u = *urow;
  __syncthreads();

  for (int l = 0; l < CS; ++l) {
    float dtc = dt, uc = u;
    if (l + 1 < CS) {
      dt = drow[(size_t)(l + 1) * D_INNER];
      u  = urow[(size_t)(l + 1) * D_INNER];
    }
    f32x4 B0 = *reinterpret_cast<const f32x4*>(&Bls[l][0]);
    f32x4 B1 = *reinterpret_cast<const f32x4*>(&Bls[l][4]);
    f32x4 B2 = *reinterpret_cast<const f32x4*>(&Bls[l][8]);
    f32x4 B3 = *reinterpret_cast<const f32x4*>(&Bls[l][12]);
    float du = dtc * uc;
    dts += dtc;
    float Bsr[D_STATE] = {B0[0],B0[1],B0[2],B0[3], B1[0],B1[1],B1[2],B1[3],
                          B2[0],B2[1],B2[2],B2[3], B3[0],B3[1],B3[2],B3[3]};
#pragma unroll
    for (int n = 0; n < D_STATE; ++n) {
      float dA = __builtin_amdgcn_exp2f(dtc * Av2[n]);
      h[n] = dA * h[n] + du * Bsr[n];
    }
  }
#pragma unroll
  for (int n = 0; n < D_STATE; ++n)
    harr[((size_t)bc * D_STATE + n) * D_INNER + d] = h[n];
  dtsum[(size_t)bc * D_INNER + d] = dts;
}

// pass2: sequential combine over NC chunks; IN-PLACE: harr[c] := h0 for chunk c
__global__ __launch_bounds__(256) void scan_pass2(
    float* __restrict__ harr,
    const float* __restrict__ dtsum,
    const float* __restrict__ A_log) {
  int gid = blockIdx.x * 256 + threadIdx.x;
  int d = gid & (D_INNER - 1);
  int bn = gid >> 11;
  int n = bn & (D_STATE - 1);
  int b = bn >> 4;
  float Av2 = -__expf(A_log[(size_t)d * D_STATE + n]) * LOG2E;
  float h = 0.f;
  for (int c = 0; c < NC; ++c) {
    size_t bc = (size_t)b * NC + c;
    size_t idx = (bc * D_STATE + n) * D_INNER + d;
    float he = harr[idx];
    harr[idx] = h;
    float P = __builtin_amdgcn_exp2f(Av2 * dtsum[bc * D_INNER + d]);
    h = P * h + he;
  }
}

// pass3: rescan with true h0, y = h·C + u*D, gate silu(z) -> bf16
__global__ __launch_bounds__(256) void scan_pass3(
    const float* __restrict__ delta,
    const float* __restrict__ xc,
    ushort_t* __restrict__ ybf,
    const float* __restrict__ xdbl,
    const ushort_t* __restrict__ xzb,
    const float* __restrict__ A_log,
    const float* __restrict__ Dp,
    const float* __restrict__ harr) {
  __shared__ __align__(16) float BCls[CS][32];   // B at [0..16), C at [16..32)
  int gid = blockIdx.x * 256 + threadIdx.x;
  int d = gid & (D_INNER - 1);
  int bc = gid >> 11;
  int c = bc & (NC - 1);
  int b = bc >> NC_LOG;
  const size_t r0 = (size_t)b * SEQ + (size_t)c * CS;

  // stage B+C rows [CS][32] (one coalesced burst; 256 threads)
  {
    int sl = threadIdx.x >> 3, sf = (threadIdx.x & 7) * 4;
    *reinterpret_cast<f32x4*>(&BCls[sl][sf]) =
        *reinterpret_cast<const f32x4*>(xdbl + (r0 + sl) * 96 + 64 + sf);
  }

  float Av2[D_STATE];
#pragma unroll
  for (int n = 0; n < D_STATE; ++n)
    Av2[n] = -__expf(A_log[(size_t)d * D_STATE + n]) * LOG2E;
  const float Dd = Dp[d];
  float h[D_STATE];
#pragma unroll
  for (int n = 0; n < D_STATE; ++n)
    h[n] = harr[((size_t)bc * D_STATE + n) * D_INNER + d];

  const float* drow = delta + r0 * D_INNER + d;
  const float* urow = xc + r0 * D_INNER + d;
  const ushort_t* zrow = xzb + r0 * (2 * D_INNER) + D_INNER + d;
  ushort_t* yrow = ybf + r0 * D_INNER + d;

  float dt = *drow;
  float u = *urow;
  float z = bf2f(*zrow);
  __syncthreads();

  for (int l = 0; l < CS; ++l) {
    float dtc = dt, uc = u, zc = z;
    if (l + 1 < CS) {
      dt = drow[(size_t)(l + 1) * D_INNER];
      u  = urow[(size_t)(l + 1) * D_INNER];
      z  = bf2f(zrow[(size_t)(l + 1) * (2 * D_INNER)]);
    }
    f32x4 B0 = *reinterpret_cast<const f32x4*>(&BCls[l][0]);
    f32x4 B1 = *reinterpret_cast<const f32x4*>(&BCls[l][4]);
    f32x4 B2 = *reinterpret_cast<const f32x4*>(&BCls[l][8]);
    f32x4 B3 = *reinterpret_cast<const f32x4*>(&BCls[l][12]);
    f32x4 C0 = *reinterpret_cast<const f32x4*>(&BCls[l][16]);
    f32x4 C1 = *reinterpret_cast<const f32x4*>(&BCls[l][20]);
    f32x4 C2 = *reinterpret_cast<const f32x4*>(&BCls[l][24]);
    f32x4 C3 = *reinterpret_cast<const f32x4*>(&BCls[l][28]);
    float du = dtc * uc;
    float Bsr[D_STATE] = {B0[0],B0[1],B0[2],B0[3], B1[0],B1[1],B1[2],B1[3],
                          B2[0],B2[1],B2[2],B2[3], B3[0],B3[1],B3[2],B3[3]};
    float Csr[D_STATE] = {C0[0],C0[1],C0[2],C0[3], C1[0],C1[1],C1[2],C1[3],
                          C2[0],C2[1],C2[2],C2[3], C3[0],C3[1],C3[2],C3[3]};
    float y = 0.f;
#pragma unroll
    for (int n = 0; n < D_STATE; ++n) {
      float dA = __builtin_amdgcn_exp2f(dtc * Av2[n]);
      h[n] = dA * h[n] + du * Bsr[n];
      y = fmaf(h[n], Csr[n], y);
    }
    y = fmaf(uc, Dd, y);
    yrow[(size_t)l * D_INNER] = f2bf(y * (zc * sigmoidf_(zc)));
  }
}

// ---------------- GEGLU: bf16 in, bf16 out ----------------
__global__ __launch_bounds__(256) void glu_kernel(
    const ushort_t* __restrict__ u, ushort_t* __restrict__ o) {
  int i = blockIdx.x * 256 + threadIdx.x;   // 8 f's per thread
  int m = i >> 9;                           // / (FF/8)
  int f0 = (i & 511) * 8;
  bf16x8 av = *reinterpret_cast<const bf16x8*>(u + (size_t)m * (2 * FF) + f0);
  bf16x8 gv = *reinterpret_cast<const bf16x8*>(u + (size_t)m * (2 * FF) + FF + f0);
  bf16x8 ov;
#pragma unroll
  for (int e = 0; e < 8; ++e) {
    float a = bf2f((ushort_t)av[e]);
    float g = bf2f((ushort_t)gv[e]);
    float ge = 0.5f * g * (1.f + erff(g * 0.70710678118654752f));
    ov[e] = (short)f2bf(a * ge);
  }
  *reinterpret_cast<bf16x8*>(o + (size_t)m * FF + f0) = ov;
}

extern "C" void kernel_launch(void* const* d_in, const int* in_sizes, int n_in,
                              void* d_out, int out_size, void* d_ws, size_t ws_size,
                              hipStream_t stream) {
  const float* x         = (const float*)d_in[0];
  const float* in_proj_w = (const float*)d_in[1];
  const float* conv_w    = (const float*)d_in[2];
  const float* conv_b    = (const float*)d_in[3];
  const float* x_proj_w  = (const float*)d_in[4];
  const float* dt_proj_w = (const float*)d_in[5];
  const float* dt_proj_b = (const float*)d_in[6];
  const float* A_log     = (const float*)d_in[7];
  const float* Dp        = (const float*)d_in[8];
  const float* out_proj_w= (const float*)d_in[9];
  const float* rms_w     = (const float*)d_in[10];
  const float* ln_w      = (const float*)d_in[11];
  const float* ln_b      = (const float*)d_in[12];
  const float* ff_w1     = (const float*)d_in[13];
  const float* ff_b1     = (const float*)d_in[14];
  const float* ff_w2     = (const float*)d_in[15];
  const float* ff_b2     = (const float*)d_in[16];
  float* out = (float*)d_out;

  float* ws = (float*)d_ws;
  // ---- layout (float-word offsets); total end = 65,536,000 w = 250.0 MiB ----
  float* res     = ws;                              // [0, 4194304)
  float* hbuf    = ws + 4194304;                    // [4194304, 8388608)
  float* xdbl    = ws + 8388608;                    // [8388608, 8781824)
  // dtsum overlays hbuf tail-safe region (hbuf dead between res_rms use and LN write):
  float* dtsum   = ws + 4194304;                    // B*NC*D_INNER = 262,144 w
  ushort_t* hbuf_bf = (ushort_t*)(ws + 8912896);    // 4M ushorts [8912896, 11010048)
  float*    pbuf    = ws + 11010048;                // x_proj partials 3.1M w
  ushort_t* y_bf    = (ushort_t*)(ws + 15204352);   // 8M ushorts [15204352, 19398656)
  ushort_t* glu_bf  = (ushort_t*)(ws + 11010048);   // overlays pbuf+y_bf (FFN phase)
  float* big   = ws + 19398656;                     // [19398656, 52953088)
  ushort_t* xz_bf = (ushort_t*)big;                 // 16.7M ushorts = 8,388,608 w (layer phase)
  float* xc    = big + 8388608;                     // 8,388,608 w
  float* delta = big + 16777216;                    // 8,388,608 w
  float* harr  = big + 25165824;                    // B*NC*16*D_INNER = 4,194,304 w
  ushort_t* ffu_bf = (ushort_t*)big;                // 33.5M ushorts (FFN phase)
  float* op_out= big;                               // 4M w (overlays xz_bf after scan)
  ushort_t* nrm_bf = (ushort_t*)delta;              // 4M ushorts (dead before dt_proj writes)
  ushort_t* in_w_bf  = (ushort_t*)(ws + 52953088);  // 8M ushorts [52953088, 57147392)
  ushort_t* out_w_bf = (ushort_t*)(ws + 57147392);  // 4M ushorts [57147392, 59244544)
  ushort_t* ff1_bf   = (ushort_t*)(ws + 59244544);  // 8M ushorts [59244544, 63438848)
  ushort_t* ff2_bf   = (ushort_t*)(ws + 63438848);  // 4M ushorts [63438848, 65536000)

  dim3 tb(16, 16);

  // weight conversions (every call; deterministic)
  f2b_kernel<<<8192, 256, 0, stream>>>(in_proj_w, in_w_bf, 8388608);
  f2b_kernel<<<4096, 256, 0, stream>>>(out_proj_w, out_w_bf, 4194304);
  f2b_kernel<<<8192, 256, 0, stream>>>(ff_w1, ff1_bf, 8388608);
  f2b_kernel<<<4096, 256, 0, stream>>>(ff_w2, ff2_bf, 4194304);

  for (int i = 0; i < DEPTH; ++i) {
    const float* cw    = conv_w + (size_t)i * D_INNER * D_CONV;
    const float* cb    = conv_b + (size_t)i * D_INNER;
    const float* xp_w  = x_proj_w + (size_t)i * 96 * D_INNER;
    const float* dtp_w = dt_proj_w + (size_t)i * D_INNER * DT_RANK;
    const float* dtp_b = dt_proj_b + (size_t)i * D_INNER;
    const float* Alg   = A_log + (size_t)i * D_INNER * D_STATE;
    const float* Di    = Dp + (size_t)i * D_INNER;

    res_rms_kernel<<<ROWS, 256, 0, stream>>>(i == 0 ? x : res, i == 0 ? nullptr : hbuf,
                                             res, nrm_bf, rms_w + (size_t)i * DIM);
    // in_proj: xz_bf[4096,4096] = nrm * in_w^T  (bf16 MFMA, bf16 out)
    gemm_bf16_nt<4><<<dim3(32, 32), 256, 0, stream>>>(
        nrm_bf, in_w_bf + (size_t)i * 4194304, nullptr, xz_bf, 2 * D_INNER, DIM,
        nullptr, 16);
    conv_silu_kernel<<<(ROWS * D_INNER / 4) / 256, 256, 0, stream>>>(xz_bf, xc, cw, cb);
    // x_proj: split-K two-stage
    xproj_partial<<<dim3(XP_KS, 64), 256, 0, stream>>>(xc, xp_w, pbuf);
    xproj_reduce<<<(ROWS * 96) / 256, 256, 0, stream>>>(pbuf, xdbl);
    gemm_nt<<<dim3(32, 64), tb, 0, stream>>>(xdbl, 96, dtp_w, DT_RANK, delta, D_INNER,
                                             D_INNER, DT_RANK, dtp_b, 1);
    scan_pass1<<<(BATCH * NC * D_INNER) / 256, 256, 0, stream>>>(delta, xc, xdbl, Alg,
                                                                 harr, dtsum);
    scan_pass2<<<(BATCH * D_STATE * D_INNER) / 256, 256, 0, stream>>>(harr, dtsum, Alg);
    scan_pass3<<<(BATCH * NC * D_INNER) / 256, 256, 0, stream>>>(delta, xc, y_bf, xdbl,
                                                                 xz_bf, Alg, Di, harr);
    // out_proj: op_out[4096,1024] = y * o_w^T  (bf16 MFMA, fp32 out); xz dead now
    gemm_bf16_nt<4><<<dim3(8, 32), 256, 0, stream>>>(
        y_bf, out_w_bf + (size_t)i * 2097152, op_out, nullptr, DIM, D_INNER,
        nullptr, 8);
    layernorm_kernel<<<ROWS, 256, 0, stream>>>(op_out, hbuf, hbuf_bf,
                                               ln_w + (size_t)i * DIM, ln_b + (size_t)i * DIM);
  }

  // FFN1: ffu_bf[4096,8192] = hbuf * ff_w1^T + b1  (bf16 MFMA, bf16 out)
  gemm_bf16_nt<4><<<dim3(64, 32), 256, 0, stream>>>(hbuf_bf, ff1_bf, nullptr, ffu_bf,
                                                    2 * FF, DIM, ff_b1, 16);
  glu_kernel<<<(ROWS * FF / 8) / 256, 256, 0, stream>>>(ffu_bf, glu_bf);
  // FFN2: out = glu * ff_w2^T + b2  (bf16 MFMA, fp32 out)
  gemm_bf16_nt<4><<<dim3(8, 32), 256, 0, stream>>>(glu_bf, ff2_bf, out, nullptr, DIM, FF,
                                                   ff_b2, 8);
}

// Round 12
// 817.985 us; speedup vs baseline: 1.0605x; 1.0479x over previous
//
#include <hip/hip_runtime.h>
#include <cstdint>
#include <cstddef>

#define DIM     1024
#define SEQ     2048
#define BATCH   2
#define DEPTH   2
#define D_INNER 2048
#define D_STATE 16
#define D_CONV  4
#define DT_RANK 64
#define FF      4096
#define ROWS    (BATCH*SEQ)   // 4096
#define EPS     1e-5f

#define CS      32            // scan chunk size
#define NC      (SEQ/CS)      // 64 chunks
#define NC_LOG  6

#define XP_KS    8            // x_proj k-split
#define XP_KSTEP (D_INNER/XP_KS)  // 256

#define LOG2E 1.44269504088896f

typedef unsigned short ushort_t;
typedef short bf16x8 __attribute__((ext_vector_type(8)));
typedef float f32x4  __attribute__((ext_vector_type(4)));

__device__ __forceinline__ float sigmoidf_(float x) { return 1.f / (1.f + __expf(-x)); }

// bf16 <-> fp32
__device__ __forceinline__ ushort_t f2bf(float x) {
  unsigned int u = __float_as_uint(x);
  u += 0x7fffu + ((u >> 16) & 1u);
  return (ushort_t)(u >> 16);
}
__device__ __forceinline__ float bf2f(ushort_t u) {
  return __uint_as_float((unsigned)u << 16);
}

// async global->LDS 16B (wave-uniform LDS base + lane*16)
__device__ __forceinline__ void async_cp16(const void* g, void* lds) {
  __builtin_amdgcn_global_load_lds(
      (const __attribute__((address_space(1))) unsigned int*)g,
      (__attribute__((address_space(3))) unsigned int*)lds, 16, 0, 0);
}

// ---------------- block-wide reduction ----------------
__device__ __forceinline__ float2 block_sum2(float a, float b) {
#pragma unroll
  for (int off = 32; off > 0; off >>= 1) {
    a += __shfl_down(a, off, 64);
    b += __shfl_down(b, off, 64);
  }
  __shared__ float sa[4], sb[4];
  __syncthreads();
  if ((threadIdx.x & 63) == 0) { int w = threadIdx.x >> 6; sa[w] = a; sb[w] = b; }
  __syncthreads();
  return make_float2(sa[0] + sa[1] + sa[2] + sa[3], sb[0] + sb[1] + sb[2] + sb[3]);
}

// ---------------- residual add + RMSNorm (bf16 normed out) ----------------
__global__ __launch_bounds__(256) void res_rms_kernel(
    const float* __restrict__ xin, const float* __restrict__ hadd,
    float* __restrict__ res, ushort_t* __restrict__ nrm, const float* __restrict__ w) {
  int row = blockIdx.x;
  const float* xr = xin + (size_t)row * DIM;
  const float* hr = hadd ? hadd + (size_t)row * DIM : nullptr;
  float* rr = res + (size_t)row * DIM;
  ushort_t* nr = nrm + (size_t)row * DIM;
  float v[4]; float ss = 0.f;
#pragma unroll
  for (int i = 0; i < 4; ++i) {
    int j = threadIdx.x + i * 256;
    float t = xr[j];
    if (hr) t += hr[j];
    v[i] = t; rr[j] = t; ss += t * t;
  }
  float2 s = block_sum2(ss, 0.f);
  float rstd = rsqrtf(s.x * (1.f / DIM) + EPS);
#pragma unroll
  for (int i = 0; i < 4; ++i) {
    int j = threadIdx.x + i * 256;
    nr[j] = f2bf(v[i] * rstd * w[j]);
  }
}

// ---------------- LayerNorm (fp32 + bf16 out) ----------------
__global__ __launch_bounds__(256) void layernorm_kernel(
    const float* __restrict__ in, float* __restrict__ out, ushort_t* __restrict__ outb,
    const float* __restrict__ w, const float* __restrict__ b) {
  int row = blockIdx.x;
  const float* xr = in + (size_t)row * DIM;
  float* orow = out + (size_t)row * DIM;
  ushort_t* obrow = outb + (size_t)row * DIM;
  float v[4]; float s1 = 0.f, s2 = 0.f;
#pragma unroll
  for (int i = 0; i < 4; ++i) {
    int j = threadIdx.x + i * 256;
    float t = xr[j];
    v[i] = t; s1 += t; s2 += t * t;
  }
  float2 s = block_sum2(s1, s2);
  float mean = s.x * (1.f / DIM);
  float var = s.y * (1.f / DIM) - mean * mean;
  float rstd = rsqrtf(var + EPS);
#pragma unroll
  for (int i = 0; i < 4; ++i) {
    int j = threadIdx.x + i * 256;
    float o = (v[i] - mean) * rstd * w[j] + b[j];
    orow[j] = o;
    obrow[j] = f2bf(o);
  }
}

// ---------------- fp32 -> bf16 converter (weights) ----------------
__global__ __launch_bounds__(256) void f2b_kernel(
    const float* __restrict__ s, ushort_t* __restrict__ d, int n) {
  int i = (blockIdx.x * 256 + threadIdx.x) * 4;
  if (i >= n) return;
  float4 v = *reinterpret_cast<const float4*>(s + i);
  d[i + 0] = f2bf(v.x); d[i + 1] = f2bf(v.y);
  d[i + 2] = f2bf(v.z); d[i + 3] = f2bf(v.w);
}

// ---------------- bf16 MFMA NT GEMM: C = A[M,K] * B[N,K]^T (+bias) ----------------
// 128x128 tile, BK=64, 4 waves (2x2), 16x16x32 MFMA, single-buffer LDS.
// Block mapping: XCD-chunk swizzle (T1) then CUTLASS-style grouped supertile.
__global__ __launch_bounds__(256) void gemm_bf16_nt(
    const ushort_t* __restrict__ A,
    const ushort_t* __restrict__ B,
    float* __restrict__ C,
    ushort_t* __restrict__ Cb,
    int N, int K,
    const float* __restrict__ bias, int grp) {
  __shared__ ushort_t As[128 * 64];
  __shared__ ushort_t Bs[128 * 64];
  const int tid = threadIdx.x;
  const int l = tid & 63;
  const int w = tid >> 6;

  const unsigned nwgx = gridDim.x;
  const unsigned nwg = nwgx * gridDim.y;
  const unsigned bid = blockIdx.y * nwgx + blockIdx.x;
  const unsigned cpx = nwg >> 3;
  const unsigned s = (bid & 7u) * cpx + (bid >> 3);
  const unsigned bandw = (unsigned)grp * nwgx;
  const unsigned band = s / bandw;
  const unsigned rem = s % bandw;
  const int m0 = (int)(band * grp + (rem % grp)) * 128;
  const int n0 = (int)(rem / grp) * 128;

  const int wm = (w >> 1) * 64;
  const int wn = (w & 1) * 64;

  const int srow = l >> 3;                      // 0..7 (row within 8-row chunk)
  const int ksrc = 8 * ((l & 7) ^ srow);        // swizzled source k-offset (elements)
  const int kg = l >> 4;                        // 0..3
  const int lr = l & 15;

  f32x4 acc[4][4];
#pragma unroll
  for (int mi = 0; mi < 4; ++mi)
#pragma unroll
    for (int ni = 0; ni < 4; ++ni) acc[mi][ni] = (f32x4)0.f;

  for (int k0 = 0; k0 < K; k0 += 64) {
#pragma unroll
    for (int j = 0; j < 4; ++j) {
      int c = j * 4 + w;                        // A chunks 0..15 (8 rows each)
      int r = c * 8 + srow;
      async_cp16(&A[(size_t)(m0 + r) * K + k0 + ksrc], &As[c * 512]);
    }
#pragma unroll
    for (int j = 0; j < 4; ++j) {
      int c = j * 4 + w;
      int r = c * 8 + srow;
      async_cp16(&B[(size_t)(n0 + r) * K + k0 + ksrc], &Bs[c * 512]);
    }
    __syncthreads();   // compiler drains vmcnt before barrier
#pragma unroll
    for (int ks = 0; ks < 2; ++ks) {
      bf16x8 af[4], bfr[4];
#pragma unroll
      for (int mi = 0; mi < 4; ++mi) {
        int r = wm + mi * 16 + lr;
        int boff = r * 128 + ((ks * 64 + kg * 16) ^ ((r & 7) << 4));
        af[mi] = *reinterpret_cast<const bf16x8*>(reinterpret_cast<const char*>(As) + boff);
      }
#pragma unroll
      for (int ni = 0; ni < 4; ++ni) {
        int r = wn + ni * 16 + lr;
        int boff = r * 128 + ((ks * 64 + kg * 16) ^ ((r & 7) << 4));
        bfr[ni] = *reinterpret_cast<const bf16x8*>(reinterpret_cast<const char*>(Bs) + boff);
      }
#pragma unroll
      for (int mi = 0; mi < 4; ++mi)
#pragma unroll
        for (int ni = 0; ni < 4; ++ni)
          acc[mi][ni] = __builtin_amdgcn_mfma_f32_16x16x32_bf16(af[mi], bfr[ni], acc[mi][ni], 0, 0, 0);
    }
    __syncthreads();
  }

  const int crow0 = (l >> 4) * 4;
  const int ccol = l & 15;
#pragma unroll
  for (int mi = 0; mi < 4; ++mi) {
#pragma unroll
    for (int ni = 0; ni < 4; ++ni) {
      int col = n0 + wn + ni * 16 + ccol;
      float bv = bias ? bias[col] : 0.f;
#pragma unroll
      for (int j = 0; j < 4; ++j) {
        int row = m0 + wm + mi * 16 + crow0 + j;
        float v = acc[mi][ni][j] + bv;
        if (Cb) Cb[(size_t)row * N + col] = f2bf(v);
        else    C[(size_t)row * N + col] = v;
      }
    }
  }
}

// ---------------- fused FFN1 + GEGLU: glu = a * gelu(g), bf16 out ----------------
// A[4096,1024] bf16, B=ff_w1[8192,1024] bf16, bias[8192].
// Block computes output cols [n0, n0+64) of glu_bf[4096, FF].
// B-tile 128 rows: rows 0..63 = ff_w1[n0..n0+64) (a-half), rows 64..127 =
// ff_w1[FF+n0..FF+n0+64) (g-half). Thread's acc[mi][ni] (ni<2 = a) pairs with
// acc[mi][ni+2] (g) for the SAME output column -> gelu applied in epilogue.
__global__ __launch_bounds__(256) void gemm_ffn1_glu(
    const ushort_t* __restrict__ A,
    const ushort_t* __restrict__ B,
    ushort_t* __restrict__ O,
    int K,
    const float* __restrict__ bias, int grp) {
  __shared__ ushort_t As[128 * 64];
  __shared__ ushort_t Bs[128 * 64];
  const int tid = threadIdx.x;
  const int l = tid & 63;
  const int w = tid >> 6;

  const unsigned nwgx = gridDim.x;                // 64 col-panels of width 64
  const unsigned nwg = nwgx * gridDim.y;
  const unsigned bid = blockIdx.y * nwgx + blockIdx.x;
  const unsigned cpx = nwg >> 3;
  const unsigned s = (bid & 7u) * cpx + (bid >> 3);
  const unsigned bandw = (unsigned)grp * nwgx;
  const unsigned band = s / bandw;
  const unsigned rem = s % bandw;
  const int m0 = (int)(band * grp + (rem % grp)) * 128;
  const int n0 = (int)(rem / grp) * 64;

  const int wm = (w >> 1) * 64;
  const int wn2 = (w & 1) * 32;

  const int srow = l >> 3;
  const int ksrc = 8 * ((l & 7) ^ srow);
  const int kg = l >> 4;
  const int lr = l & 15;

  f32x4 acc[4][4];
#pragma unroll
  for (int mi = 0; mi < 4; ++mi)
#pragma unroll
    for (int ni = 0; ni < 4; ++ni) acc[mi][ni] = (f32x4)0.f;

  for (int k0 = 0; k0 < K; k0 += 64) {
#pragma unroll
    for (int j = 0; j < 4; ++j) {
      int c = j * 4 + w;
      int r = c * 8 + srow;
      async_cp16(&A[(size_t)(m0 + r) * K + k0 + ksrc], &As[c * 512]);
    }
#pragma unroll
    for (int j = 0; j < 4; ++j) {
      int c = j * 4 + w;
      int gr = (c < 8) ? (n0 + c * 8 + srow)
                       : (FF + n0 + (c - 8) * 8 + srow);
      async_cp16(&B[(size_t)gr * K + k0 + ksrc], &Bs[c * 512]);
    }
    __syncthreads();
#pragma unroll
    for (int ks = 0; ks < 2; ++ks) {
      bf16x8 af[4], bfr[4];
#pragma unroll
      for (int mi = 0; mi < 4; ++mi) {
        int r = wm + mi * 16 + lr;
        int boff = r * 128 + ((ks * 64 + kg * 16) ^ ((r & 7) << 4));
        af[mi] = *reinterpret_cast<const bf16x8*>(reinterpret_cast<const char*>(As) + boff);
      }
#pragma unroll
      for (int ni = 0; ni < 4; ++ni) {
        int r = (ni < 2 ? wn2 + ni * 16 : 64 + wn2 + (ni - 2) * 16) + lr;
        int boff = r * 128 + ((ks * 64 + kg * 16) ^ ((r & 7) << 4));
        bfr[ni] = *reinterpret_cast<const bf16x8*>(reinterpret_cast<const char*>(Bs) + boff);
      }
#pragma unroll
      for (int mi = 0; mi < 4; ++mi)
#pragma unroll
        for (int ni = 0; ni < 4; ++ni)
          acc[mi][ni] = __builtin_amdgcn_mfma_f32_16x16x32_bf16(af[mi], bfr[ni], acc[mi][ni], 0, 0, 0);
    }
    __syncthreads();
  }

  const int crow0 = (l >> 4) * 4;
  const int ccol = l & 15;
#pragma unroll
  for (int mi = 0; mi < 4; ++mi) {
#pragma unroll
    for (int ni = 0; ni < 2; ++ni) {
      int col = n0 + wn2 + ni * 16 + ccol;
      float ba = bias[col];
      float bg = bias[FF + col];
#pragma unroll
      for (int j = 0; j < 4; ++j) {
        int row = m0 + wm + mi * 16 + crow0 + j;
        float a = acc[mi][ni][j] + ba;
        float g = acc[mi][ni + 2][j] + bg;
        float ge = 0.5f * g * (1.f + erff(g * 0.70710678118654752f));
        O[(size_t)row * FF + col] = f2bf(a * ge);
      }
    }
  }
}

// ---------------- fp32 NT GEMM (dt_proj) ----------------
__global__ __launch_bounds__(256) void gemm_nt(
    const float* __restrict__ A, int lda,
    const float* __restrict__ B, int ldb,
    float* __restrict__ C, int ldc,
    int N, int K,
    const float* __restrict__ bias, int act) {
  __shared__ __align__(16) float Asf[16][68];
  __shared__ __align__(16) float Bsf[16][68];
  const int tx = threadIdx.x;
  const int ty = threadIdx.y;
  const int tid = ty * 16 + tx;
  const int m0 = blockIdx.y * 64;
  const int n0 = blockIdx.x * 64;
  const int lrow = tid >> 2;
  const int lk = (tid & 3) * 4;

  float acc[4][4] = {{0.f}};

  for (int k0 = 0; k0 < K; k0 += 16) {
    float4 av, bv;
    {
      const float* ap = A + (size_t)(m0 + lrow) * lda + k0 + lk;
      av = *reinterpret_cast<const float4*>(ap);
    }
    int brow = n0 + lrow;
    if (brow < N) {
      const float* bp = B + (size_t)brow * ldb + k0 + lk;
      bv = *reinterpret_cast<const float4*>(bp);
    } else {
      bv = make_float4(0.f, 0.f, 0.f, 0.f);
    }
    __syncthreads();
    Asf[lk + 0][lrow] = av.x; Asf[lk + 1][lrow] = av.y;
    Asf[lk + 2][lrow] = av.z; Asf[lk + 3][lrow] = av.w;
    Bsf[lk + 0][lrow] = bv.x; Bsf[lk + 1][lrow] = bv.y;
    Bsf[lk + 2][lrow] = bv.z; Bsf[lk + 3][lrow] = bv.w;
    __syncthreads();
#pragma unroll
    for (int k = 0; k < 16; ++k) {
      const float4 a4 = *reinterpret_cast<const float4*>(&Asf[k][ty * 4]);
      const float4 b4 = *reinterpret_cast<const float4*>(&Bsf[k][tx * 4]);
      float a[4] = {a4.x, a4.y, a4.z, a4.w};
      float bb[4] = {b4.x, b4.y, b4.z, b4.w};
#pragma unroll
      for (int i = 0; i < 4; ++i)
#pragma unroll
        for (int j = 0; j < 4; ++j)
          acc[i][j] = fmaf(a[i], bb[j], acc[i][j]);
    }
  }

#pragma unroll
  for (int i = 0; i < 4; ++i) {
    int m = m0 + ty * 4 + i;
#pragma unroll
    for (int j = 0; j < 4; ++j) {
      int n = n0 + tx * 4 + j;
      if (n < N) {
        float v = acc[i][j];
        if (bias) v += bias[n];
        if (act == 1) v = (v > 20.f) ? v : log1pf(__expf(v));
        C[(size_t)m * ldc + n] = v;
      }
    }
  }
}

// ---------------- x_proj split-K stage 1 ----------------
__global__ __launch_bounds__(256) void xproj_partial(
    const float* __restrict__ A,   // xc [4096, 2048]
    const float* __restrict__ W,   // [96, 2048]
    float* __restrict__ pbuf) {    // [XP_KS, 4096, 96]
  __shared__ __align__(16) float As[64][68];
  __shared__ __align__(16) float Wsd[96][68];
  const int ks = blockIdx.x;
  const int mb = blockIdx.y;
  const int tid = threadIdx.x;
  const int r0 = (tid >> 4) * 4;        // 0..60
  const int c0 = (tid & 15) * 6;        // 0..90

  float acc[4][6];
#pragma unroll
  for (int i = 0; i < 4; ++i)
#pragma unroll
    for (int j = 0; j < 6; ++j) acc[i][j] = 0.f;

  for (int k0 = 0; k0 < XP_KSTEP; k0 += 64) {
    const int kbase = ks * XP_KSTEP + k0;
    __syncthreads();
    {
      int r = tid >> 2, c = (tid & 3) * 16;
      const float* src = A + (size_t)(mb * 64 + r) * D_INNER + kbase + c;
#pragma unroll
      for (int q = 0; q < 4; ++q)
        *reinterpret_cast<float4*>(&As[r][c + q * 4]) =
            *reinterpret_cast<const float4*>(src + q * 4);
    }
#pragma unroll
    for (int q = 0; q < 6; ++q) {
      int f = q * 256 + tid;
      int wr = f >> 4;
      int wc = (f & 15) * 4;
      *reinterpret_cast<float4*>(&Wsd[wr][wc]) =
          *reinterpret_cast<const float4*>(&W[(size_t)wr * D_INNER + kbase + wc]);
    }
    __syncthreads();
#pragma unroll 16
    for (int k = 0; k < 64; ++k) {
      float a[4], wv[6];
#pragma unroll
      for (int i = 0; i < 4; ++i) a[i] = As[r0 + i][k];
#pragma unroll
      for (int j = 0; j < 6; ++j) wv[j] = Wsd[c0 + j][k];
#pragma unroll
      for (int i = 0; i < 4; ++i)
#pragma unroll
        for (int j = 0; j < 6; ++j)
          acc[i][j] = fmaf(a[i], wv[j], acc[i][j]);
    }
  }

  float* dst = pbuf + ((size_t)ks * ROWS + mb * 64) * 96;
#pragma unroll
  for (int i = 0; i < 4; ++i)
#pragma unroll
    for (int j = 0; j < 6; ++j)
      dst[(size_t)(r0 + i) * 96 + c0 + j] = acc[i][j];
}

// ---------------- x_proj split-K stage 2: reduce ----------------
__global__ __launch_bounds__(256) void xproj_reduce(
    const float* __restrict__ pbuf, float* __restrict__ xdbl) {
  int i = blockIdx.x * 256 + threadIdx.x;   // 0 .. ROWS*96-1
  float s = 0.f;
#pragma unroll
  for (int ks = 0; ks < XP_KS; ++ks)
    s += pbuf[(size_t)ks * (ROWS * 96) + i];
  xdbl[i] = s;
}

// ---------------- causal depthwise conv (k=4) + SiLU, bf16 in / fp32 out ----------------
__global__ __launch_bounds__(256) void conv_silu_kernel(
    const ushort_t* __restrict__ xzb, float* __restrict__ xc,
    const float* __restrict__ cw, const float* __restrict__ cb) {
  int t = (blockIdx.x * 256 + threadIdx.x) * 4;
  if (t >= ROWS * D_INNER) return;
  int d = t & (D_INNER - 1);
  int row = t >> 11;
  int l = row & (SEQ - 1);
  float acc[4];
#pragma unroll
  for (int q = 0; q < 4; ++q) acc[q] = cb[d + q];
#pragma unroll
  for (int j = 0; j < 4; ++j) {
    int ls = l - 3 + j;
    if (ls >= 0) {
      ushort4 uv = *reinterpret_cast<const ushort4*>(
          xzb + (size_t)(row - 3 + j) * (2 * D_INNER) + d);
      acc[0] = fmaf(cw[(d + 0) * 4 + j], bf2f(uv.x), acc[0]);
      acc[1] = fmaf(cw[(d + 1) * 4 + j], bf2f(uv.y), acc[1]);
      acc[2] = fmaf(cw[(d + 2) * 4 + j], bf2f(uv.z), acc[2]);
      acc[3] = fmaf(cw[(d + 3) * 4 + j], bf2f(uv.w), acc[3]);
    }
  }
  float4 o;
  o.x = acc[0] * sigmoidf_(acc[0]);
  o.y = acc[1] * sigmoidf_(acc[1]);
  o.z = acc[2] * sigmoidf_(acc[2]);
  o.w = acc[3] * sigmoidf_(acc[3]);
  *reinterpret_cast<float4*>(xc + t) = o;
}

// ================= chunked selective scan (CS=32, LDS B/C, 4-deep prefetch) =================
__global__ __launch_bounds__(256) void scan_pass1(
    const float* __restrict__ delta,
    const float* __restrict__ xc,
    const float* __restrict__ xdbl,
    const float* __restrict__ A_log,
    float* __restrict__ harr,
    float* __restrict__ dtsum) {
  __shared__ __align__(16) float Bls[CS][16];
  int gid = blockIdx.x * 256 + threadIdx.x;
  int d = gid & (D_INNER - 1);
  int bc = gid >> 11;
  int c = bc & (NC - 1);
  int b = bc >> NC_LOG;
  const size_t r0 = (size_t)b * SEQ + (size_t)c * CS;

  if (threadIdx.x < CS * 4) {
    int sl = threadIdx.x >> 2, sf = (threadIdx.x & 3) * 4;
    *reinterpret_cast<f32x4*>(&Bls[sl][sf]) =
        *reinterpret_cast<const f32x4*>(xdbl + (r0 + sl) * 96 + 64 + sf);
  }

  float Av2[D_STATE];
#pragma unroll
  for (int n = 0; n < D_STATE; ++n)
    Av2[n] = -__expf(A_log[(size_t)d * D_STATE + n]) * LOG2E;
  float h[D_STATE];
#pragma unroll
  for (int n = 0; n < D_STATE; ++n) h[n] = 0.f;
  float dts = 0.f;

  const float* drow = delta + r0 * D_INNER + d;
  const float* urow = xc + r0 * D_INNER + d;

  float pdt[4], pu[4];
#pragma unroll
  for (int g = 0; g < 4; ++g) {
    pdt[g] = drow[(size_t)g * D_INNER];
    pu[g]  = urow[(size_t)g * D_INNER];
  }
  __syncthreads();

  for (int l0 = 0; l0 < CS; l0 += 4) {
    float cdt[4], cu[4];
#pragma unroll
    for (int g = 0; g < 4; ++g) { cdt[g] = pdt[g]; cu[g] = pu[g]; }
    if (l0 + 4 < CS) {
#pragma unroll
      for (int g = 0; g < 4; ++g) {
        pdt[g] = drow[(size_t)(l0 + 4 + g) * D_INNER];
        pu[g]  = urow[(size_t)(l0 + 4 + g) * D_INNER];
      }
    }
#pragma unroll
    for (int g = 0; g < 4; ++g) {
      int l = l0 + g;
      f32x4 B0 = *reinterpret_cast<const f32x4*>(&Bls[l][0]);
      f32x4 B1 = *reinterpret_cast<const f32x4*>(&Bls[l][4]);
      f32x4 B2 = *reinterpret_cast<const f32x4*>(&Bls[l][8]);
      f32x4 B3 = *reinterpret_cast<const f32x4*>(&Bls[l][12]);
      float du = cdt[g] * cu[g];
      dts += cdt[g];
      float Bsr[D_STATE] = {B0[0],B0[1],B0[2],B0[3], B1[0],B1[1],B1[2],B1[3],
                            B2[0],B2[1],B2[2],B2[3], B3[0],B3[1],B3[2],B3[3]};
#pragma unroll
      for (int n = 0; n < D_STATE; ++n) {
        float dA = __builtin_amdgcn_exp2f(cdt[g] * Av2[n]);
        h[n] = dA * h[n] + du * Bsr[n];
      }
    }
  }
#pragma unroll
  for (int n = 0; n < D_STATE; ++n)
    harr[((size_t)bc * D_STATE + n) * D_INNER + d] = h[n];
  dtsum[(size_t)bc * D_INNER + d] = dts;
}

// pass2: sequential combine over NC chunks; IN-PLACE: harr[c] := h0 for chunk c
__global__ __launch_bounds__(256) void scan_pass2(
    float* __restrict__ harr,
    const float* __restrict__ dtsum,
    const float* __restrict__ A_log) {
  int gid = blockIdx.x * 256 + threadIdx.x;
  int d = gid & (D_INNER - 1);
  int bn = gid >> 11;
  int n = bn & (D_STATE - 1);
  int b = bn >> 4;
  float Av2 = -__expf(A_log[(size_t)d * D_STATE + n]) * LOG2E;
  float h = 0.f;
  for (int c = 0; c < NC; ++c) {
    size_t bc = (size_t)b * NC + c;
    size_t idx = (bc * D_STATE + n) * D_INNER + d;
    float he = harr[idx];
    harr[idx] = h;
    float P = __builtin_amdgcn_exp2f(Av2 * dtsum[bc * D_INNER + d]);
    h = P * h + he;
  }
}

// pass3: rescan with true h0, y = h·C + u*D, gate silu(z) -> bf16
__global__ __launch_bounds__(256) void scan_pass3(
    const float* __restrict__ delta,
    const float* __restrict__ xc,
    ushort_t* __restrict__ ybf,
    const float* __restrict__ xdbl,
    const ushort_t* __restrict__ xzb,
    const float* __restrict__ A_log,
    const float* __restrict__ Dp,
    const float* __restrict__ harr) {
  __shared__ __align__(16) float BCls[CS][32];   // B at [0..16), C at [16..32)
  int gid = blockIdx.x * 256 + threadIdx.x;
  int d = gid & (D_INNER - 1);
  int bc = gid >> 11;
  int c = bc & (NC - 1);
  int b = bc >> NC_LOG;
  const size_t r0 = (size_t)b * SEQ + (size_t)c * CS;

  {
    int sl = threadIdx.x >> 3, sf = (threadIdx.x & 7) * 4;
    *reinterpret_cast<f32x4*>(&BCls[sl][sf]) =
        *reinterpret_cast<const f32x4*>(xdbl + (r0 + sl) * 96 + 64 + sf);
  }

  float Av2[D_STATE];
#pragma unroll
  for (int n = 0; n < D_STATE; ++n)
    Av2[n] = -__expf(A_log[(size_t)d * D_STATE + n]) * LOG2E;
  const float Dd = Dp[d];
  float h[D_STATE];
#pragma unroll
  for (int n = 0; n < D_STATE; ++n)
    h[n] = harr[((size_t)bc * D_STATE + n) * D_INNER + d];

  const float* drow = delta + r0 * D_INNER + d;
  const float* urow = xc + r0 * D_INNER + d;
  const ushort_t* zrow = xzb + r0 * (2 * D_INNER) + D_INNER + d;
  ushort_t* yrow = ybf + r0 * D_INNER + d;

  float pdt[4], pu[4], pz[4];
#pragma unroll
  for (int g = 0; g < 4; ++g) {
    pdt[g] = drow[(size_t)g * D_INNER];
    pu[g]  = urow[(size_t)g * D_INNER];
    pz[g]  = bf2f(zrow[(size_t)g * (2 * D_INNER)]);
  }
  __syncthreads();

  for (int l0 = 0; l0 < CS; l0 += 4) {
    float cdt[4], cu[4], cz[4];
#pragma unroll
    for (int g = 0; g < 4; ++g) { cdt[g] = pdt[g]; cu[g] = pu[g]; cz[g] = pz[g]; }
    if (l0 + 4 < CS) {
#pragma unroll
      for (int g = 0; g < 4; ++g) {
        pdt[g] = drow[(size_t)(l0 + 4 + g) * D_INNER];
        pu[g]  = urow[(size_t)(l0 + 4 + g) * D_INNER];
        pz[g]  = bf2f(zrow[(size_t)(l0 + 4 + g) * (2 * D_INNER)]);
      }
    }
#pragma unroll
    for (int g = 0; g < 4; ++g) {
      int l = l0 + g;
      f32x4 B0 = *reinterpret_cast<const f32x4*>(&BCls[l][0]);
      f32x4 B1 = *reinterpret_cast<const f32x4*>(&BCls[l][4]);
      f32x4 B2 = *reinterpret_cast<const f32x4*>(&BCls[l][8]);
      f32x4 B3 = *reinterpret_cast<const f32x4*>(&BCls[l][12]);
      f32x4 C0 = *reinterpret_cast<const f32x4*>(&BCls[l][16]);
      f32x4 C1 = *reinterpret_cast<const f32x4*>(&BCls[l][20]);
      f32x4 C2 = *reinterpret_cast<const f32x4*>(&BCls[l][24]);
      f32x4 C3 = *reinterpret_cast<const f32x4*>(&BCls[l][28]);
      float du = cdt[g] * cu[g];
      float Bsr[D_STATE] = {B0[0],B0[1],B0[2],B0[3], B1[0],B1[1],B1[2],B1[3],
                            B2[0],B2[1],B2[2],B2[3], B3[0],B3[1],B3[2],B3[3]};
      float Csr[D_STATE] = {C0[0],C0[1],C0[2],C0[3], C1[0],C1[1],C1[2],C1[3],
                            C2[0],C2[1],C2[2],C2[3], C3[0],C3[1],C3[2],C3[3]};
      float y = 0.f;
#pragma unroll
      for (int n = 0; n < D_STATE; ++n) {
        float dA = __builtin_amdgcn_exp2f(cdt[g] * Av2[n]);
        h[n] = dA * h[n] + du * Bsr[n];
        y = fmaf(h[n], Csr[n], y);
      }
      y = fmaf(cu[g], Dd, y);
      yrow[(size_t)l * D_INNER] = f2bf(y * (cz[g] * sigmoidf_(cz[g])));
    }
  }
}

extern "C" void kernel_launch(void* const* d_in, const int* in_sizes, int n_in,
                              void* d_out, int out_size, void* d_ws, size_t ws_size,
                              hipStream_t stream) {
  const float* x         = (const float*)d_in[0];
  const float* in_proj_w = (const float*)d_in[1];
  const float* conv_w    = (const float*)d_in[2];
  const float* conv_b    = (const float*)d_in[3];
  const float* x_proj_w  = (const float*)d_in[4];
  const float* dt_proj_w = (const float*)d_in[5];
  const float* dt_proj_b = (const float*)d_in[6];
  const float* A_log     = (const float*)d_in[7];
  const float* Dp        = (const float*)d_in[8];
  const float* out_proj_w= (const float*)d_in[9];
  const float* rms_w     = (const float*)d_in[10];
  const float* ln_w      = (const float*)d_in[11];
  const float* ln_b      = (const float*)d_in[12];
  const float* ff_w1     = (const float*)d_in[13];
  const float* ff_b1     = (const float*)d_in[14];
  const float* ff_w2     = (const float*)d_in[15];
  const float* ff_b2     = (const float*)d_in[16];
  float* out = (float*)d_out;

  float* ws = (float*)d_ws;
  // ---- layout (float-word offsets); total end = 65,536,000 w = 250.0 MiB ----
  float* res     = ws;                              // [0, 4194304)
  float* hbuf    = ws + 4194304;                    // [4194304, 8388608)
  float* xdbl    = ws + 8388608;                    // [8388608, 8781824)
  float* dtsum   = ws + 4194304;                    // overlays hbuf; B*NC*D_INNER = 262,144 w
  ushort_t* hbuf_bf = (ushort_t*)(ws + 8912896);    // 4M ushorts [8912896, 11010048)
  float*    pbuf    = ws + 11010048;                // x_proj partials 3.1M w
  ushort_t* y_bf    = (ushort_t*)(ws + 15204352);   // 8M ushorts [15204352, 19398656)
  ushort_t* glu_bf  = (ushort_t*)(ws + 11010048);   // overlays pbuf+y_bf (FFN phase)
  float* big   = ws + 19398656;                     // [19398656, 52953088)
  ushort_t* xz_bf = (ushort_t*)big;                 // 16.7M ushorts = 8,388,608 w (layer phase)
  float* xc    = big + 8388608;                     // 8,388,608 w
  float* delta = big + 16777216;                    // 8,388,608 w
  float* harr  = big + 25165824;                    // B*NC*16*D_INNER = 4,194,304 w
  float* op_out= big;                               // 4M w (overlays xz_bf after scan)
  ushort_t* nrm_bf = (ushort_t*)delta;              // 4M ushorts (dead before dt_proj writes)
  ushort_t* in_w_bf  = (ushort_t*)(ws + 52953088);  // 8M ushorts [52953088, 57147392)
  ushort_t* out_w_bf = (ushort_t*)(ws + 57147392);  // 4M ushorts [57147392, 59244544)
  ushort_t* ff1_bf   = (ushort_t*)(ws + 59244544);  // 8M ushorts [59244544, 63438848)
  ushort_t* ff2_bf   = (ushort_t*)(ws + 63438848);  // 4M ushorts [63438848, 65536000)

  dim3 tb(16, 16);

  // weight conversions (every call; deterministic)
  f2b_kernel<<<8192, 256, 0, stream>>>(in_proj_w, in_w_bf, 8388608);
  f2b_kernel<<<4096, 256, 0, stream>>>(out_proj_w, out_w_bf, 4194304);
  f2b_kernel<<<8192, 256, 0, stream>>>(ff_w1, ff1_bf, 8388608);
  f2b_kernel<<<4096, 256, 0, stream>>>(ff_w2, ff2_bf, 4194304);

  for (int i = 0; i < DEPTH; ++i) {
    const float* cw    = conv_w + (size_t)i * D_INNER * D_CONV;
    const float* cb    = conv_b + (size_t)i * D_INNER;
    const float* xp_w  = x_proj_w + (size_t)i * 96 * D_INNER;
    const float* dtp_w = dt_proj_w + (size_t)i * D_INNER * DT_RANK;
    const float* dtp_b = dt_proj_b + (size_t)i * D_INNER;
    const float* Alg   = A_log + (size_t)i * D_INNER * D_STATE;
    const float* Di    = Dp + (size_t)i * D_INNER;

    res_rms_kernel<<<ROWS, 256, 0, stream>>>(i == 0 ? x : res, i == 0 ? nullptr : hbuf,
                                             res, nrm_bf, rms_w + (size_t)i * DIM);
    // in_proj: xz_bf[4096,4096] = nrm * in_w^T  (bf16 MFMA, bf16 out)
    gemm_bf16_nt<<<dim3(32, 32), 256, 0, stream>>>(
        nrm_bf, in_w_bf + (size_t)i * 4194304, nullptr, xz_bf, 2 * D_INNER, DIM,
        nullptr, 16);
    conv_silu_kernel<<<(ROWS * D_INNER / 4) / 256, 256, 0, stream>>>(xz_bf, xc, cw, cb);
    // x_proj: split-K two-stage
    xproj_partial<<<dim3(XP_KS, 64), 256, 0, stream>>>(xc, xp_w, pbuf);
    xproj_reduce<<<(ROWS * 96) / 256, 256, 0, stream>>>(pbuf, xdbl);
    gemm_nt<<<dim3(32, 64), tb, 0, stream>>>(xdbl, 96, dtp_w, DT_RANK, delta, D_INNER,
                                             D_INNER, DT_RANK, dtp_b, 1);
    scan_pass1<<<(BATCH * NC * D_INNER) / 256, 256, 0, stream>>>(delta, xc, xdbl, Alg,
                                                                 harr, dtsum);
    scan_pass2<<<(BATCH * D_STATE * D_INNER) / 256, 256, 0, stream>>>(harr, dtsum, Alg);
    scan_pass3<<<(BATCH * NC * D_INNER) / 256, 256, 0, stream>>>(delta, xc, y_bf, xdbl,
                                                                 xz_bf, Alg, Di, harr);
    // out_proj: op_out[4096,1024] = y * o_w^T  (bf16 MFMA, fp32 out); xz dead now
    gemm_bf16_nt<<<dim3(8, 32), 256, 0, stream>>>(
        y_bf, out_w_bf + (size_t)i * 2097152, op_out, nullptr, DIM, D_INNER,
        nullptr, 8);
    layernorm_kernel<<<ROWS, 256, 0, stream>>>(op_out, hbuf, hbuf_bf,
                                               ln_w + (size_t)i * DIM, ln_b + (size_t)i * DIM);
  }

  // FFN1 + GEGLU fused: glu_bf[4096,4096] = a*gelu(g), a|g = hbuf*ff_w1^T + b1
  gemm_ffn1_glu<<<dim3(64, 32), 256, 0, stream>>>(hbuf_bf, ff1_bf, glu_bf, DIM,
                                                  ff_b1, 16);
  // FFN2: out = glu * ff_w2^T + b2  (bf16 MFMA, fp32 out)
  gemm_bf16_nt<<<dim3(8, 32), 256, 0, stream>>>(glu_bf, ff2_bf, out, nullptr, DIM, FF,
                                                ff_b2, 8);
}

// Round 13
// 790.617 us; speedup vs baseline: 1.0972x; 1.0346x over previous
//
#include <hip/hip_runtime.h>
#include <cstdint>
#include <cstddef>

#define DIM     1024
#define SEQ     2048
#define BATCH   2
#define DEPTH   2
#define D_INNER 2048
#define D_STATE 16
#define D_CONV  4
#define DT_RANK 64
#define FF      4096
#define ROWS    (BATCH*SEQ)   // 4096
#define EPS     1e-5f

#define CS      32            // scan chunk size
#define NC      (SEQ/CS)      // 64 chunks
#define NC_LOG  6

#define XP_KS    8            // x_proj k-split
#define XP_KSTEP (D_INNER/XP_KS)  // 256

#define LOG2E 1.44269504088896f

typedef unsigned short ushort_t;
typedef short bf16x8 __attribute__((ext_vector_type(8)));
typedef float f32x4  __attribute__((ext_vector_type(4)));

__device__ __forceinline__ float sigmoidf_(float x) { return 1.f / (1.f + __expf(-x)); }

// bf16 <-> fp32
__device__ __forceinline__ ushort_t f2bf(float x) {
  unsigned int u = __float_as_uint(x);
  u += 0x7fffu + ((u >> 16) & 1u);
  return (ushort_t)(u >> 16);
}
__device__ __forceinline__ float bf2f(ushort_t u) {
  return __uint_as_float((unsigned)u << 16);
}

// async global->LDS 16B (wave-uniform LDS base + lane*16)
__device__ __forceinline__ void async_cp16(const void* g, void* lds) {
  __builtin_amdgcn_global_load_lds(
      (const __attribute__((address_space(1))) unsigned int*)g,
      (__attribute__((address_space(3))) unsigned int*)lds, 16, 0, 0);
}

// ---------------- block-wide reduction ----------------
__device__ __forceinline__ float2 block_sum2(float a, float b) {
#pragma unroll
  for (int off = 32; off > 0; off >>= 1) {
    a += __shfl_down(a, off, 64);
    b += __shfl_down(b, off, 64);
  }
  __shared__ float sa[4], sb[4];
  __syncthreads();
  if ((threadIdx.x & 63) == 0) { int w = threadIdx.x >> 6; sa[w] = a; sb[w] = b; }
  __syncthreads();
  return make_float2(sa[0] + sa[1] + sa[2] + sa[3], sb[0] + sb[1] + sb[2] + sb[3]);
}

// ---------------- residual add + RMSNorm (bf16 normed out) ----------------
__global__ __launch_bounds__(256) void res_rms_kernel(
    const float* __restrict__ xin, const float* __restrict__ hadd,
    float* __restrict__ res, ushort_t* __restrict__ nrm, const float* __restrict__ w) {
  int row = blockIdx.x;
  const float* xr = xin + (size_t)row * DIM;
  const float* hr = hadd ? hadd + (size_t)row * DIM : nullptr;
  float* rr = res + (size_t)row * DIM;
  ushort_t* nr = nrm + (size_t)row * DIM;
  float v[4]; float ss = 0.f;
#pragma unroll
  for (int i = 0; i < 4; ++i) {
    int j = threadIdx.x + i * 256;
    float t = xr[j];
    if (hr) t += hr[j];
    v[i] = t; rr[j] = t; ss += t * t;
  }
  float2 s = block_sum2(ss, 0.f);
  float rstd = rsqrtf(s.x * (1.f / DIM) + EPS);
#pragma unroll
  for (int i = 0; i < 4; ++i) {
    int j = threadIdx.x + i * 256;
    nr[j] = f2bf(v[i] * rstd * w[j]);
  }
}

// ---------------- LayerNorm (fp32 + bf16 out) ----------------
__global__ __launch_bounds__(256) void layernorm_kernel(
    const float* __restrict__ in, float* __restrict__ out, ushort_t* __restrict__ outb,
    const float* __restrict__ w, const float* __restrict__ b) {
  int row = blockIdx.x;
  const float* xr = in + (size_t)row * DIM;
  float* orow = out + (size_t)row * DIM;
  ushort_t* obrow = outb + (size_t)row * DIM;
  float v[4]; float s1 = 0.f, s2 = 0.f;
#pragma unroll
  for (int i = 0; i < 4; ++i) {
    int j = threadIdx.x + i * 256;
    float t = xr[j];
    v[i] = t; s1 += t; s2 += t * t;
  }
  float2 s = block_sum2(s1, s2);
  float mean = s.x * (1.f / DIM);
  float var = s.y * (1.f / DIM) - mean * mean;
  float rstd = rsqrtf(var + EPS);
#pragma unroll
  for (int i = 0; i < 4; ++i) {
    int j = threadIdx.x + i * 256;
    float o = (v[i] - mean) * rstd * w[j] + b[j];
    orow[j] = o;
    obrow[j] = f2bf(o);
  }
}

// ---------------- fp32 -> bf16 converter (weights) ----------------
__global__ __launch_bounds__(256) void f2b_kernel(
    const float* __restrict__ s, ushort_t* __restrict__ d, int n) {
  int i = (blockIdx.x * 256 + threadIdx.x) * 4;
  if (i >= n) return;
  float4 v = *reinterpret_cast<const float4*>(s + i);
  d[i + 0] = f2bf(v.x); d[i + 1] = f2bf(v.y);
  d[i + 2] = f2bf(v.z); d[i + 3] = f2bf(v.w);
}

// ---------------- bf16 MFMA NT GEMM: C = A[M,K] * B[N,K]^T (+bias) ----------------
// 128x128 tile, BK=64, 4 waves (2x2), 16x16x32 MFMA, single-buffer LDS.
// Block mapping: XCD-chunk swizzle (T1) then CUTLASS-style grouped supertile.
__global__ __launch_bounds__(256) void gemm_bf16_nt(
    const ushort_t* __restrict__ A,
    const ushort_t* __restrict__ B,
    float* __restrict__ C,
    ushort_t* __restrict__ Cb,
    int N, int K,
    const float* __restrict__ bias, int grp) {
  __shared__ ushort_t As[128 * 64];
  __shared__ ushort_t Bs[128 * 64];
  const int tid = threadIdx.x;
  const int l = tid & 63;
  const int w = tid >> 6;

  const unsigned nwgx = gridDim.x;
  const unsigned nwg = nwgx * gridDim.y;
  const unsigned bid = blockIdx.y * nwgx + blockIdx.x;
  const unsigned cpx = nwg >> 3;
  const unsigned s = (bid & 7u) * cpx + (bid >> 3);
  const unsigned bandw = (unsigned)grp * nwgx;
  const unsigned band = s / bandw;
  const unsigned rem = s % bandw;
  const int m0 = (int)(band * grp + (rem % grp)) * 128;
  const int n0 = (int)(rem / grp) * 128;

  const int wm = (w >> 1) * 64;
  const int wn = (w & 1) * 64;

  const int srow = l >> 3;                      // 0..7 (row within 8-row chunk)
  const int ksrc = 8 * ((l & 7) ^ srow);        // swizzled source k-offset (elements)
  const int kg = l >> 4;                        // 0..3
  const int lr = l & 15;

  f32x4 acc[4][4];
#pragma unroll
  for (int mi = 0; mi < 4; ++mi)
#pragma unroll
    for (int ni = 0; ni < 4; ++ni) acc[mi][ni] = (f32x4)0.f;

  for (int k0 = 0; k0 < K; k0 += 64) {
#pragma unroll
    for (int j = 0; j < 4; ++j) {
      int c = j * 4 + w;                        // A chunks 0..15 (8 rows each)
      int r = c * 8 + srow;
      async_cp16(&A[(size_t)(m0 + r) * K + k0 + ksrc], &As[c * 512]);
    }
#pragma unroll
    for (int j = 0; j < 4; ++j) {
      int c = j * 4 + w;
      int r = c * 8 + srow;
      async_cp16(&B[(size_t)(n0 + r) * K + k0 + ksrc], &Bs[c * 512]);
    }
    __syncthreads();   // compiler drains vmcnt before barrier
#pragma unroll
    for (int ks = 0; ks < 2; ++ks) {
      bf16x8 af[4], bfr[4];
#pragma unroll
      for (int mi = 0; mi < 4; ++mi) {
        int r = wm + mi * 16 + lr;
        int boff = r * 128 + ((ks * 64 + kg * 16) ^ ((r & 7) << 4));
        af[mi] = *reinterpret_cast<const bf16x8*>(reinterpret_cast<const char*>(As) + boff);
      }
#pragma unroll
      for (int ni = 0; ni < 4; ++ni) {
        int r = wn + ni * 16 + lr;
        int boff = r * 128 + ((ks * 64 + kg * 16) ^ ((r & 7) << 4));
        bfr[ni] = *reinterpret_cast<const bf16x8*>(reinterpret_cast<const char*>(Bs) + boff);
      }
#pragma unroll
      for (int mi = 0; mi < 4; ++mi)
#pragma unroll
        for (int ni = 0; ni < 4; ++ni)
          acc[mi][ni] = __builtin_amdgcn_mfma_f32_16x16x32_bf16(af[mi], bfr[ni], acc[mi][ni], 0, 0, 0);
    }
    __syncthreads();
  }

  const int crow0 = (l >> 4) * 4;
  const int ccol = l & 15;
#pragma unroll
  for (int mi = 0; mi < 4; ++mi) {
#pragma unroll
    for (int ni = 0; ni < 4; ++ni) {
      int col = n0 + wn + ni * 16 + ccol;
      float bv = bias ? bias[col] : 0.f;
#pragma unroll
      for (int j = 0; j < 4; ++j) {
        int row = m0 + wm + mi * 16 + crow0 + j;
        float v = acc[mi][ni][j] + bv;
        if (Cb) Cb[(size_t)row * N + col] = f2bf(v);
        else    C[(size_t)row * N + col] = v;
      }
    }
  }
}

// ---------------- bf16 MFMA NT GEMM, 64x128 tile (for N=1024 GEMMs) ----------------
// 4 waves as 2(M)x2(N), each wave 32x64 (acc[2][4]). Grid (N/128, M/64) -> 2x blocks
// of the 128x128 variant: 2+ blocks/CU so TLP hides the stage->drain latency.
__global__ __launch_bounds__(256) void gemm_bf16_nt64(
    const ushort_t* __restrict__ A,
    const ushort_t* __restrict__ B,
    float* __restrict__ C,
    int N, int K,
    const float* __restrict__ bias, int grp) {
  __shared__ ushort_t As[64 * 64];
  __shared__ ushort_t Bs[128 * 64];
  const int tid = threadIdx.x;
  const int l = tid & 63;
  const int w = tid >> 6;

  const unsigned nwgx = gridDim.x;
  const unsigned nwg = nwgx * gridDim.y;
  const unsigned bid = blockIdx.y * nwgx + blockIdx.x;
  const unsigned cpx = nwg >> 3;
  const unsigned s = (bid & 7u) * cpx + (bid >> 3);
  const unsigned bandw = (unsigned)grp * nwgx;
  const unsigned band = s / bandw;
  const unsigned rem = s % bandw;
  const int m0 = (int)(band * grp + (rem % grp)) * 64;
  const int n0 = (int)(rem / grp) * 128;

  const int wm = (w >> 1) * 32;
  const int wn = (w & 1) * 64;

  const int srow = l >> 3;
  const int ksrc = 8 * ((l & 7) ^ srow);
  const int kg = l >> 4;
  const int lr = l & 15;

  f32x4 acc[2][4];
#pragma unroll
  for (int mi = 0; mi < 2; ++mi)
#pragma unroll
    for (int ni = 0; ni < 4; ++ni) acc[mi][ni] = (f32x4)0.f;

  for (int k0 = 0; k0 < K; k0 += 64) {
#pragma unroll
    for (int j = 0; j < 2; ++j) {               // A: 8 chunks (64 rows)
      int c = j * 4 + w;
      int r = c * 8 + srow;
      async_cp16(&A[(size_t)(m0 + r) * K + k0 + ksrc], &As[c * 512]);
    }
#pragma unroll
    for (int j = 0; j < 4; ++j) {               // B: 16 chunks (128 rows)
      int c = j * 4 + w;
      int r = c * 8 + srow;
      async_cp16(&B[(size_t)(n0 + r) * K + k0 + ksrc], &Bs[c * 512]);
    }
    __syncthreads();
#pragma unroll
    for (int ks = 0; ks < 2; ++ks) {
      bf16x8 af[2], bfr[4];
#pragma unroll
      for (int mi = 0; mi < 2; ++mi) {
        int r = wm + mi * 16 + lr;
        int boff = r * 128 + ((ks * 64 + kg * 16) ^ ((r & 7) << 4));
        af[mi] = *reinterpret_cast<const bf16x8*>(reinterpret_cast<const char*>(As) + boff);
      }
#pragma unroll
      for (int ni = 0; ni < 4; ++ni) {
        int r = wn + ni * 16 + lr;
        int boff = r * 128 + ((ks * 64 + kg * 16) ^ ((r & 7) << 4));
        bfr[ni] = *reinterpret_cast<const bf16x8*>(reinterpret_cast<const char*>(Bs) + boff);
      }
#pragma unroll
      for (int mi = 0; mi < 2; ++mi)
#pragma unroll
        for (int ni = 0; ni < 4; ++ni)
          acc[mi][ni] = __builtin_amdgcn_mfma_f32_16x16x32_bf16(af[mi], bfr[ni], acc[mi][ni], 0, 0, 0);
    }
    __syncthreads();
  }

  const int crow0 = (l >> 4) * 4;
  const int ccol = l & 15;
#pragma unroll
  for (int mi = 0; mi < 2; ++mi) {
#pragma unroll
    for (int ni = 0; ni < 4; ++ni) {
      int col = n0 + wn + ni * 16 + ccol;
      float bv = bias ? bias[col] : 0.f;
#pragma unroll
      for (int j = 0; j < 4; ++j) {
        int row = m0 + wm + mi * 16 + crow0 + j;
        C[(size_t)row * N + col] = acc[mi][ni][j] + bv;
      }
    }
  }
}

// ---------------- fused FFN1 + GEGLU: glu = a * gelu(g), bf16 out ----------------
__global__ __launch_bounds__(256) void gemm_ffn1_glu(
    const ushort_t* __restrict__ A,
    const ushort_t* __restrict__ B,
    ushort_t* __restrict__ O,
    int K,
    const float* __restrict__ bias, int grp) {
  __shared__ ushort_t As[128 * 64];
  __shared__ ushort_t Bs[128 * 64];
  const int tid = threadIdx.x;
  const int l = tid & 63;
  const int w = tid >> 6;

  const unsigned nwgx = gridDim.x;                // 64 col-panels of width 64
  const unsigned nwg = nwgx * gridDim.y;
  const unsigned bid = blockIdx.y * nwgx + blockIdx.x;
  const unsigned cpx = nwg >> 3;
  const unsigned s = (bid & 7u) * cpx + (bid >> 3);
  const unsigned bandw = (unsigned)grp * nwgx;
  const unsigned band = s / bandw;
  const unsigned rem = s % bandw;
  const int m0 = (int)(band * grp + (rem % grp)) * 128;
  const int n0 = (int)(rem / grp) * 64;

  const int wm = (w >> 1) * 64;
  const int wn2 = (w & 1) * 32;

  const int srow = l >> 3;
  const int ksrc = 8 * ((l & 7) ^ srow);
  const int kg = l >> 4;
  const int lr = l & 15;

  f32x4 acc[4][4];
#pragma unroll
  for (int mi = 0; mi < 4; ++mi)
#pragma unroll
    for (int ni = 0; ni < 4; ++ni) acc[mi][ni] = (f32x4)0.f;

  for (int k0 = 0; k0 < K; k0 += 64) {
#pragma unroll
    for (int j = 0; j < 4; ++j) {
      int c = j * 4 + w;
      int r = c * 8 + srow;
      async_cp16(&A[(size_t)(m0 + r) * K + k0 + ksrc], &As[c * 512]);
    }
#pragma unroll
    for (int j = 0; j < 4; ++j) {
      int c = j * 4 + w;
      int gr = (c < 8) ? (n0 + c * 8 + srow)
                       : (FF + n0 + (c - 8) * 8 + srow);
      async_cp16(&B[(size_t)gr * K + k0 + ksrc], &Bs[c * 512]);
    }
    __syncthreads();
#pragma unroll
    for (int ks = 0; ks < 2; ++ks) {
      bf16x8 af[4], bfr[4];
#pragma unroll
      for (int mi = 0; mi < 4; ++mi) {
        int r = wm + mi * 16 + lr;
        int boff = r * 128 + ((ks * 64 + kg * 16) ^ ((r & 7) << 4));
        af[mi] = *reinterpret_cast<const bf16x8*>(reinterpret_cast<const char*>(As) + boff);
      }
#pragma unroll
      for (int ni = 0; ni < 4; ++ni) {
        int r = (ni < 2 ? wn2 + ni * 16 : 64 + wn2 + (ni - 2) * 16) + lr;
        int boff = r * 128 + ((ks * 64 + kg * 16) ^ ((r & 7) << 4));
        bfr[ni] = *reinterpret_cast<const bf16x8*>(reinterpret_cast<const char*>(Bs) + boff);
      }
#pragma unroll
      for (int mi = 0; mi < 4; ++mi)
#pragma unroll
        for (int ni = 0; ni < 4; ++ni)
          acc[mi][ni] = __builtin_amdgcn_mfma_f32_16x16x32_bf16(af[mi], bfr[ni], acc[mi][ni], 0, 0, 0);
    }
    __syncthreads();
  }

  const int crow0 = (l >> 4) * 4;
  const int ccol = l & 15;
#pragma unroll
  for (int mi = 0; mi < 4; ++mi) {
#pragma unroll
    for (int ni = 0; ni < 2; ++ni) {
      int col = n0 + wn2 + ni * 16 + ccol;
      float ba = bias[col];
      float bg = bias[FF + col];
#pragma unroll
      for (int j = 0; j < 4; ++j) {
        int row = m0 + wm + mi * 16 + crow0 + j;
        float a = acc[mi][ni][j] + ba;
        float g = acc[mi][ni + 2][j] + bg;
        float ge = 0.5f * g * (1.f + erff(g * 0.70710678118654752f));
        O[(size_t)row * FF + col] = f2bf(a * ge);
      }
    }
  }
}

// ---------------- fp32 NT GEMM (dt_proj) ----------------
__global__ __launch_bounds__(256) void gemm_nt(
    const float* __restrict__ A, int lda,
    const float* __restrict__ B, int ldb,
    float* __restrict__ C, int ldc,
    int N, int K,
    const float* __restrict__ bias, int act) {
  __shared__ __align__(16) float Asf[16][68];
  __shared__ __align__(16) float Bsf[16][68];
  const int tx = threadIdx.x;
  const int ty = threadIdx.y;
  const int tid = ty * 16 + tx;
  const int m0 = blockIdx.y * 64;
  const int n0 = blockIdx.x * 64;
  const int lrow = tid >> 2;
  const int lk = (tid & 3) * 4;

  float acc[4][4] = {{0.f}};

  for (int k0 = 0; k0 < K; k0 += 16) {
    float4 av, bv;
    {
      const float* ap = A + (size_t)(m0 + lrow) * lda + k0 + lk;
      av = *reinterpret_cast<const float4*>(ap);
    }
    int brow = n0 + lrow;
    if (brow < N) {
      const float* bp = B + (size_t)brow * ldb + k0 + lk;
      bv = *reinterpret_cast<const float4*>(bp);
    } else {
      bv = make_float4(0.f, 0.f, 0.f, 0.f);
    }
    __syncthreads();
    Asf[lk + 0][lrow] = av.x; Asf[lk + 1][lrow] = av.y;
    Asf[lk + 2][lrow] = av.z; Asf[lk + 3][lrow] = av.w;
    Bsf[lk + 0][lrow] = bv.x; Bsf[lk + 1][lrow] = bv.y;
    Bsf[lk + 2][lrow] = bv.z; Bsf[lk + 3][lrow] = bv.w;
    __syncthreads();
#pragma unroll
    for (int k = 0; k < 16; ++k) {
      const float4 a4 = *reinterpret_cast<const float4*>(&Asf[k][ty * 4]);
      const float4 b4 = *reinterpret_cast<const float4*>(&Bsf[k][tx * 4]);
      float a[4] = {a4.x, a4.y, a4.z, a4.w};
      float bb[4] = {b4.x, b4.y, b4.z, b4.w};
#pragma unroll
      for (int i = 0; i < 4; ++i)
#pragma unroll
        for (int j = 0; j < 4; ++j)
          acc[i][j] = fmaf(a[i], bb[j], acc[i][j]);
    }
  }

#pragma unroll
  for (int i = 0; i < 4; ++i) {
    int m = m0 + ty * 4 + i;
#pragma unroll
    for (int j = 0; j < 4; ++j) {
      int n = n0 + tx * 4 + j;
      if (n < N) {
        float v = acc[i][j];
        if (bias) v += bias[n];
        if (act == 1) v = (v > 20.f) ? v : log1pf(__expf(v));
        C[(size_t)m * ldc + n] = v;
      }
    }
  }
}

// ---------------- x_proj split-K stage 1 ----------------
__global__ __launch_bounds__(256) void xproj_partial(
    const float* __restrict__ A,   // xc [4096, 2048]
    const float* __restrict__ W,   // [96, 2048]
    float* __restrict__ pbuf) {    // [XP_KS, 4096, 96]
  __shared__ __align__(16) float As[64][68];
  __shared__ __align__(16) float Wsd[96][68];
  const int ks = blockIdx.x;
  const int mb = blockIdx.y;
  const int tid = threadIdx.x;
  const int r0 = (tid >> 4) * 4;        // 0..60
  const int c0 = (tid & 15) * 6;        // 0..90

  float acc[4][6];
#pragma unroll
  for (int i = 0; i < 4; ++i)
#pragma unroll
    for (int j = 0; j < 6; ++j) acc[i][j] = 0.f;

  for (int k0 = 0; k0 < XP_KSTEP; k0 += 64) {
    const int kbase = ks * XP_KSTEP + k0;
    __syncthreads();
    {
      int r = tid >> 2, c = (tid & 3) * 16;
      const float* src = A + (size_t)(mb * 64 + r) * D_INNER + kbase + c;
#pragma unroll
      for (int q = 0; q < 4; ++q)
        *reinterpret_cast<float4*>(&As[r][c + q * 4]) =
            *reinterpret_cast<const float4*>(src + q * 4);
    }
#pragma unroll
    for (int q = 0; q < 6; ++q) {
      int f = q * 256 + tid;
      int wr = f >> 4;
      int wc = (f & 15) * 4;
      *reinterpret_cast<float4*>(&Wsd[wr][wc]) =
          *reinterpret_cast<const float4*>(&W[(size_t)wr * D_INNER + kbase + wc]);
    }
    __syncthreads();
#pragma unroll 16
    for (int k = 0; k < 64; ++k) {
      float a[4], wv[6];
#pragma unroll
      for (int i = 0; i < 4; ++i) a[i] = As[r0 + i][k];
#pragma unroll
      for (int j = 0; j < 6; ++j) wv[j] = Wsd[c0 + j][k];
#pragma unroll
      for (int i = 0; i < 4; ++i)
#pragma unroll
        for (int j = 0; j < 6; ++j)
          acc[i][j] = fmaf(a[i], wv[j], acc[i][j]);
    }
  }

  float* dst = pbuf + ((size_t)ks * ROWS + mb * 64) * 96;
#pragma unroll
  for (int i = 0; i < 4; ++i)
#pragma unroll
    for (int j = 0; j < 6; ++j)
      dst[(size_t)(r0 + i) * 96 + c0 + j] = acc[i][j];
}

// ---------------- x_proj split-K stage 2: reduce ----------------
__global__ __launch_bounds__(256) void xproj_reduce(
    const float* __restrict__ pbuf, float* __restrict__ xdbl) {
  int i = blockIdx.x * 256 + threadIdx.x;   // 0 .. ROWS*96-1
  float s = 0.f;
#pragma unroll
  for (int ks = 0; ks < XP_KS; ++ks)
    s += pbuf[(size_t)ks * (ROWS * 96) + i];
  xdbl[i] = s;
}

// ---------------- causal depthwise conv (k=4) + SiLU, bf16 in / fp32 out ----------------
__global__ __launch_bounds__(256) void conv_silu_kernel(
    const ushort_t* __restrict__ xzb, float* __restrict__ xc,
    const float* __restrict__ cw, const float* __restrict__ cb) {
  int t = (blockIdx.x * 256 + threadIdx.x) * 4;
  if (t >= ROWS * D_INNER) return;
  int d = t & (D_INNER - 1);
  int row = t >> 11;
  int l = row & (SEQ - 1);
  float acc[4];
#pragma unroll
  for (int q = 0; q < 4; ++q) acc[q] = cb[d + q];
#pragma unroll
  for (int j = 0; j < 4; ++j) {
    int ls = l - 3 + j;
    if (ls >= 0) {
      ushort4 uv = *reinterpret_cast<const ushort4*>(
          xzb + (size_t)(row - 3 + j) * (2 * D_INNER) + d);
      acc[0] = fmaf(cw[(d + 0) * 4 + j], bf2f(uv.x), acc[0]);
      acc[1] = fmaf(cw[(d + 1) * 4 + j], bf2f(uv.y), acc[1]);
      acc[2] = fmaf(cw[(d + 2) * 4 + j], bf2f(uv.z), acc[2]);
      acc[3] = fmaf(cw[(d + 3) * 4 + j], bf2f(uv.w), acc[3]);
    }
  }
  float4 o;
  o.x = acc[0] * sigmoidf_(acc[0]);
  o.y = acc[1] * sigmoidf_(acc[1]);
  o.z = acc[2] * sigmoidf_(acc[2]);
  o.w = acc[3] * sigmoidf_(acc[3]);
  *reinterpret_cast<float4*>(xc + t) = o;
}

// ================= chunked selective scan (CS=32, LDS B/C, 4-deep prefetch) =================
__global__ __launch_bounds__(256) void scan_pass1(
    const float* __restrict__ delta,
    const float* __restrict__ xc,
    const float* __restrict__ xdbl,
    const float* __restrict__ A_log,
    float* __restrict__ harr,
    float* __restrict__ dtsum) {
  __shared__ __align__(16) float Bls[CS][16];
  int gid = blockIdx.x * 256 + threadIdx.x;
  int d = gid & (D_INNER - 1);
  int bc = gid >> 11;
  int c = bc & (NC - 1);
  int b = bc >> NC_LOG;
  const size_t r0 = (size_t)b * SEQ + (size_t)c * CS;

  if (threadIdx.x < CS * 4) {
    int sl = threadIdx.x >> 2, sf = (threadIdx.x & 3) * 4;
    *reinterpret_cast<f32x4*>(&Bls[sl][sf]) =
        *reinterpret_cast<const f32x4*>(xdbl + (r0 + sl) * 96 + 64 + sf);
  }

  float Av2[D_STATE];
#pragma unroll
  for (int n = 0; n < D_STATE; ++n)
    Av2[n] = -__expf(A_log[(size_t)d * D_STATE + n]) * LOG2E;
  float h[D_STATE];
#pragma unroll
  for (int n = 0; n < D_STATE; ++n) h[n] = 0.f;
  float dts = 0.f;

  const float* drow = delta + r0 * D_INNER + d;
  const float* urow = xc + r0 * D_INNER + d;

  float pdt[4], pu[4];
#pragma unroll
  for (int g = 0; g < 4; ++g) {
    pdt[g] = drow[(size_t)g * D_INNER];
    pu[g]  = urow[(size_t)g * D_INNER];
  }
  __syncthreads();

  for (int l0 = 0; l0 < CS; l0 += 4) {
    float cdt[4], cu[4];
#pragma unroll
    for (int g = 0; g < 4; ++g) { cdt[g] = pdt[g]; cu[g] = pu[g]; }
    if (l0 + 4 < CS) {
#pragma unroll
      for (int g = 0; g < 4; ++g) {
        pdt[g] = drow[(size_t)(l0 + 4 + g) * D_INNER];
        pu[g]  = urow[(size_t)(l0 + 4 + g) * D_INNER];
      }
    }
#pragma unroll
    for (int g = 0; g < 4; ++g) {
      int l = l0 + g;
      f32x4 B0 = *reinterpret_cast<const f32x4*>(&Bls[l][0]);
      f32x4 B1 = *reinterpret_cast<const f32x4*>(&Bls[l][4]);
      f32x4 B2 = *reinterpret_cast<const f32x4*>(&Bls[l][8]);
      f32x4 B3 = *reinterpret_cast<const f32x4*>(&Bls[l][12]);
      float du = cdt[g] * cu[g];
      dts += cdt[g];
      float Bsr[D_STATE] = {B0[0],B0[1],B0[2],B0[3], B1[0],B1[1],B1[2],B1[3],
                            B2[0],B2[1],B2[2],B2[3], B3[0],B3[1],B3[2],B3[3]};
#pragma unroll
      for (int n = 0; n < D_STATE; ++n) {
        float dA = __builtin_amdgcn_exp2f(cdt[g] * Av2[n]);
        h[n] = dA * h[n] + du * Bsr[n];
      }
    }
  }
#pragma unroll
  for (int n = 0; n < D_STATE; ++n)
    harr[((size_t)bc * D_STATE + n) * D_INNER + d] = h[n];
  dtsum[(size_t)bc * D_INNER + d] = dts;
}

// pass2: sequential combine over NC chunks; IN-PLACE: harr[c] := h0 for chunk c
__global__ __launch_bounds__(256) void scan_pass2(
    float* __restrict__ harr,
    const float* __restrict__ dtsum,
    const float* __restrict__ A_log) {
  int gid = blockIdx.x * 256 + threadIdx.x;
  int d = gid & (D_INNER - 1);
  int bn = gid >> 11;
  int n = bn & (D_STATE - 1);
  int b = bn >> 4;
  float Av2 = -__expf(A_log[(size_t)d * D_STATE + n]) * LOG2E;
  float h = 0.f;
  for (int c = 0; c < NC; ++c) {
    size_t bc = (size_t)b * NC + c;
    size_t idx = (bc * D_STATE + n) * D_INNER + d;
    float he = harr[idx];
    harr[idx] = h;
    float P = __builtin_amdgcn_exp2f(Av2 * dtsum[bc * D_INNER + d]);
    h = P * h + he;
  }
}

// pass3: rescan with true h0, y = h·C + u*D, gate silu(z) -> bf16
__global__ __launch_bounds__(256) void scan_pass3(
    const float* __restrict__ delta,
    const float* __restrict__ xc,
    ushort_t* __restrict__ ybf,
    const float* __restrict__ xdbl,
    const ushort_t* __restrict__ xzb,
    const float* __restrict__ A_log,
    const float* __restrict__ Dp,
    const float* __restrict__ harr) {
  __shared__ __align__(16) float BCls[CS][32];   // B at [0..16), C at [16..32)
  int gid = blockIdx.x * 256 + threadIdx.x;
  int d = gid & (D_INNER - 1);
  int bc = gid >> 11;
  int c = bc & (NC - 1);
  int b = bc >> NC_LOG;
  const size_t r0 = (size_t)b * SEQ + (size_t)c * CS;

  {
    int sl = threadIdx.x >> 3, sf = (threadIdx.x & 7) * 4;
    *reinterpret_cast<f32x4*>(&BCls[sl][sf]) =
        *reinterpret_cast<const f32x4*>(xdbl + (r0 + sl) * 96 + 64 + sf);
  }

  float Av2[D_STATE];
#pragma unroll
  for (int n = 0; n < D_STATE; ++n)
    Av2[n] = -__expf(A_log[(size_t)d * D_STATE + n]) * LOG2E;
  const float Dd = Dp[d];
  float h[D_STATE];
#pragma unroll
  for (int n = 0; n < D_STATE; ++n)
    h[n] = harr[((size_t)bc * D_STATE + n) * D_INNER + d];

  const float* drow = delta + r0 * D_INNER + d;
  const float* urow = xc + r0 * D_INNER + d;
  const ushort_t* zrow = xzb + r0 * (2 * D_INNER) + D_INNER + d;
  ushort_t* yrow = ybf + r0 * D_INNER + d;

  float pdt[4], pu[4], pz[4];
#pragma unroll
  for (int g = 0; g < 4; ++g) {
    pdt[g] = drow[(size_t)g * D_INNER];
    pu[g]  = urow[(size_t)g * D_INNER];
    pz[g]  = bf2f(zrow[(size_t)g * (2 * D_INNER)]);
  }
  __syncthreads();

  for (int l0 = 0; l0 < CS; l0 += 4) {
    float cdt[4], cu[4], cz[4];
#pragma unroll
    for (int g = 0; g < 4; ++g) { cdt[g] = pdt[g]; cu[g] = pu[g]; cz[g] = pz[g]; }
    if (l0 + 4 < CS) {
#pragma unroll
      for (int g = 0; g < 4; ++g) {
        pdt[g] = drow[(size_t)(l0 + 4 + g) * D_INNER];
        pu[g]  = urow[(size_t)(l0 + 4 + g) * D_INNER];
        pz[g]  = bf2f(zrow[(size_t)(l0 + 4 + g) * (2 * D_INNER)]);
      }
    }
#pragma unroll
    for (int g = 0; g < 4; ++g) {
      int l = l0 + g;
      f32x4 B0 = *reinterpret_cast<const f32x4*>(&BCls[l][0]);
      f32x4 B1 = *reinterpret_cast<const f32x4*>(&BCls[l][4]);
      f32x4 B2 = *reinterpret_cast<const f32x4*>(&BCls[l][8]);
      f32x4 B3 = *reinterpret_cast<const f32x4*>(&BCls[l][12]);
      f32x4 C0 = *reinterpret_cast<const f32x4*>(&BCls[l][16]);
      f32x4 C1 = *reinterpret_cast<const f32x4*>(&BCls[l][20]);
      f32x4 C2 = *reinterpret_cast<const f32x4*>(&BCls[l][24]);
      f32x4 C3 = *reinterpret_cast<const f32x4*>(&BCls[l][28]);
      float du = cdt[g] * cu[g];
      float Bsr[D_STATE] = {B0[0],B0[1],B0[2],B0[3], B1[0],B1[1],B1[2],B1[3],
                            B2[0],B2[1],B2[2],B2[3], B3[0],B3[1],B3[2],B3[3]};
      float Csr[D_STATE] = {C0[0],C0[1],C0[2],C0[3], C1[0],C1[1],C1[2],C1[3],
                            C2[0],C2[1],C2[2],C2[3], C3[0],C3[1],C3[2],C3[3]};
      float y = 0.f;
#pragma unroll
      for (int n = 0; n < D_STATE; ++n) {
        float dA = __builtin_amdgcn_exp2f(cdt[g] * Av2[n]);
        h[n] = dA * h[n] + du * Bsr[n];
        y = fmaf(h[n], Csr[n], y);
      }
      y = fmaf(cu[g], Dd, y);
      yrow[(size_t)l * D_INNER] = f2bf(y * (cz[g] * sigmoidf_(cz[g])));
    }
  }
}

extern "C" void kernel_launch(void* const* d_in, const int* in_sizes, int n_in,
                              void* d_out, int out_size, void* d_ws, size_t ws_size,
                              hipStream_t stream) {
  const float* x         = (const float*)d_in[0];
  const float* in_proj_w = (const float*)d_in[1];
  const float* conv_w    = (const float*)d_in[2];
  const float* conv_b    = (const float*)d_in[3];
  const float* x_proj_w  = (const float*)d_in[4];
  const float* dt_proj_w = (const float*)d_in[5];
  const float* dt_proj_b = (const float*)d_in[6];
  const float* A_log     = (const float*)d_in[7];
  const float* Dp        = (const float*)d_in[8];
  const float* out_proj_w= (const float*)d_in[9];
  const float* rms_w     = (const float*)d_in[10];
  const float* ln_w      = (const float*)d_in[11];
  const float* ln_b      = (const float*)d_in[12];
  const float* ff_w1     = (const float*)d_in[13];
  const float* ff_b1     = (const float*)d_in[14];
  const float* ff_w2     = (const float*)d_in[15];
  const float* ff_b2     = (const float*)d_in[16];
  float* out = (float*)d_out;

  float* ws = (float*)d_ws;
  // ---- layout (float-word offsets); total end = 65,536,000 w = 250.0 MiB ----
  float* res     = ws;                              // [0, 4194304)
  float* hbuf    = ws + 4194304;                    // [4194304, 8388608)
  float* xdbl    = ws + 8388608;                    // [8388608, 8781824)
  float* dtsum   = ws + 4194304;                    // overlays hbuf; B*NC*D_INNER = 262,144 w
  ushort_t* hbuf_bf = (ushort_t*)(ws + 8912896);    // 4M ushorts [8912896, 11010048)
  float*    pbuf    = ws + 11010048;                // x_proj partials 3.1M w
  ushort_t* y_bf    = (ushort_t*)(ws + 15204352);   // 8M ushorts [15204352, 19398656)
  ushort_t* glu_bf  = (ushort_t*)(ws + 11010048);   // overlays pbuf+y_bf (FFN phase)
  float* big   = ws + 19398656;                     // [19398656, 52953088)
  ushort_t* xz_bf = (ushort_t*)big;                 // 16.7M ushorts = 8,388,608 w (layer phase)
  float* xc    = big + 8388608;                     // 8,388,608 w
  float* delta = big + 16777216;                    // 8,388,608 w
  float* harr  = big + 25165824;                    // B*NC*16*D_INNER = 4,194,304 w
  float* op_out= big;                               // 4M w (overlays xz_bf after scan)
  ushort_t* nrm_bf = (ushort_t*)delta;              // 4M ushorts (dead before dt_proj writes)
  ushort_t* in_w_bf  = (ushort_t*)(ws + 52953088);  // 8M ushorts [52953088, 57147392)
  ushort_t* out_w_bf = (ushort_t*)(ws + 57147392);  // 4M ushorts [57147392, 59244544)
  ushort_t* ff1_bf   = (ushort_t*)(ws + 59244544);  // 8M ushorts [59244544, 63438848)
  ushort_t* ff2_bf   = (ushort_t*)(ws + 63438848);  // 4M ushorts [63438848, 65536000)

  dim3 tb(16, 16);

  // weight conversions (every call; deterministic)
  f2b_kernel<<<8192, 256, 0, stream>>>(in_proj_w, in_w_bf, 8388608);
  f2b_kernel<<<4096, 256, 0, stream>>>(out_proj_w, out_w_bf, 4194304);
  f2b_kernel<<<8192, 256, 0, stream>>>(ff_w1, ff1_bf, 8388608);
  f2b_kernel<<<4096, 256, 0, stream>>>(ff_w2, ff2_bf, 4194304);

  for (int i = 0; i < DEPTH; ++i) {
    const float* cw    = conv_w + (size_t)i * D_INNER * D_CONV;
    const float* cb    = conv_b + (size_t)i * D_INNER;
    const float* xp_w  = x_proj_w + (size_t)i * 96 * D_INNER;
    const float* dtp_w = dt_proj_w + (size_t)i * D_INNER * DT_RANK;
    const float* dtp_b = dt_proj_b + (size_t)i * D_INNER;
    const float* Alg   = A_log + (size_t)i * D_INNER * D_STATE;
    const float* Di    = Dp + (size_t)i * D_INNER;

    res_rms_kernel<<<ROWS, 256, 0, stream>>>(i == 0 ? x : res, i == 0 ? nullptr : hbuf,
                                             res, nrm_bf, rms_w + (size_t)i * DIM);
    // in_proj: xz_bf[4096,4096] = nrm * in_w^T  (bf16 MFMA, bf16 out)
    gemm_bf16_nt<<<dim3(32, 32), 256, 0, stream>>>(
        nrm_bf, in_w_bf + (size_t)i * 4194304, nullptr, xz_bf, 2 * D_INNER, DIM,
        nullptr, 16);
    conv_silu_kernel<<<(ROWS * D_INNER / 4) / 256, 256, 0, stream>>>(xz_bf, xc, cw, cb);
    // x_proj: split-K two-stage
    xproj_partial<<<dim3(XP_KS, 64), 256, 0, stream>>>(xc, xp_w, pbuf);
    xproj_reduce<<<(ROWS * 96) / 256, 256, 0, stream>>>(pbuf, xdbl);
    gemm_nt<<<dim3(32, 64), tb, 0, stream>>>(xdbl, 96, dtp_w, DT_RANK, delta, D_INNER,
                                             D_INNER, DT_RANK, dtp_b, 1);
    scan_pass1<<<(BATCH * NC * D_INNER) / 256, 256, 0, stream>>>(delta, xc, xdbl, Alg,
                                                                 harr, dtsum);
    scan_pass2<<<(BATCH * D_STATE * D_INNER) / 256, 256, 0, stream>>>(harr, dtsum, Alg);
    scan_pass3<<<(BATCH * NC * D_INNER) / 256, 256, 0, stream>>>(delta, xc, y_bf, xdbl,
                                                                 xz_bf, Alg, Di, harr);
    // out_proj: op_out[4096,1024] = y * o_w^T  (64x128-tile bf16 MFMA); xz dead now
    gemm_bf16_nt64<<<dim3(8, 64), 256, 0, stream>>>(
        y_bf, out_w_bf + (size_t)i * 2097152, op_out, DIM, D_INNER, nullptr, 8);
    layernorm_kernel<<<ROWS, 256, 0, stream>>>(op_out, hbuf, hbuf_bf,
                                               ln_w + (size_t)i * DIM, ln_b + (size_t)i * DIM);
  }

  // FFN1 + GEGLU fused: glu_bf[4096,4096] = a*gelu(g), a|g = hbuf*ff_w1^T + b1
  gemm_ffn1_glu<<<dim3(64, 32), 256, 0, stream>>>(hbuf_bf, ff1_bf, glu_bf, DIM,
                                                  ff_b1, 16);
  // FFN2: out = glu * ff_w2^T + b2  (64x128-tile bf16 MFMA)
  gemm_bf16_nt64<<<dim3(8, 64), 256, 0, stream>>>(glu_bf, ff2_bf, out, DIM, FF,
                                                  ff_b2, 8);
}

// Round 14
// 759.871 us; speedup vs baseline: 1.1416x; 1.0405x over previous
//
#include <hip/hip_runtime.h>
#include <cstdint>
#include <cstddef>

#define DIM     1024
#define SEQ     2048
#define BATCH   2
#define DEPTH   2
#define D_INNER 2048
#define D_STATE 16
#define D_CONV  4
#define DT_RANK 64
#define FF      4096
#define ROWS    (BATCH*SEQ)   // 4096
#define EPS     1e-5f

#define CS      32            // scan chunk size
#define NC      (SEQ/CS)      // 64 chunks
#define NC_LOG  6

#define XP_KS    8            // x_proj k-split
#define XP_KSTEP (D_INNER/XP_KS)  // 256

#define LOG2E 1.44269504088896f

typedef unsigned short ushort_t;
typedef short bf16x8 __attribute__((ext_vector_type(8)));
typedef float f32x4  __attribute__((ext_vector_type(4)));

__device__ __forceinline__ float sigmoidf_(float x) { return 1.f / (1.f + __expf(-x)); }

// bf16 <-> fp32
__device__ __forceinline__ ushort_t f2bf(float x) {
  unsigned int u = __float_as_uint(x);
  u += 0x7fffu + ((u >> 16) & 1u);
  return (ushort_t)(u >> 16);
}
__device__ __forceinline__ float bf2f(ushort_t u) {
  return __uint_as_float((unsigned)u << 16);
}

// async global->LDS 16B (wave-uniform LDS base + lane*16)
__device__ __forceinline__ void async_cp16(const void* g, void* lds) {
  __builtin_amdgcn_global_load_lds(
      (const __attribute__((address_space(1))) unsigned int*)g,
      (__attribute__((address_space(3))) unsigned int*)lds, 16, 0, 0);
}

// ---------------- block-wide reduction ----------------
__device__ __forceinline__ float2 block_sum2(float a, float b) {
#pragma unroll
  for (int off = 32; off > 0; off >>= 1) {
    a += __shfl_down(a, off, 64);
    b += __shfl_down(b, off, 64);
  }
  __shared__ float sa[4], sb[4];
  __syncthreads();
  if ((threadIdx.x & 63) == 0) { int w = threadIdx.x >> 6; sa[w] = a; sb[w] = b; }
  __syncthreads();
  return make_float2(sa[0] + sa[1] + sa[2] + sa[3], sb[0] + sb[1] + sb[2] + sb[3]);
}

// ---------------- residual add + RMSNorm (bf16 normed out) ----------------
__global__ __launch_bounds__(256) void res_rms_kernel(
    const float* __restrict__ xin,
    float* __restrict__ res, ushort_t* __restrict__ nrm, const float* __restrict__ w) {
  int row = blockIdx.x;
  const float* xr = xin + (size_t)row * DIM;
  float* rr = res + (size_t)row * DIM;
  ushort_t* nr = nrm + (size_t)row * DIM;
  float v[4]; float ss = 0.f;
#pragma unroll
  for (int i = 0; i < 4; ++i) {
    int j = threadIdx.x + i * 256;
    float t = xr[j];
    v[i] = t; rr[j] = t; ss += t * t;
  }
  float2 s = block_sum2(ss, 0.f);
  float rstd = rsqrtf(s.x * (1.f / DIM) + EPS);
#pragma unroll
  for (int i = 0; i < 4; ++i) {
    int j = threadIdx.x + i * 256;
    nr[j] = f2bf(v[i] * rstd * w[j]);
  }
}

// ---------------- fused LayerNorm -> residual add -> RMSNorm (bf16 out) ----------------
// t = LN(in)*lw+lb; res += t; nrm = RMS(res)*rw
__global__ __launch_bounds__(256) void ln_res_rms_kernel(
    const float* __restrict__ in, float* __restrict__ res,
    const float* __restrict__ lw, const float* __restrict__ lb,
    const float* __restrict__ rw, ushort_t* __restrict__ nrm) {
  int row = blockIdx.x;
  const float* xr = in + (size_t)row * DIM;
  float* rr = res + (size_t)row * DIM;
  ushort_t* nr = nrm + (size_t)row * DIM;
  float v[4]; float s1 = 0.f, s2 = 0.f;
#pragma unroll
  for (int i = 0; i < 4; ++i) {
    int j = threadIdx.x + i * 256;
    float t = xr[j];
    v[i] = t; s1 += t; s2 += t * t;
  }
  float2 s = block_sum2(s1, s2);
  float mean = s.x * (1.f / DIM);
  float var = s.y * (1.f / DIM) - mean * mean;
  float rstd = rsqrtf(var + EPS);
  float t4[4]; float ss = 0.f;
#pragma unroll
  for (int i = 0; i < 4; ++i) {
    int j = threadIdx.x + i * 256;
    float o = (v[i] - mean) * rstd * lw[j] + lb[j];
    float t = rr[j] + o;
    rr[j] = t;
    t4[i] = t; ss += t * t;
  }
  float2 s2v = block_sum2(ss, 0.f);
  float rstd2 = rsqrtf(s2v.x * (1.f / DIM) + EPS);
#pragma unroll
  for (int i = 0; i < 4; ++i) {
    int j = threadIdx.x + i * 256;
    nr[j] = f2bf(t4[i] * rstd2 * rw[j]);
  }
}

// ---------------- final LayerNorm (bf16 out only) ----------------
__global__ __launch_bounds__(256) void ln_final_kernel(
    const float* __restrict__ in, ushort_t* __restrict__ outb,
    const float* __restrict__ w, const float* __restrict__ b) {
  int row = blockIdx.x;
  const float* xr = in + (size_t)row * DIM;
  ushort_t* obrow = outb + (size_t)row * DIM;
  float v[4]; float s1 = 0.f, s2 = 0.f;
#pragma unroll
  for (int i = 0; i < 4; ++i) {
    int j = threadIdx.x + i * 256;
    float t = xr[j];
    v[i] = t; s1 += t; s2 += t * t;
  }
  float2 s = block_sum2(s1, s2);
  float mean = s.x * (1.f / DIM);
  float var = s.y * (1.f / DIM) - mean * mean;
  float rstd = rsqrtf(var + EPS);
#pragma unroll
  for (int i = 0; i < 4; ++i) {
    int j = threadIdx.x + i * 256;
    obrow[j] = f2bf((v[i] - mean) * rstd * w[j] + b[j]);
  }
}

// ---------------- fused fp32 -> bf16 conversion for all 4 weight tensors ----------------
// segments (elements): w0 8388608 | w1 4194304 | w2 8388608 | w3 4194304
__global__ __launch_bounds__(256) void f2b_all(
    const float* __restrict__ w0, ushort_t* __restrict__ d0,
    const float* __restrict__ w1, ushort_t* __restrict__ d1,
    const float* __restrict__ w2, ushort_t* __restrict__ d2,
    const float* __restrict__ w3, ushort_t* __restrict__ d3) {
  int i = (blockIdx.x * 256 + threadIdx.x) * 4;
  const float* s; ushort_t* d; int off;
  if (i < 8388608)        { s = w0; d = d0; off = i; }
  else if (i < 12582912)  { s = w1; d = d1; off = i - 8388608; }
  else if (i < 20971520)  { s = w2; d = d2; off = i - 12582912; }
  else                    { s = w3; d = d3; off = i - 20971520; }
  float4 v = *reinterpret_cast<const float4*>(s + off);
  d[off + 0] = f2bf(v.x); d[off + 1] = f2bf(v.y);
  d[off + 2] = f2bf(v.z); d[off + 3] = f2bf(v.w);
}

// ---------------- bf16 MFMA NT GEMM: C = A[M,K] * B[N,K]^T (+bias) ----------------
// 128x128 tile, BK=64, 4 waves (2x2), 16x16x32 MFMA, single-buffer LDS.
// Block mapping: XCD-chunk swizzle (T1) then CUTLASS-style grouped supertile.
__global__ __launch_bounds__(256) void gemm_bf16_nt(
    const ushort_t* __restrict__ A,
    const ushort_t* __restrict__ B,
    float* __restrict__ C,
    ushort_t* __restrict__ Cb,
    int N, int K,
    const float* __restrict__ bias, int grp) {
  __shared__ ushort_t As[128 * 64];
  __shared__ ushort_t Bs[128 * 64];
  const int tid = threadIdx.x;
  const int l = tid & 63;
  const int w = tid >> 6;

  const unsigned nwgx = gridDim.x;
  const unsigned nwg = nwgx * gridDim.y;
  const unsigned bid = blockIdx.y * nwgx + blockIdx.x;
  const unsigned cpx = nwg >> 3;
  const unsigned s = (bid & 7u) * cpx + (bid >> 3);
  const unsigned bandw = (unsigned)grp * nwgx;
  const unsigned band = s / bandw;
  const unsigned rem = s % bandw;
  const int m0 = (int)(band * grp + (rem % grp)) * 128;
  const int n0 = (int)(rem / grp) * 128;

  const int wm = (w >> 1) * 64;
  const int wn = (w & 1) * 64;

  const int srow = l >> 3;                      // 0..7 (row within 8-row chunk)
  const int ksrc = 8 * ((l & 7) ^ srow);        // swizzled source k-offset (elements)
  const int kg = l >> 4;                        // 0..3
  const int lr = l & 15;

  f32x4 acc[4][4];
#pragma unroll
  for (int mi = 0; mi < 4; ++mi)
#pragma unroll
    for (int ni = 0; ni < 4; ++ni) acc[mi][ni] = (f32x4)0.f;

  for (int k0 = 0; k0 < K; k0 += 64) {
#pragma unroll
    for (int j = 0; j < 4; ++j) {
      int c = j * 4 + w;                        // A chunks 0..15 (8 rows each)
      int r = c * 8 + srow;
      async_cp16(&A[(size_t)(m0 + r) * K + k0 + ksrc], &As[c * 512]);
    }
#pragma unroll
    for (int j = 0; j < 4; ++j) {
      int c = j * 4 + w;
      int r = c * 8 + srow;
      async_cp16(&B[(size_t)(n0 + r) * K + k0 + ksrc], &Bs[c * 512]);
    }
    __syncthreads();   // compiler drains vmcnt before barrier
#pragma unroll
    for (int ks = 0; ks < 2; ++ks) {
      bf16x8 af[4], bfr[4];
#pragma unroll
      for (int mi = 0; mi < 4; ++mi) {
        int r = wm + mi * 16 + lr;
        int boff = r * 128 + ((ks * 64 + kg * 16) ^ ((r & 7) << 4));
        af[mi] = *reinterpret_cast<const bf16x8*>(reinterpret_cast<const char*>(As) + boff);
      }
#pragma unroll
      for (int ni = 0; ni < 4; ++ni) {
        int r = wn + ni * 16 + lr;
        int boff = r * 128 + ((ks * 64 + kg * 16) ^ ((r & 7) << 4));
        bfr[ni] = *reinterpret_cast<const bf16x8*>(reinterpret_cast<const char*>(Bs) + boff);
      }
#pragma unroll
      for (int mi = 0; mi < 4; ++mi)
#pragma unroll
        for (int ni = 0; ni < 4; ++ni)
          acc[mi][ni] = __builtin_amdgcn_mfma_f32_16x16x32_bf16(af[mi], bfr[ni], acc[mi][ni], 0, 0, 0);
    }
    __syncthreads();
  }

  const int crow0 = (l >> 4) * 4;
  const int ccol = l & 15;
#pragma unroll
  for (int mi = 0; mi < 4; ++mi) {
#pragma unroll
    for (int ni = 0; ni < 4; ++ni) {
      int col = n0 + wn + ni * 16 + ccol;
      float bv = bias ? bias[col] : 0.f;
#pragma unroll
      for (int j = 0; j < 4; ++j) {
        int row = m0 + wm + mi * 16 + crow0 + j;
        float v = acc[mi][ni][j] + bv;
        if (Cb) Cb[(size_t)row * N + col] = f2bf(v);
        else    C[(size_t)row * N + col] = v;
      }
    }
  }
}

// ---------------- bf16 MFMA NT GEMM, 64x128 tile (for N=1024 GEMMs) ----------------
__global__ __launch_bounds__(256) void gemm_bf16_nt64(
    const ushort_t* __restrict__ A,
    const ushort_t* __restrict__ B,
    float* __restrict__ C,
    int N, int K,
    const float* __restrict__ bias, int grp) {
  __shared__ ushort_t As[64 * 64];
  __shared__ ushort_t Bs[128 * 64];
  const int tid = threadIdx.x;
  const int l = tid & 63;
  const int w = tid >> 6;

  const unsigned nwgx = gridDim.x;
  const unsigned nwg = nwgx * gridDim.y;
  const unsigned bid = blockIdx.y * nwgx + blockIdx.x;
  const unsigned cpx = nwg >> 3;
  const unsigned s = (bid & 7u) * cpx + (bid >> 3);
  const unsigned bandw = (unsigned)grp * nwgx;
  const unsigned band = s / bandw;
  const unsigned rem = s % bandw;
  const int m0 = (int)(band * grp + (rem % grp)) * 64;
  const int n0 = (int)(rem / grp) * 128;

  const int wm = (w >> 1) * 32;
  const int wn = (w & 1) * 64;

  const int srow = l >> 3;
  const int ksrc = 8 * ((l & 7) ^ srow);
  const int kg = l >> 4;
  const int lr = l & 15;

  f32x4 acc[2][4];
#pragma unroll
  for (int mi = 0; mi < 2; ++mi)
#pragma unroll
    for (int ni = 0; ni < 4; ++ni) acc[mi][ni] = (f32x4)0.f;

  for (int k0 = 0; k0 < K; k0 += 64) {
#pragma unroll
    for (int j = 0; j < 2; ++j) {               // A: 8 chunks (64 rows)
      int c = j * 4 + w;
      int r = c * 8 + srow;
      async_cp16(&A[(size_t)(m0 + r) * K + k0 + ksrc], &As[c * 512]);
    }
#pragma unroll
    for (int j = 0; j < 4; ++j) {               // B: 16 chunks (128 rows)
      int c = j * 4 + w;
      int r = c * 8 + srow;
      async_cp16(&B[(size_t)(n0 + r) * K + k0 + ksrc], &Bs[c * 512]);
    }
    __syncthreads();
#pragma unroll
    for (int ks = 0; ks < 2; ++ks) {
      bf16x8 af[2], bfr[4];
#pragma unroll
      for (int mi = 0; mi < 2; ++mi) {
        int r = wm + mi * 16 + lr;
        int boff = r * 128 + ((ks * 64 + kg * 16) ^ ((r & 7) << 4));
        af[mi] = *reinterpret_cast<const bf16x8*>(reinterpret_cast<const char*>(As) + boff);
      }
#pragma unroll
      for (int ni = 0; ni < 4; ++ni) {
        int r = wn + ni * 16 + lr;
        int boff = r * 128 + ((ks * 64 + kg * 16) ^ ((r & 7) << 4));
        bfr[ni] = *reinterpret_cast<const bf16x8*>(reinterpret_cast<const char*>(Bs) + boff);
      }
#pragma unroll
      for (int mi = 0; mi < 2; ++mi)
#pragma unroll
        for (int ni = 0; ni < 4; ++ni)
          acc[mi][ni] = __builtin_amdgcn_mfma_f32_16x16x32_bf16(af[mi], bfr[ni], acc[mi][ni], 0, 0, 0);
    }
    __syncthreads();
  }

  const int crow0 = (l >> 4) * 4;
  const int ccol = l & 15;
#pragma unroll
  for (int mi = 0; mi < 2; ++mi) {
#pragma unroll
    for (int ni = 0; ni < 4; ++ni) {
      int col = n0 + wn + ni * 16 + ccol;
      float bv = bias ? bias[col] : 0.f;
#pragma unroll
      for (int j = 0; j < 4; ++j) {
        int row = m0 + wm + mi * 16 + crow0 + j;
        C[(size_t)row * N + col] = acc[mi][ni][j] + bv;
      }
    }
  }
}

// ---------------- fused FFN1 + GEGLU: glu = a * gelu(g), bf16 out ----------------
__global__ __launch_bounds__(256) void gemm_ffn1_glu(
    const ushort_t* __restrict__ A,
    const ushort_t* __restrict__ B,
    ushort_t* __restrict__ O,
    int K,
    const float* __restrict__ bias, int grp) {
  __shared__ ushort_t As[128 * 64];
  __shared__ ushort_t Bs[128 * 64];
  const int tid = threadIdx.x;
  const int l = tid & 63;
  const int w = tid >> 6;

  const unsigned nwgx = gridDim.x;                // 64 col-panels of width 64
  const unsigned nwg = nwgx * gridDim.y;
  const unsigned bid = blockIdx.y * nwgx + blockIdx.x;
  const unsigned cpx = nwg >> 3;
  const unsigned s = (bid & 7u) * cpx + (bid >> 3);
  const unsigned bandw = (unsigned)grp * nwgx;
  const unsigned band = s / bandw;
  const unsigned rem = s % bandw;
  const int m0 = (int)(band * grp + (rem % grp)) * 128;
  const int n0 = (int)(rem / grp) * 64;

  const int wm = (w >> 1) * 64;
  const int wn2 = (w & 1) * 32;

  const int srow = l >> 3;
  const int ksrc = 8 * ((l & 7) ^ srow);
  const int kg = l >> 4;
  const int lr = l & 15;

  f32x4 acc[4][4];
#pragma unroll
  for (int mi = 0; mi < 4; ++mi)
#pragma unroll
    for (int ni = 0; ni < 4; ++ni) acc[mi][ni] = (f32x4)0.f;

  for (int k0 = 0; k0 < K; k0 += 64) {
#pragma unroll
    for (int j = 0; j < 4; ++j) {
      int c = j * 4 + w;
      int r = c * 8 + srow;
      async_cp16(&A[(size_t)(m0 + r) * K + k0 + ksrc], &As[c * 512]);
    }
#pragma unroll
    for (int j = 0; j < 4; ++j) {
      int c = j * 4 + w;
      int gr = (c < 8) ? (n0 + c * 8 + srow)
                       : (FF + n0 + (c - 8) * 8 + srow);
      async_cp16(&B[(size_t)gr * K + k0 + ksrc], &Bs[c * 512]);
    }
    __syncthreads();
#pragma unroll
    for (int ks = 0; ks < 2; ++ks) {
      bf16x8 af[4], bfr[4];
#pragma unroll
      for (int mi = 0; mi < 4; ++mi) {
        int r = wm + mi * 16 + lr;
        int boff = r * 128 + ((ks * 64 + kg * 16) ^ ((r & 7) << 4));
        af[mi] = *reinterpret_cast<const bf16x8*>(reinterpret_cast<const char*>(As) + boff);
      }
#pragma unroll
      for (int ni = 0; ni < 4; ++ni) {
        int r = (ni < 2 ? wn2 + ni * 16 : 64 + wn2 + (ni - 2) * 16) + lr;
        int boff = r * 128 + ((ks * 64 + kg * 16) ^ ((r & 7) << 4));
        bfr[ni] = *reinterpret_cast<const bf16x8*>(reinterpret_cast<const char*>(Bs) + boff);
      }
#pragma unroll
      for (int mi = 0; mi < 4; ++mi)
#pragma unroll
        for (int ni = 0; ni < 4; ++ni)
          acc[mi][ni] = __builtin_amdgcn_mfma_f32_16x16x32_bf16(af[mi], bfr[ni], acc[mi][ni], 0, 0, 0);
    }
    __syncthreads();
  }

  const int crow0 = (l >> 4) * 4;
  const int ccol = l & 15;
#pragma unroll
  for (int mi = 0; mi < 4; ++mi) {
#pragma unroll
    for (int ni = 0; ni < 2; ++ni) {
      int col = n0 + wn2 + ni * 16 + ccol;
      float ba = bias[col];
      float bg = bias[FF + col];
#pragma unroll
      for (int j = 0; j < 4; ++j) {
        int row = m0 + wm + mi * 16 + crow0 + j;
        float a = acc[mi][ni][j] + ba;
        float g = acc[mi][ni + 2][j] + bg;
        float ge = 0.5f * g * (1.f + erff(g * 0.70710678118654752f));
        O[(size_t)row * FF + col] = f2bf(a * ge);
      }
    }
  }
}

// ---------------- fp32 NT GEMM (dt_proj) ----------------
__global__ __launch_bounds__(256) void gemm_nt(
    const float* __restrict__ A, int lda,
    const float* __restrict__ B, int ldb,
    float* __restrict__ C, int ldc,
    int N, int K,
    const float* __restrict__ bias, int act) {
  __shared__ __align__(16) float Asf[16][68];
  __shared__ __align__(16) float Bsf[16][68];
  const int tx = threadIdx.x;
  const int ty = threadIdx.y;
  const int tid = ty * 16 + tx;
  const int m0 = blockIdx.y * 64;
  const int n0 = blockIdx.x * 64;
  const int lrow = tid >> 2;
  const int lk = (tid & 3) * 4;

  float acc[4][4] = {{0.f}};

  for (int k0 = 0; k0 < K; k0 += 16) {
    float4 av, bv;
    {
      const float* ap = A + (size_t)(m0 + lrow) * lda + k0 + lk;
      av = *reinterpret_cast<const float4*>(ap);
    }
    int brow = n0 + lrow;
    if (brow < N) {
      const float* bp = B + (size_t)brow * ldb + k0 + lk;
      bv = *reinterpret_cast<const float4*>(bp);
    } else {
      bv = make_float4(0.f, 0.f, 0.f, 0.f);
    }
    __syncthreads();
    Asf[lk + 0][lrow] = av.x; Asf[lk + 1][lrow] = av.y;
    Asf[lk + 2][lrow] = av.z; Asf[lk + 3][lrow] = av.w;
    Bsf[lk + 0][lrow] = bv.x; Bsf[lk + 1][lrow] = bv.y;
    Bsf[lk + 2][lrow] = bv.z; Bsf[lk + 3][lrow] = bv.w;
    __syncthreads();
#pragma unroll
    for (int k = 0; k < 16; ++k) {
      const float4 a4 = *reinterpret_cast<const float4*>(&Asf[k][ty * 4]);
      const float4 b4 = *reinterpret_cast<const float4*>(&Bsf[k][tx * 4]);
      float a[4] = {a4.x, a4.y, a4.z, a4.w};
      float bb[4] = {b4.x, b4.y, b4.z, b4.w};
#pragma unroll
      for (int i = 0; i < 4; ++i)
#pragma unroll
        for (int j = 0; j < 4; ++j)
          acc[i][j] = fmaf(a[i], bb[j], acc[i][j]);
    }
  }

#pragma unroll
  for (int i = 0; i < 4; ++i) {
    int m = m0 + ty * 4 + i;
#pragma unroll
    for (int j = 0; j < 4; ++j) {
      int n = n0 + tx * 4 + j;
      if (n < N) {
        float v = acc[i][j];
        if (bias) v += bias[n];
        if (act == 1) v = (v > 20.f) ? v : log1pf(__expf(v));
        C[(size_t)m * ldc + n] = v;
      }
    }
  }
}

// ---------------- x_proj split-K stage 1 (bf16 activations) ----------------
__global__ __launch_bounds__(256) void xproj_partial(
    const ushort_t* __restrict__ A,   // xcb [4096, 2048] bf16
    const float* __restrict__ W,      // [96, 2048]
    float* __restrict__ pbuf) {       // [XP_KS, 4096, 96]
  __shared__ __align__(16) float As[64][68];
  __shared__ __align__(16) float Wsd[96][68];
  const int ks = blockIdx.x;
  const int mb = blockIdx.y;
  const int tid = threadIdx.x;
  const int r0 = (tid >> 4) * 4;        // 0..60
  const int c0 = (tid & 15) * 6;        // 0..90

  float acc[4][6];
#pragma unroll
  for (int i = 0; i < 4; ++i)
#pragma unroll
    for (int j = 0; j < 6; ++j) acc[i][j] = 0.f;

  for (int k0 = 0; k0 < XP_KSTEP; k0 += 64) {
    const int kbase = ks * XP_KSTEP + k0;
    __syncthreads();
    {
      int r = tid >> 2, c = (tid & 3) * 16;
      const ushort_t* src = A + (size_t)(mb * 64 + r) * D_INNER + kbase + c;
#pragma unroll
      for (int q = 0; q < 4; ++q) {
        ushort4 uv = *reinterpret_cast<const ushort4*>(src + q * 4);
        As[r][c + q * 4 + 0] = bf2f(uv.x);
        As[r][c + q * 4 + 1] = bf2f(uv.y);
        As[r][c + q * 4 + 2] = bf2f(uv.z);
        As[r][c + q * 4 + 3] = bf2f(uv.w);
      }
    }
#pragma unroll
    for (int q = 0; q < 6; ++q) {
      int f = q * 256 + tid;
      int wr = f >> 4;
      int wc = (f & 15) * 4;
      *reinterpret_cast<float4*>(&Wsd[wr][wc]) =
          *reinterpret_cast<const float4*>(&W[(size_t)wr * D_INNER + kbase + wc]);
    }
    __syncthreads();
#pragma unroll 16
    for (int k = 0; k < 64; ++k) {
      float a[4], wv[6];
#pragma unroll
      for (int i = 0; i < 4; ++i) a[i] = As[r0 + i][k];
#pragma unroll
      for (int j = 0; j < 6; ++j) wv[j] = Wsd[c0 + j][k];
#pragma unroll
      for (int i = 0; i < 4; ++i)
#pragma unroll
        for (int j = 0; j < 6; ++j)
          acc[i][j] = fmaf(a[i], wv[j], acc[i][j]);
    }
  }

  float* dst = pbuf + ((size_t)ks * ROWS + mb * 64) * 96;
#pragma unroll
  for (int i = 0; i < 4; ++i)
#pragma unroll
    for (int j = 0; j < 6; ++j)
      dst[(size_t)(r0 + i) * 96 + c0 + j] = acc[i][j];
}

// ---------------- x_proj split-K stage 2: reduce ----------------
__global__ __launch_bounds__(256) void xproj_reduce(
    const float* __restrict__ pbuf, float* __restrict__ xdbl) {
  int i = blockIdx.x * 256 + threadIdx.x;   // 0 .. ROWS*96-1
  float s = 0.f;
#pragma unroll
  for (int ks = 0; ks < XP_KS; ++ks)
    s += pbuf[(size_t)ks * (ROWS * 96) + i];
  xdbl[i] = s;
}

// ---------------- causal depthwise conv (k=4) + SiLU, bf16 in / bf16 out ----------------
__global__ __launch_bounds__(256) void conv_silu_kernel(
    const ushort_t* __restrict__ xzb, ushort_t* __restrict__ xcb,
    const float* __restrict__ cw, const float* __restrict__ cb) {
  int t = (blockIdx.x * 256 + threadIdx.x) * 4;
  if (t >= ROWS * D_INNER) return;
  int d = t & (D_INNER - 1);
  int row = t >> 11;
  int l = row & (SEQ - 1);
  float acc[4];
#pragma unroll
  for (int q = 0; q < 4; ++q) acc[q] = cb[d + q];
#pragma unroll
  for (int j = 0; j < 4; ++j) {
    int ls = l - 3 + j;
    if (ls >= 0) {
      ushort4 uv = *reinterpret_cast<const ushort4*>(
          xzb + (size_t)(row - 3 + j) * (2 * D_INNER) + d);
      acc[0] = fmaf(cw[(d + 0) * 4 + j], bf2f(uv.x), acc[0]);
      acc[1] = fmaf(cw[(d + 1) * 4 + j], bf2f(uv.y), acc[1]);
      acc[2] = fmaf(cw[(d + 2) * 4 + j], bf2f(uv.z), acc[2]);
      acc[3] = fmaf(cw[(d + 3) * 4 + j], bf2f(uv.w), acc[3]);
    }
  }
  ushort4 o;
  o.x = f2bf(acc[0] * sigmoidf_(acc[0]));
  o.y = f2bf(acc[1] * sigmoidf_(acc[1]));
  o.z = f2bf(acc[2] * sigmoidf_(acc[2]));
  o.w = f2bf(acc[3] * sigmoidf_(acc[3]));
  *reinterpret_cast<ushort4*>(xcb + t) = o;
}

// ================= chunked selective scan (CS=32, LDS B/C, 4-deep prefetch) =================
__global__ __launch_bounds__(256) void scan_pass1(
    const float* __restrict__ delta,
    const ushort_t* __restrict__ xcb,
    const float* __restrict__ xdbl,
    const float* __restrict__ A_log,
    float* __restrict__ harr,
    float* __restrict__ dtsum) {
  __shared__ __align__(16) float Bls[CS][16];
  int gid = blockIdx.x * 256 + threadIdx.x;
  int d = gid & (D_INNER - 1);
  int bc = gid >> 11;
  int c = bc & (NC - 1);
  int b = bc >> NC_LOG;
  const size_t r0 = (size_t)b * SEQ + (size_t)c * CS;

  if (threadIdx.x < CS * 4) {
    int sl = threadIdx.x >> 2, sf = (threadIdx.x & 3) * 4;
    *reinterpret_cast<f32x4*>(&Bls[sl][sf]) =
        *reinterpret_cast<const f32x4*>(xdbl + (r0 + sl) * 96 + 64 + sf);
  }

  float Av2[D_STATE];
#pragma unroll
  for (int n = 0; n < D_STATE; ++n)
    Av2[n] = -__expf(A_log[(size_t)d * D_STATE + n]) * LOG2E;
  float h[D_STATE];
#pragma unroll
  for (int n = 0; n < D_STATE; ++n) h[n] = 0.f;
  float dts = 0.f;

  const float* drow = delta + r0 * D_INNER + d;
  const ushort_t* urow = xcb + r0 * D_INNER + d;

  float pdt[4], pu[4];
#pragma unroll
  for (int g = 0; g < 4; ++g) {
    pdt[g] = drow[(size_t)g * D_INNER];
    pu[g]  = bf2f(urow[(size_t)g * D_INNER]);
  }
  __syncthreads();

  for (int l0 = 0; l0 < CS; l0 += 4) {
    float cdt[4], cu[4];
#pragma unroll
    for (int g = 0; g < 4; ++g) { cdt[g] = pdt[g]; cu[g] = pu[g]; }
    if (l0 + 4 < CS) {
#pragma unroll
      for (int g = 0; g < 4; ++g) {
        pdt[g] = drow[(size_t)(l0 + 4 + g) * D_INNER];
        pu[g]  = bf2f(urow[(size_t)(l0 + 4 + g) * D_INNER]);
      }
    }
#pragma unroll
    for (int g = 0; g < 4; ++g) {
      int l = l0 + g;
      f32x4 B0 = *reinterpret_cast<const f32x4*>(&Bls[l][0]);
      f32x4 B1 = *reinterpret_cast<const f32x4*>(&Bls[l][4]);
      f32x4 B2 = *reinterpret_cast<const f32x4*>(&Bls[l][8]);
      f32x4 B3 = *reinterpret_cast<const f32x4*>(&Bls[l][12]);
      float du = cdt[g] * cu[g];
      dts += cdt[g];
      float Bsr[D_STATE] = {B0[0],B0[1],B0[2],B0[3], B1[0],B1[1],B1[2],B1[3],
                            B2[0],B2[1],B2[2],B2[3], B3[0],B3[1],B3[2],B3[3]};
#pragma unroll
      for (int n = 0; n < D_STATE; ++n) {
        float dA = __builtin_amdgcn_exp2f(cdt[g] * Av2[n]);
        h[n] = dA * h[n] + du * Bsr[n];
      }
    }
  }
#pragma unroll
  for (int n = 0; n < D_STATE; ++n)
    harr[((size_t)bc * D_STATE + n) * D_INNER + d] = h[n];
  dtsum[(size_t)bc * D_INNER + d] = dts;
}

// pass2: sequential combine over NC chunks; IN-PLACE: harr[c] := h0 for chunk c
__global__ __launch_bounds__(256) void scan_pass2(
    float* __restrict__ harr,
    const float* __restrict__ dtsum,
    const float* __restrict__ A_log) {
  int gid = blockIdx.x * 256 + threadIdx.x;
  int d = gid & (D_INNER - 1);
  int bn = gid >> 11;
  int n = bn & (D_STATE - 1);
  int b = bn >> 4;
  float Av2 = -__expf(A_log[(size_t)d * D_STATE + n]) * LOG2E;
  float h = 0.f;
  for (int c = 0; c < NC; ++c) {
    size_t bc = (size_t)b * NC + c;
    size_t idx = (bc * D_STATE + n) * D_INNER + d;
    float he = harr[idx];
    harr[idx] = h;
    float P = __builtin_amdgcn_exp2f(Av2 * dtsum[bc * D_INNER + d]);
    h = P * h + he;
  }
}

// pass3: rescan with true h0, y = h·C + u*D, gate silu(z) -> bf16
__global__ __launch_bounds__(256) void scan_pass3(
    const float* __restrict__ delta,
    const ushort_t* __restrict__ xcb,
    ushort_t* __restrict__ ybf,
    const float* __restrict__ xdbl,
    const ushort_t* __restrict__ xzb,
    const float* __restrict__ A_log,
    const float* __restrict__ Dp,
    const float* __restrict__ harr) {
  __shared__ __align__(16) float BCls[CS][32];   // B at [0..16), C at [16..32)
  int gid = blockIdx.x * 256 + threadIdx.x;
  int d = gid & (D_INNER - 1);
  int bc = gid >> 11;
  int c = bc & (NC - 1);
  int b = bc >> NC_LOG;
  const size_t r0 = (size_t)b * SEQ + (size_t)c * CS;

  {
    int sl = threadIdx.x >> 3, sf = (threadIdx.x & 7) * 4;
    *reinterpret_cast<f32x4*>(&BCls[sl][sf]) =
        *reinterpret_cast<const f32x4*>(xdbl + (r0 + sl) * 96 + 64 + sf);
  }

  float Av2[D_STATE];
#pragma unroll
  for (int n = 0; n < D_STATE; ++n)
    Av2[n] = -__expf(A_log[(size_t)d * D_STATE + n]) * LOG2E;
  const float Dd = Dp[d];
  float h[D_STATE];
#pragma unroll
  for (int n = 0; n < D_STATE; ++n)
    h[n] = harr[((size_t)bc * D_STATE + n) * D_INNER + d];

  const float* drow = delta + r0 * D_INNER + d;
  const ushort_t* urow = xcb + r0 * D_INNER + d;
  const ushort_t* zrow = xzb + r0 * (2 * D_INNER) + D_INNER + d;
  ushort_t* yrow = ybf + r0 * D_INNER + d;

  float pdt[4], pu[4], pz[4];
#pragma unroll
  for (int g = 0; g < 4; ++g) {
    pdt[g] = drow[(size_t)g * D_INNER];
    pu[g]  = bf2f(urow[(size_t)g * D_INNER]);
    pz[g]  = bf2f(zrow[(size_t)g * (2 * D_INNER)]);
  }
  __syncthreads();

  for (int l0 = 0; l0 < CS; l0 += 4) {
    float cdt[4], cu[4], cz[4];
#pragma unroll
    for (int g = 0; g < 4; ++g) { cdt[g] = pdt[g]; cu[g] = pu[g]; cz[g] = pz[g]; }
    if (l0 + 4 < CS) {
#pragma unroll
      for (int g = 0; g < 4; ++g) {
        pdt[g] = drow[(size_t)(l0 + 4 + g) * D_INNER];
        pu[g]  = bf2f(urow[(size_t)(l0 + 4 + g) * D_INNER]);
        pz[g]  = bf2f(zrow[(size_t)(l0 + 4 + g) * (2 * D_INNER)]);
      }
    }
#pragma unroll
    for (int g = 0; g < 4; ++g) {
      int l = l0 + g;
      f32x4 B0 = *reinterpret_cast<const f32x4*>(&BCls[l][0]);
      f32x4 B1 = *reinterpret_cast<const f32x4*>(&BCls[l][4]);
      f32x4 B2 = *reinterpret_cast<const f32x4*>(&BCls[l][8]);
      f32x4 B3 = *reinterpret_cast<const f32x4*>(&BCls[l][12]);
      f32x4 C0 = *reinterpret_cast<const f32x4*>(&BCls[l][16]);
      f32x4 C1 = *reinterpret_cast<const f32x4*>(&BCls[l][20]);
      f32x4 C2 = *reinterpret_cast<const f32x4*>(&BCls[l][24]);
      f32x4 C3 = *reinterpret_cast<const f32x4*>(&BCls[l][28]);
      float du = cdt[g] * cu[g];
      float Bsr[D_STATE] = {B0[0],B0[1],B0[2],B0[3], B1[0],B1[1],B1[2],B1[3],
                            B2[0],B2[1],B2[2],B2[3], B3[0],B3[1],B3[2],B3[3]};
      float Csr[D_STATE] = {C0[0],C0[1],C0[2],C0[3], C1[0],C1[1],C1[2],C1[3],
                            C2[0],C2[1],C2[2],C2[3], C3[0],C3[1],C3[2],C3[3]};
      float y = 0.f;
#pragma unroll
      for (int n = 0; n < D_STATE; ++n) {
        float dA = __builtin_amdgcn_exp2f(cdt[g] * Av2[n]);
        h[n] = dA * h[n] + du * Bsr[n];
        y = fmaf(h[n], Csr[n], y);
      }
      y = fmaf(cu[g], Dd, y);
      yrow[(size_t)l * D_INNER] = f2bf(y * (cz[g] * sigmoidf_(cz[g])));
    }
  }
}

extern "C" void kernel_launch(void* const* d_in, const int* in_sizes, int n_in,
                              void* d_out, int out_size, void* d_ws, size_t ws_size,
                              hipStream_t stream) {
  const float* x         = (const float*)d_in[0];
  const float* in_proj_w = (const float*)d_in[1];
  const float* conv_w    = (const float*)d_in[2];
  const float* conv_b    = (const float*)d_in[3];
  const float* x_proj_w  = (const float*)d_in[4];
  const float* dt_proj_w = (const float*)d_in[5];
  const float* dt_proj_b = (const float*)d_in[6];
  const float* A_log     = (const float*)d_in[7];
  const float* Dp        = (const float*)d_in[8];
  const float* out_proj_w= (const float*)d_in[9];
  const float* rms_w     = (const float*)d_in[10];
  const float* ln_w      = (const float*)d_in[11];
  const float* ln_b      = (const float*)d_in[12];
  const float* ff_w1     = (const float*)d_in[13];
  const float* ff_b1     = (const float*)d_in[14];
  const float* ff_w2     = (const float*)d_in[15];
  const float* ff_b2     = (const float*)d_in[16];
  float* out = (float*)d_out;

  float* ws = (float*)d_ws;
  // ---- layout (float-word offsets); total end = 65,536,000 w = 250.0 MiB ----
  float* res     = ws;                              // [0, 4194304)
  float* dtsum   = ws + 4194304;                    // B*NC*D_INNER = 262,144 w (old hbuf slot)
  float* xdbl    = ws + 8388608;                    // [8388608, 8781824)
  ushort_t* hbuf_bf = (ushort_t*)(ws + 8912896);    // 4M ushorts [8912896, 11010048)
  float*    pbuf    = ws + 11010048;                // x_proj partials 3.1M w
  ushort_t* y_bf    = (ushort_t*)(ws + 15204352);   // 8M ushorts [15204352, 19398656)
  ushort_t* glu_bf  = (ushort_t*)(ws + 11010048);   // overlays pbuf+y_bf (FFN phase)
  float* big   = ws + 19398656;                     // [19398656, 52953088)
  ushort_t* xz_bf = (ushort_t*)big;                 // 16.7M ushorts = 8,388,608 w (layer phase)
  ushort_t* xcb   = (ushort_t*)(big + 8388608);     // 8.4M ushorts = 4,194,304 w
  float* delta = big + 16777216;                    // 8,388,608 w
  float* harr  = big + 25165824;                    // B*NC*16*D_INNER = 4,194,304 w
  float* op_out= big;                               // 4M w (overlays xz_bf after scan)
  ushort_t* nrm_bf = (ushort_t*)delta;              // 4M ushorts (dead before dt_proj writes)
  ushort_t* in_w_bf  = (ushort_t*)(ws + 52953088);  // 8M ushorts [52953088, 57147392)
  ushort_t* out_w_bf = (ushort_t*)(ws + 57147392);  // 4M ushorts [57147392, 59244544)
  ushort_t* ff1_bf   = (ushort_t*)(ws + 59244544);  // 8M ushorts [59244544, 63438848)
  ushort_t* ff2_bf   = (ushort_t*)(ws + 63438848);  // 4M ushorts [63438848, 65536000)

  dim3 tb(16, 16);

  // all 4 weight conversions in one launch (24576 blocks cover 25,165,824 elems)
  f2b_all<<<24576, 256, 0, stream>>>(in_proj_w, in_w_bf, out_proj_w, out_w_bf,
                                     ff_w1, ff1_bf, ff_w2, ff2_bf);

  // layer 0 input norm
  res_rms_kernel<<<ROWS, 256, 0, stream>>>(x, res, nrm_bf, rms_w);

  for (int i = 0; i < DEPTH; ++i) {
    const float* cw    = conv_w + (size_t)i * D_INNER * D_CONV;
    const float* cb    = conv_b + (size_t)i * D_INNER;
    const float* xp_w  = x_proj_w + (size_t)i * 96 * D_INNER;
    const float* dtp_w = dt_proj_w + (size_t)i * D_INNER * DT_RANK;
    const float* dtp_b = dt_proj_b + (size_t)i * D_INNER;
    const float* Alg   = A_log + (size_t)i * D_INNER * D_STATE;
    const float* Di    = Dp + (size_t)i * D_INNER;

    // in_proj: xz_bf[4096,4096] = nrm * in_w^T  (bf16 MFMA, bf16 out)
    gemm_bf16_nt<<<dim3(32, 32), 256, 0, stream>>>(
        nrm_bf, in_w_bf + (size_t)i * 4194304, nullptr, xz_bf, 2 * D_INNER, DIM,
        nullptr, 16);
    conv_silu_kernel<<<(ROWS * D_INNER / 4) / 256, 256, 0, stream>>>(xz_bf, xcb, cw, cb);
    // x_proj: split-K two-stage
    xproj_partial<<<dim3(XP_KS, 64), 256, 0, stream>>>(xcb, xp_w, pbuf);
    xproj_reduce<<<(ROWS * 96) / 256, 256, 0, stream>>>(pbuf, xdbl);
    gemm_nt<<<dim3(32, 64), tb, 0, stream>>>(xdbl, 96, dtp_w, DT_RANK, delta, D_INNER,
                                             D_INNER, DT_RANK, dtp_b, 1);
    scan_pass1<<<(BATCH * NC * D_INNER) / 256, 256, 0, stream>>>(delta, xcb, xdbl, Alg,
                                                                 harr, dtsum);
    scan_pass2<<<(BATCH * D_STATE * D_INNER) / 256, 256, 0, stream>>>(harr, dtsum, Alg);
    scan_pass3<<<(BATCH * NC * D_INNER) / 256, 256, 0, stream>>>(delta, xcb, y_bf, xdbl,
                                                                 xz_bf, Alg, Di, harr);
    // out_proj: op_out[4096,1024] = y * o_w^T  (64x128-tile bf16 MFMA); xz dead now
    gemm_bf16_nt64<<<dim3(8, 64), 256, 0, stream>>>(
        y_bf, out_w_bf + (size_t)i * 2097152, op_out, DIM, D_INNER, nullptr, 8);
    if (i + 1 < DEPTH) {
      // fused: res += LN(op_out); nrm_bf = RMS(res) with next layer's rms weight
      ln_res_rms_kernel<<<ROWS, 256, 0, stream>>>(
          op_out, res, ln_w + (size_t)i * DIM, ln_b + (size_t)i * DIM,
          rms_w + (size_t)(i + 1) * DIM, nrm_bf);
    } else {
      ln_final_kernel<<<ROWS, 256, 0, stream>>>(
          op_out, hbuf_bf, ln_w + (size_t)i * DIM, ln_b + (size_t)i * DIM);
    }
  }

  // FFN1 + GEGLU fused: glu_bf[4096,4096] = a*gelu(g), a|g = hbuf*ff_w1^T + b1
  gemm_ffn1_glu<<<dim3(64, 32), 256, 0, stream>>>(hbuf_bf, ff1_bf, glu_bf, DIM,
                                                  ff_b1, 16);
  // FFN2: out = glu * ff_w2^T + b2  (64x128-tile bf16 MFMA)
  gemm_bf16_nt64<<<dim3(8, 64), 256, 0, stream>>>(glu_bf, ff2_bf, out, DIM, FF,
                                                  ff_b2, 8);
}

// Round 15
// 756.799 us; speedup vs baseline: 1.1463x; 1.0041x over previous
//
#include <hip/hip_runtime.h>
#include <cstdint>
#include <cstddef>

#define DIM     1024
#define SEQ     2048
#define BATCH   2
#define DEPTH   2
#define D_INNER 2048
#define D_STATE 16
#define D_CONV  4
#define DT_RANK 64
#define FF      4096
#define ROWS    (BATCH*SEQ)   // 4096
#define EPS     1e-5f

#define CS      32            // scan chunk size
#define NC      (SEQ/CS)      // 64 chunks
#define NC_LOG  6

#define XP_KS    8            // x_proj k-split
#define XP_KSTEP (D_INNER/XP_KS)  // 256

#define LOG2E 1.44269504088896f

typedef unsigned short ushort_t;
typedef short bf16x8 __attribute__((ext_vector_type(8)));
typedef float f32x4  __attribute__((ext_vector_type(4)));

__device__ __forceinline__ float sigmoidf_(float x) { return 1.f / (1.f + __expf(-x)); }

// bf16 <-> fp32
__device__ __forceinline__ ushort_t f2bf(float x) {
  unsigned int u = __float_as_uint(x);
  u += 0x7fffu + ((u >> 16) & 1u);
  return (ushort_t)(u >> 16);
}
__device__ __forceinline__ float bf2f(ushort_t u) {
  return __uint_as_float((unsigned)u << 16);
}

// async global->LDS 16B (wave-uniform LDS base + lane*16)
__device__ __forceinline__ void async_cp16(const void* g, void* lds) {
  __builtin_amdgcn_global_load_lds(
      (const __attribute__((address_space(1))) unsigned int*)g,
      (__attribute__((address_space(3))) unsigned int*)lds, 16, 0, 0);
}

// ---------------- block-wide reduction ----------------
__device__ __forceinline__ float2 block_sum2(float a, float b) {
#pragma unroll
  for (int off = 32; off > 0; off >>= 1) {
    a += __shfl_down(a, off, 64);
    b += __shfl_down(b, off, 64);
  }
  __shared__ float sa[4], sb[4];
  __syncthreads();
  if ((threadIdx.x & 63) == 0) { int w = threadIdx.x >> 6; sa[w] = a; sb[w] = b; }
  __syncthreads();
  return make_float2(sa[0] + sa[1] + sa[2] + sa[3], sb[0] + sb[1] + sb[2] + sb[3]);
}

// ---------------- residual add + RMSNorm (bf16 normed out) ----------------
__global__ __launch_bounds__(256) void res_rms_kernel(
    const float* __restrict__ xin,
    float* __restrict__ res, ushort_t* __restrict__ nrm, const float* __restrict__ w) {
  int row = blockIdx.x;
  const float* xr = xin + (size_t)row * DIM;
  float* rr = res + (size_t)row * DIM;
  ushort_t* nr = nrm + (size_t)row * DIM;
  float v[4]; float ss = 0.f;
#pragma unroll
  for (int i = 0; i < 4; ++i) {
    int j = threadIdx.x + i * 256;
    float t = xr[j];
    v[i] = t; rr[j] = t; ss += t * t;
  }
  float2 s = block_sum2(ss, 0.f);
  float rstd = rsqrtf(s.x * (1.f / DIM) + EPS);
#pragma unroll
  for (int i = 0; i < 4; ++i) {
    int j = threadIdx.x + i * 256;
    nr[j] = f2bf(v[i] * rstd * w[j]);
  }
}

// ---------------- fused LayerNorm -> residual add -> RMSNorm (bf16 out) ----------------
__global__ __launch_bounds__(256) void ln_res_rms_kernel(
    const float* __restrict__ in, float* __restrict__ res,
    const float* __restrict__ lw, const float* __restrict__ lb,
    const float* __restrict__ rw, ushort_t* __restrict__ nrm) {
  int row = blockIdx.x;
  const float* xr = in + (size_t)row * DIM;
  float* rr = res + (size_t)row * DIM;
  ushort_t* nr = nrm + (size_t)row * DIM;
  float v[4]; float s1 = 0.f, s2 = 0.f;
#pragma unroll
  for (int i = 0; i < 4; ++i) {
    int j = threadIdx.x + i * 256;
    float t = xr[j];
    v[i] = t; s1 += t; s2 += t * t;
  }
  float2 s = block_sum2(s1, s2);
  float mean = s.x * (1.f / DIM);
  float var = s.y * (1.f / DIM) - mean * mean;
  float rstd = rsqrtf(var + EPS);
  float t4[4]; float ss = 0.f;
#pragma unroll
  for (int i = 0; i < 4; ++i) {
    int j = threadIdx.x + i * 256;
    float o = (v[i] - mean) * rstd * lw[j] + lb[j];
    float t = rr[j] + o;
    rr[j] = t;
    t4[i] = t; ss += t * t;
  }
  float2 s2v = block_sum2(ss, 0.f);
  float rstd2 = rsqrtf(s2v.x * (1.f / DIM) + EPS);
#pragma unroll
  for (int i = 0; i < 4; ++i) {
    int j = threadIdx.x + i * 256;
    nr[j] = f2bf(t4[i] * rstd2 * rw[j]);
  }
}

// ---------------- final LayerNorm (bf16 out only) ----------------
__global__ __launch_bounds__(256) void ln_final_kernel(
    const float* __restrict__ in, ushort_t* __restrict__ outb,
    const float* __restrict__ w, const float* __restrict__ b) {
  int row = blockIdx.x;
  const float* xr = in + (size_t)row * DIM;
  ushort_t* obrow = outb + (size_t)row * DIM;
  float v[4]; float s1 = 0.f, s2 = 0.f;
#pragma unroll
  for (int i = 0; i < 4; ++i) {
    int j = threadIdx.x + i * 256;
    float t = xr[j];
    v[i] = t; s1 += t; s2 += t * t;
  }
  float2 s = block_sum2(s1, s2);
  float mean = s.x * (1.f / DIM);
  float var = s.y * (1.f / DIM) - mean * mean;
  float rstd = rsqrtf(var + EPS);
#pragma unroll
  for (int i = 0; i < 4; ++i) {
    int j = threadIdx.x + i * 256;
    obrow[j] = f2bf((v[i] - mean) * rstd * w[j] + b[j]);
  }
}

// ---------------- fused fp32 -> bf16 conversion for all 4 weight tensors ----------------
__global__ __launch_bounds__(256) void f2b_all(
    const float* __restrict__ w0, ushort_t* __restrict__ d0,
    const float* __restrict__ w1, ushort_t* __restrict__ d1,
    const float* __restrict__ w2, ushort_t* __restrict__ d2,
    const float* __restrict__ w3, ushort_t* __restrict__ d3) {
  int i = (blockIdx.x * 256 + threadIdx.x) * 4;
  const float* s; ushort_t* d; int off;
  if (i < 8388608)        { s = w0; d = d0; off = i; }
  else if (i < 12582912)  { s = w1; d = d1; off = i - 8388608; }
  else if (i < 20971520)  { s = w2; d = d2; off = i - 12582912; }
  else                    { s = w3; d = d3; off = i - 20971520; }
  float4 v = *reinterpret_cast<const float4*>(s + off);
  d[off + 0] = f2bf(v.x); d[off + 1] = f2bf(v.y);
  d[off + 2] = f2bf(v.z); d[off + 3] = f2bf(v.w);
}

// ---------------- bf16 MFMA NT GEMM: C = A[M,K] * B[N,K]^T (+bias) ----------------
// 128x128 tile, BK=64, 4 waves (2x2), 16x16x32 MFMA.
// DOUBLE-BUFFERED LDS + counted vmcnt (T3+T4 minimum): next tile's 8
// global_load_lds stay in flight across the barrier (vmcnt(8), never 0 in loop).
// Raw s_barrier via asm (no compiler-inserted vmcnt(0) drain).
__global__ __launch_bounds__(256) void gemm_bf16_nt(
    const ushort_t* __restrict__ A,
    const ushort_t* __restrict__ B,
    float* __restrict__ C,
    ushort_t* __restrict__ Cb,
    int N, int K,
    const float* __restrict__ bias, int grp) {
  __shared__ ushort_t As[2][128 * 64];
  __shared__ ushort_t Bs[2][128 * 64];
  const int tid = threadIdx.x;
  const int l = tid & 63;
  const int w = tid >> 6;

  const unsigned nwgx = gridDim.x;
  const unsigned nwg = nwgx * gridDim.y;
  const unsigned bid = blockIdx.y * nwgx + blockIdx.x;
  const unsigned cpx = nwg >> 3;
  const unsigned s = (bid & 7u) * cpx + (bid >> 3);
  const unsigned bandw = (unsigned)grp * nwgx;
  const unsigned band = s / bandw;
  const unsigned rem = s % bandw;
  const int m0 = (int)(band * grp + (rem % grp)) * 128;
  const int n0 = (int)(rem / grp) * 128;

  const int wm = (w >> 1) * 64;
  const int wn = (w & 1) * 64;

  const int srow = l >> 3;                      // 0..7 (row within 8-row chunk)
  const int ksrc = 8 * ((l & 7) ^ srow);        // swizzled source k-offset (elements)
  const int kg = l >> 4;                        // 0..3
  const int lr = l & 15;

  f32x4 acc[4][4];
#pragma unroll
  for (int mi = 0; mi < 4; ++mi)
#pragma unroll
    for (int ni = 0; ni < 4; ++ni) acc[mi][ni] = (f32x4)0.f;

  const int nt = K >> 6;

#define STAGE_NT(buf, t)                                                      \
  do {                                                                        \
    int k0_ = (t) << 6;                                                       \
    _Pragma("unroll")                                                         \
    for (int j = 0; j < 4; ++j) {                                             \
      int c = j * 4 + w;                                                      \
      int r = c * 8 + srow;                                                   \
      async_cp16(&A[(size_t)(m0 + r) * K + k0_ + ksrc], &As[buf][c * 512]);   \
    }                                                                         \
    _Pragma("unroll")                                                         \
    for (int j = 0; j < 4; ++j) {                                             \
      int c = j * 4 + w;                                                      \
      int r = c * 8 + srow;                                                   \
      async_cp16(&B[(size_t)(n0 + r) * K + k0_ + ksrc], &Bs[buf][c * 512]);   \
    }                                                                         \
  } while (0)

#define COMPUTE_NT(buf)                                                       \
  do {                                                                        \
    _Pragma("unroll")                                                         \
    for (int ks = 0; ks < 2; ++ks) {                                          \
      bf16x8 af[4], bfr[4];                                                   \
      _Pragma("unroll")                                                       \
      for (int mi = 0; mi < 4; ++mi) {                                        \
        int r = wm + mi * 16 + lr;                                            \
        int boff = r * 128 + ((ks * 64 + kg * 16) ^ ((r & 7) << 4));          \
        af[mi] = *reinterpret_cast<const bf16x8*>(                            \
            reinterpret_cast<const char*>(As[buf]) + boff);                   \
      }                                                                       \
      _Pragma("unroll")                                                       \
      for (int ni = 0; ni < 4; ++ni) {                                        \
        int r = wn + ni * 16 + lr;                                            \
        int boff = r * 128 + ((ks * 64 + kg * 16) ^ ((r & 7) << 4));          \
        bfr[ni] = *reinterpret_cast<const bf16x8*>(                           \
            reinterpret_cast<const char*>(Bs[buf]) + boff);                   \
      }                                                                       \
      _Pragma("unroll")                                                       \
      for (int mi = 0; mi < 4; ++mi)                                          \
        _Pragma("unroll")                                                     \
        for (int ni = 0; ni < 4; ++ni)                                        \
          acc[mi][ni] = __builtin_amdgcn_mfma_f32_16x16x32_bf16(              \
              af[mi], bfr[ni], acc[mi][ni], 0, 0, 0);                         \
    }                                                                         \
  } while (0)

  STAGE_NT(0, 0);
  int cur = 0;
  for (int t = 0; t < nt; ++t) {
    if (t + 1 < nt) {
      STAGE_NT(cur ^ 1, t + 1);
      asm volatile("s_waitcnt vmcnt(8)" ::: "memory");
    } else {
      asm volatile("s_waitcnt vmcnt(0)" ::: "memory");
    }
    asm volatile("s_barrier" ::: "memory");
    COMPUTE_NT(cur);
    asm volatile("s_barrier" ::: "memory");
    cur ^= 1;
  }
#undef STAGE_NT
#undef COMPUTE_NT

  const int crow0 = (l >> 4) * 4;
  const int ccol = l & 15;
#pragma unroll
  for (int mi = 0; mi < 4; ++mi) {
#pragma unroll
    for (int ni = 0; ni < 4; ++ni) {
      int col = n0 + wn + ni * 16 + ccol;
      float bv = bias ? bias[col] : 0.f;
#pragma unroll
      for (int j = 0; j < 4; ++j) {
        int row = m0 + wm + mi * 16 + crow0 + j;
        float v = acc[mi][ni][j] + bv;
        if (Cb) Cb[(size_t)row * N + col] = f2bf(v);
        else    C[(size_t)row * N + col] = v;
      }
    }
  }
}

// ---------------- bf16 MFMA NT GEMM, 64x128 tile (for N=1024 GEMMs) ----------------
__global__ __launch_bounds__(256) void gemm_bf16_nt64(
    const ushort_t* __restrict__ A,
    const ushort_t* __restrict__ B,
    float* __restrict__ C,
    int N, int K,
    const float* __restrict__ bias, int grp) {
  __shared__ ushort_t As[64 * 64];
  __shared__ ushort_t Bs[128 * 64];
  const int tid = threadIdx.x;
  const int l = tid & 63;
  const int w = tid >> 6;

  const unsigned nwgx = gridDim.x;
  const unsigned nwg = nwgx * gridDim.y;
  const unsigned bid = blockIdx.y * nwgx + blockIdx.x;
  const unsigned cpx = nwg >> 3;
  const unsigned s = (bid & 7u) * cpx + (bid >> 3);
  const unsigned bandw = (unsigned)grp * nwgx;
  const unsigned band = s / bandw;
  const unsigned rem = s % bandw;
  const int m0 = (int)(band * grp + (rem % grp)) * 64;
  const int n0 = (int)(rem / grp) * 128;

  const int wm = (w >> 1) * 32;
  const int wn = (w & 1) * 64;

  const int srow = l >> 3;
  const int ksrc = 8 * ((l & 7) ^ srow);
  const int kg = l >> 4;
  const int lr = l & 15;

  f32x4 acc[2][4];
#pragma unroll
  for (int mi = 0; mi < 2; ++mi)
#pragma unroll
    for (int ni = 0; ni < 4; ++ni) acc[mi][ni] = (f32x4)0.f;

  for (int k0 = 0; k0 < K; k0 += 64) {
#pragma unroll
    for (int j = 0; j < 2; ++j) {               // A: 8 chunks (64 rows)
      int c = j * 4 + w;
      int r = c * 8 + srow;
      async_cp16(&A[(size_t)(m0 + r) * K + k0 + ksrc], &As[c * 512]);
    }
#pragma unroll
    for (int j = 0; j < 4; ++j) {               // B: 16 chunks (128 rows)
      int c = j * 4 + w;
      int r = c * 8 + srow;
      async_cp16(&B[(size_t)(n0 + r) * K + k0 + ksrc], &Bs[c * 512]);
    }
    __syncthreads();
#pragma unroll
    for (int ks = 0; ks < 2; ++ks) {
      bf16x8 af[2], bfr[4];
#pragma unroll
      for (int mi = 0; mi < 2; ++mi) {
        int r = wm + mi * 16 + lr;
        int boff = r * 128 + ((ks * 64 + kg * 16) ^ ((r & 7) << 4));
        af[mi] = *reinterpret_cast<const bf16x8*>(reinterpret_cast<const char*>(As) + boff);
      }
#pragma unroll
      for (int ni = 0; ni < 4; ++ni) {
        int r = wn + ni * 16 + lr;
        int boff = r * 128 + ((ks * 64 + kg * 16) ^ ((r & 7) << 4));
        bfr[ni] = *reinterpret_cast<const bf16x8*>(reinterpret_cast<const char*>(Bs) + boff);
      }
#pragma unroll
      for (int mi = 0; mi < 2; ++mi)
#pragma unroll
        for (int ni = 0; ni < 4; ++ni)
          acc[mi][ni] = __builtin_amdgcn_mfma_f32_16x16x32_bf16(af[mi], bfr[ni], acc[mi][ni], 0, 0, 0);
    }
    __syncthreads();
  }

  const int crow0 = (l >> 4) * 4;
  const int ccol = l & 15;
#pragma unroll
  for (int mi = 0; mi < 2; ++mi) {
#pragma unroll
    for (int ni = 0; ni < 4; ++ni) {
      int col = n0 + wn + ni * 16 + ccol;
      float bv = bias ? bias[col] : 0.f;
#pragma unroll
      for (int j = 0; j < 4; ++j) {
        int row = m0 + wm + mi * 16 + crow0 + j;
        C[(size_t)row * N + col] = acc[mi][ni][j] + bv;
      }
    }
  }
}

// ---------------- fused FFN1 + GEGLU: glu = a * gelu(g), bf16 out ----------------
// Double-buffered + counted vmcnt, same schedule as gemm_bf16_nt.
__global__ __launch_bounds__(256) void gemm_ffn1_glu(
    const ushort_t* __restrict__ A,
    const ushort_t* __restrict__ B,
    ushort_t* __restrict__ O,
    int K,
    const float* __restrict__ bias, int grp) {
  __shared__ ushort_t As[2][128 * 64];
  __shared__ ushort_t Bs[2][128 * 64];
  const int tid = threadIdx.x;
  const int l = tid & 63;
  const int w = tid >> 6;

  const unsigned nwgx = gridDim.x;                // 64 col-panels of width 64
  const unsigned nwg = nwgx * gridDim.y;
  const unsigned bid = blockIdx.y * nwgx + blockIdx.x;
  const unsigned cpx = nwg >> 3;
  const unsigned s = (bid & 7u) * cpx + (bid >> 3);
  const unsigned bandw = (unsigned)grp * nwgx;
  const unsigned band = s / bandw;
  const unsigned rem = s % bandw;
  const int m0 = (int)(band * grp + (rem % grp)) * 128;
  const int n0 = (int)(rem / grp) * 64;

  const int wm = (w >> 1) * 64;
  const int wn2 = (w & 1) * 32;

  const int srow = l >> 3;
  const int ksrc = 8 * ((l & 7) ^ srow);
  const int kg = l >> 4;
  const int lr = l & 15;

  f32x4 acc[4][4];
#pragma unroll
  for (int mi = 0; mi < 4; ++mi)
#pragma unroll
    for (int ni = 0; ni < 4; ++ni) acc[mi][ni] = (f32x4)0.f;

  const int nt = K >> 6;

#define STAGE_FG(buf, t)                                                      \
  do {                                                                        \
    int k0_ = (t) << 6;                                                       \
    _Pragma("unroll")                                                         \
    for (int j = 0; j < 4; ++j) {                                             \
      int c = j * 4 + w;                                                      \
      int r = c * 8 + srow;                                                   \
      async_cp16(&A[(size_t)(m0 + r) * K + k0_ + ksrc], &As[buf][c * 512]);   \
    }                                                                         \
    _Pragma("unroll")                                                         \
    for (int j = 0; j < 4; ++j) {                                             \
      int c = j * 4 + w;                                                      \
      int gr = (c < 8) ? (n0 + c * 8 + srow)                                  \
                       : (FF + n0 + (c - 8) * 8 + srow);                      \
      async_cp16(&B[(size_t)gr * K + k0_ + ksrc], &Bs[buf][c * 512]);         \
    }                                                                         \
  } while (0)

#define COMPUTE_FG(buf)                                                       \
  do {                                                                        \
    _Pragma("unroll")                                                         \
    for (int ks = 0; ks < 2; ++ks) {                                          \
      bf16x8 af[4], bfr[4];                                                   \
      _Pragma("unroll")                                                       \
      for (int mi = 0; mi < 4; ++mi) {                                        \
        int r = wm + mi * 16 + lr;                                            \
        int boff = r * 128 + ((ks * 64 + kg * 16) ^ ((r & 7) << 4));          \
        af[mi] = *reinterpret_cast<const bf16x8*>(                            \
            reinterpret_cast<const char*>(As[buf]) + boff);                   \
      }                                                                       \
      _Pragma("unroll")                                                       \
      for (int ni = 0; ni < 4; ++ni) {                                        \
        int r = (ni < 2 ? wn2 + ni * 16 : 64 + wn2 + (ni - 2) * 16) + lr;     \
        int boff = r * 128 + ((ks * 64 + kg * 16) ^ ((r & 7) << 4));          \
        bfr[ni] = *reinterpret_cast<const bf16x8*>(                           \
            reinterpret_cast<const char*>(Bs[buf]) + boff);                   \
      }                                                                       \
      _Pragma("unroll")                                                       \
      for (int mi = 0; mi < 4; ++mi)                                          \
        _Pragma("unroll")                                                     \
        for (int ni = 0; ni < 4; ++ni)                                        \
          acc[mi][ni] = __builtin_amdgcn_mfma_f32_16x16x32_bf16(              \
              af[mi], bfr[ni], acc[mi][ni], 0, 0, 0);                         \
    }                                                                         \
  } while (0)

  STAGE_FG(0, 0);
  int cur = 0;
  for (int t = 0; t < nt; ++t) {
    if (t + 1 < nt) {
      STAGE_FG(cur ^ 1, t + 1);
      asm volatile("s_waitcnt vmcnt(8)" ::: "memory");
    } else {
      asm volatile("s_waitcnt vmcnt(0)" ::: "memory");
    }
    asm volatile("s_barrier" ::: "memory");
    COMPUTE_FG(cur);
    asm volatile("s_barrier" ::: "memory");
    cur ^= 1;
  }
#undef STAGE_FG
#undef COMPUTE_FG

  const int crow0 = (l >> 4) * 4;
  const int ccol = l & 15;
#pragma unroll
  for (int mi = 0; mi < 4; ++mi) {
#pragma unroll
    for (int ni = 0; ni < 2; ++ni) {
      int col = n0 + wn2 + ni * 16 + ccol;
      float ba = bias[col];
      float bg = bias[FF + col];
#pragma unroll
      for (int j = 0; j < 4; ++j) {
        int row = m0 + wm + mi * 16 + crow0 + j;
        float a = acc[mi][ni][j] + ba;
        float g = acc[mi][ni + 2][j] + bg;
        float ge = 0.5f * g * (1.f + erff(g * 0.70710678118654752f));
        O[(size_t)row * FF + col] = f2bf(a * ge);
      }
    }
  }
}

// ---------------- fp32 NT GEMM (dt_proj) ----------------
__global__ __launch_bounds__(256) void gemm_nt(
    const float* __restrict__ A, int lda,
    const float* __restrict__ B, int ldb,
    float* __restrict__ C, int ldc,
    int N, int K,
    const float* __restrict__ bias, int act) {
  __shared__ __align__(16) float Asf[16][68];
  __shared__ __align__(16) float Bsf[16][68];
  const int tx = threadIdx.x;
  const int ty = threadIdx.y;
  const int tid = ty * 16 + tx;
  const int m0 = blockIdx.y * 64;
  const int n0 = blockIdx.x * 64;
  const int lrow = tid >> 2;
  const int lk = (tid & 3) * 4;

  float acc[4][4] = {{0.f}};

  for (int k0 = 0; k0 < K; k0 += 16) {
    float4 av, bv;
    {
      const float* ap = A + (size_t)(m0 + lrow) * lda + k0 + lk;
      av = *reinterpret_cast<const float4*>(ap);
    }
    int brow = n0 + lrow;
    if (brow < N) {
      const float* bp = B + (size_t)brow * ldb + k0 + lk;
      bv = *reinterpret_cast<const float4*>(bp);
    } else {
      bv = make_float4(0.f, 0.f, 0.f, 0.f);
    }
    __syncthreads();
    Asf[lk + 0][lrow] = av.x; Asf[lk + 1][lrow] = av.y;
    Asf[lk + 2][lrow] = av.z; Asf[lk + 3][lrow] = av.w;
    Bsf[lk + 0][lrow] = bv.x; Bsf[lk + 1][lrow] = bv.y;
    Bsf[lk + 2][lrow] = bv.z; Bsf[lk + 3][lrow] = bv.w;
    __syncthreads();
#pragma unroll
    for (int k = 0; k < 16; ++k) {
      const float4 a4 = *reinterpret_cast<const float4*>(&Asf[k][ty * 4]);
      const float4 b4 = *reinterpret_cast<const float4*>(&Bsf[k][tx * 4]);
      float a[4] = {a4.x, a4.y, a4.z, a4.w};
      float bb[4] = {b4.x, b4.y, b4.z, b4.w};
#pragma unroll
      for (int i = 0; i < 4; ++i)
#pragma unroll
        for (int j = 0; j < 4; ++j)
          acc[i][j] = fmaf(a[i], bb[j], acc[i][j]);
    }
  }

#pragma unroll
  for (int i = 0; i < 4; ++i) {
    int m = m0 + ty * 4 + i;
#pragma unroll
    for (int j = 0; j < 4; ++j) {
      int n = n0 + tx * 4 + j;
      if (n < N) {
        float v = acc[i][j];
        if (bias) v += bias[n];
        if (act == 1) v = (v > 20.f) ? v : log1pf(__expf(v));
        C[(size_t)m * ldc + n] = v;
      }
    }
  }
}

// ---------------- x_proj split-K stage 1 (bf16 activations) ----------------
__global__ __launch_bounds__(256) void xproj_partial(
    const ushort_t* __restrict__ A,   // xcb [4096, 2048] bf16
    const float* __restrict__ W,      // [96, 2048]
    float* __restrict__ pbuf) {       // [XP_KS, 4096, 96]
  __shared__ __align__(16) float As[64][68];
  __shared__ __align__(16) float Wsd[96][68];
  const int ks = blockIdx.x;
  const int mb = blockIdx.y;
  const int tid = threadIdx.x;
  const int r0 = (tid >> 4) * 4;        // 0..60
  const int c0 = (tid & 15) * 6;        // 0..90

  float acc[4][6];
#pragma unroll
  for (int i = 0; i < 4; ++i)
#pragma unroll
    for (int j = 0; j < 6; ++j) acc[i][j] = 0.f;

  for (int k0 = 0; k0 < XP_KSTEP; k0 += 64) {
    const int kbase = ks * XP_KSTEP + k0;
    __syncthreads();
    {
      int r = tid >> 2, c = (tid & 3) * 16;
      const ushort_t* src = A + (size_t)(mb * 64 + r) * D_INNER + kbase + c;
#pragma unroll
      for (int q = 0; q < 4; ++q) {
        ushort4 uv = *reinterpret_cast<const ushort4*>(src + q * 4);
        As[r][c + q * 4 + 0] = bf2f(uv.x);
        As[r][c + q * 4 + 1] = bf2f(uv.y);
        As[r][c + q * 4 + 2] = bf2f(uv.z);
        As[r][c + q * 4 + 3] = bf2f(uv.w);
      }
    }
#pragma unroll
    for (int q = 0; q < 6; ++q) {
      int f = q * 256 + tid;
      int wr = f >> 4;
      int wc = (f & 15) * 4;
      *reinterpret_cast<float4*>(&Wsd[wr][wc]) =
          *reinterpret_cast<const float4*>(&W[(size_t)wr * D_INNER + kbase + wc]);
    }
    __syncthreads();
#pragma unroll 16
    for (int k = 0; k < 64; ++k) {
      float a[4], wv[6];
#pragma unroll
      for (int i = 0; i < 4; ++i) a[i] = As[r0 + i][k];
#pragma unroll
      for (int j = 0; j < 6; ++j) wv[j] = Wsd[c0 + j][k];
#pragma unroll
      for (int i = 0; i < 4; ++i)
#pragma unroll
        for (int j = 0; j < 6; ++j)
          acc[i][j] = fmaf(a[i], wv[j], acc[i][j]);
    }
  }

  float* dst = pbuf + ((size_t)ks * ROWS + mb * 64) * 96;
#pragma unroll
  for (int i = 0; i < 4; ++i)
#pragma unroll
    for (int j = 0; j < 6; ++j)
      dst[(size_t)(r0 + i) * 96 + c0 + j] = acc[i][j];
}

// ---------------- x_proj split-K stage 2: reduce ----------------
__global__ __launch_bounds__(256) void xproj_reduce(
    const float* __restrict__ pbuf, float* __restrict__ xdbl) {
  int i = blockIdx.x * 256 + threadIdx.x;   // 0 .. ROWS*96-1
  float s = 0.f;
#pragma unroll
  for (int ks = 0; ks < XP_KS; ++ks)
    s += pbuf[(size_t)ks * (ROWS * 96) + i];
  xdbl[i] = s;
}

// ---------------- causal depthwise conv (k=4) + SiLU, bf16 in / bf16 out ----------------
__global__ __launch_bounds__(256) void conv_silu_kernel(
    const ushort_t* __restrict__ xzb, ushort_t* __restrict__ xcb,
    const float* __restrict__ cw, const float* __restrict__ cb) {
  int t = (blockIdx.x * 256 + threadIdx.x) * 4;
  if (t >= ROWS * D_INNER) return;
  int d = t & (D_INNER - 1);
  int row = t >> 11;
  int l = row & (SEQ - 1);
  float acc[4];
#pragma unroll
  for (int q = 0; q < 4; ++q) acc[q] = cb[d + q];
#pragma unroll
  for (int j = 0; j < 4; ++j) {
    int ls = l - 3 + j;
    if (ls >= 0) {
      ushort4 uv = *reinterpret_cast<const ushort4*>(
          xzb + (size_t)(row - 3 + j) * (2 * D_INNER) + d);
      acc[0] = fmaf(cw[(d + 0) * 4 + j], bf2f(uv.x), acc[0]);
      acc[1] = fmaf(cw[(d + 1) * 4 + j], bf2f(uv.y), acc[1]);
      acc[2] = fmaf(cw[(d + 2) * 4 + j], bf2f(uv.z), acc[2]);
      acc[3] = fmaf(cw[(d + 3) * 4 + j], bf2f(uv.w), acc[3]);
    }
  }
  ushort4 o;
  o.x = f2bf(acc[0] * sigmoidf_(acc[0]));
  o.y = f2bf(acc[1] * sigmoidf_(acc[1]));
  o.z = f2bf(acc[2] * sigmoidf_(acc[2]));
  o.w = f2bf(acc[3] * sigmoidf_(acc[3]));
  *reinterpret_cast<ushort4*>(xcb + t) = o;
}

// ================= chunked selective scan (CS=32, LDS B/C, 4-deep prefetch) =================
__global__ __launch_bounds__(256) void scan_pass1(
    const float* __restrict__ delta,
    const ushort_t* __restrict__ xcb,
    const float* __restrict__ xdbl,
    const float* __restrict__ A_log,
    float* __restrict__ harr,
    float* __restrict__ dtsum) {
  __shared__ __align__(16) float Bls[CS][16];
  int gid = blockIdx.x * 256 + threadIdx.x;
  int d = gid & (D_INNER - 1);
  int bc = gid >> 11;
  int c = bc & (NC - 1);
  int b = bc >> NC_LOG;
  const size_t r0 = (size_t)b * SEQ + (size_t)c * CS;

  if (threadIdx.x < CS * 4) {
    int sl = threadIdx.x >> 2, sf = (threadIdx.x & 3) * 4;
    *reinterpret_cast<f32x4*>(&Bls[sl][sf]) =
        *reinterpret_cast<const f32x4*>(xdbl + (r0 + sl) * 96 + 64 + sf);
  }

  float Av2[D_STATE];
#pragma unroll
  for (int n = 0; n < D_STATE; ++n)
    Av2[n] = -__expf(A_log[(size_t)d * D_STATE + n]) * LOG2E;
  float h[D_STATE];
#pragma unroll
  for (int n = 0; n < D_STATE; ++n) h[n] = 0.f;
  float dts = 0.f;

  const float* drow = delta + r0 * D_INNER + d;
  const ushort_t* urow = xcb + r0 * D_INNER + d;

  float pdt[4], pu[4];
#pragma unroll
  for (int g = 0; g < 4; ++g) {
    pdt[g] = drow[(size_t)g * D_INNER];
    pu[g]  = bf2f(urow[(size_t)g * D_INNER]);
  }
  __syncthreads();

  for (int l0 = 0; l0 < CS; l0 += 4) {
    float cdt[4], cu[4];
#pragma unroll
    for (int g = 0; g < 4; ++g) { cdt[g] = pdt[g]; cu[g] = pu[g]; }
    if (l0 + 4 < CS) {
#pragma unroll
      for (int g = 0; g < 4; ++g) {
        pdt[g] = drow[(size_t)(l0 + 4 + g) * D_INNER];
        pu[g]  = bf2f(urow[(size_t)(l0 + 4 + g) * D_INNER]);
      }
    }
#pragma unroll
    for (int g = 0; g < 4; ++g) {
      int l = l0 + g;
      f32x4 B0 = *reinterpret_cast<const f32x4*>(&Bls[l][0]);
      f32x4 B1 = *reinterpret_cast<const f32x4*>(&Bls[l][4]);
      f32x4 B2 = *reinterpret_cast<const f32x4*>(&Bls[l][8]);
      f32x4 B3 = *reinterpret_cast<const f32x4*>(&Bls[l][12]);
      float du = cdt[g] * cu[g];
      dts += cdt[g];
      float Bsr[D_STATE] = {B0[0],B0[1],B0[2],B0[3], B1[0],B1[1],B1[2],B1[3],
                            B2[0],B2[1],B2[2],B2[3], B3[0],B3[1],B3[2],B3[3]};
#pragma unroll
      for (int n = 0; n < D_STATE; ++n) {
        float dA = __builtin_amdgcn_exp2f(cdt[g] * Av2[n]);
        h[n] = dA * h[n] + du * Bsr[n];
      }
    }
  }
#pragma unroll
  for (int n = 0; n < D_STATE; ++n)
    harr[((size_t)bc * D_STATE + n) * D_INNER + d] = h[n];
  dtsum[(size_t)bc * D_INNER + d] = dts;
}

// pass2: sequential combine over NC chunks; IN-PLACE: harr[c] := h0 for chunk c
__global__ __launch_bounds__(256) void scan_pass2(
    float* __restrict__ harr,
    const float* __restrict__ dtsum,
    const float* __restrict__ A_log) {
  int gid = blockIdx.x * 256 + threadIdx.x;
  int d = gid & (D_INNER - 1);
  int bn = gid >> 11;
  int n = bn & (D_STATE - 1);
  int b = bn >> 4;
  float Av2 = -__expf(A_log[(size_t)d * D_STATE + n]) * LOG2E;
  float h = 0.f;
  for (int c = 0; c < NC; ++c) {
    size_t bc = (size_t)b * NC + c;
    size_t idx = (bc * D_STATE + n) * D_INNER + d;
    float he = harr[idx];
    harr[idx] = h;
    float P = __builtin_amdgcn_exp2f(Av2 * dtsum[bc * D_INNER + d]);
    h = P * h + he;
  }
}

// pass3: rescan with true h0, y = h·C + u*D, gate silu(z) -> bf16
__global__ __launch_bounds__(256) void scan_pass3(
    const float* __restrict__ delta,
    const ushort_t* __restrict__ xcb,
    ushort_t* __restrict__ ybf,
    const float* __restrict__ xdbl,
    const ushort_t* __restrict__ xzb,
    const float* __restrict__ A_log,
    const float* __restrict__ Dp,
    const float* __restrict__ harr) {
  __shared__ __align__(16) float BCls[CS][32];   // B at [0..16), C at [16..32)
  int gid = blockIdx.x * 256 + threadIdx.x;
  int d = gid & (D_INNER - 1);
  int bc = gid >> 11;
  int c = bc & (NC - 1);
  int b = bc >> NC_LOG;
  const size_t r0 = (size_t)b * SEQ + (size_t)c * CS;

  {
    int sl = threadIdx.x >> 3, sf = (threadIdx.x & 7) * 4;
    *reinterpret_cast<f32x4*>(&BCls[sl][sf]) =
        *reinterpret_cast<const f32x4*>(xdbl + (r0 + sl) * 96 + 64 + sf);
  }

  float Av2[D_STATE];
#pragma unroll
  for (int n = 0; n < D_STATE; ++n)
    Av2[n] = -__expf(A_log[(size_t)d * D_STATE + n]) * LOG2E;
  const float Dd = Dp[d];
  float h[D_STATE];
#pragma unroll
  for (int n = 0; n < D_STATE; ++n)
    h[n] = harr[((size_t)bc * D_STATE + n) * D_INNER + d];

  const float* drow = delta + r0 * D_INNER + d;
  const ushort_t* urow = xcb + r0 * D_INNER + d;
  const ushort_t* zrow = xzb + r0 * (2 * D_INNER) + D_INNER + d;
  ushort_t* yrow = ybf + r0 * D_INNER + d;

  float pdt[4], pu[4], pz[4];
#pragma unroll
  for (int g = 0; g < 4; ++g) {
    pdt[g] = drow[(size_t)g * D_INNER];
    pu[g]  = bf2f(urow[(size_t)g * D_INNER]);
    pz[g]  = bf2f(zrow[(size_t)g * (2 * D_INNER)]);
  }
  __syncthreads();

  for (int l0 = 0; l0 < CS; l0 += 4) {
    float cdt[4], cu[4], cz[4];
#pragma unroll
    for (int g = 0; g < 4; ++g) { cdt[g] = pdt[g]; cu[g] = pu[g]; cz[g] = pz[g]; }
    if (l0 + 4 < CS) {
#pragma unroll
      for (int g = 0; g < 4; ++g) {
        pdt[g] = drow[(size_t)(l0 + 4 + g) * D_INNER];
        pu[g]  = bf2f(urow[(size_t)(l0 + 4 + g) * D_INNER]);
        pz[g]  = bf2f(zrow[(size_t)(l0 + 4 + g) * (2 * D_INNER)]);
      }
    }
#pragma unroll
    for (int g = 0; g < 4; ++g) {
      int l = l0 + g;
      f32x4 B0 = *reinterpret_cast<const f32x4*>(&BCls[l][0]);
      f32x4 B1 = *reinterpret_cast<const f32x4*>(&BCls[l][4]);
      f32x4 B2 = *reinterpret_cast<const f32x4*>(&BCls[l][8]);
      f32x4 B3 = *reinterpret_cast<const f32x4*>(&BCls[l][12]);
      f32x4 C0 = *reinterpret_cast<const f32x4*>(&BCls[l][16]);
      f32x4 C1 = *reinterpret_cast<const f32x4*>(&BCls[l][20]);
      f32x4 C2 = *reinterpret_cast<const f32x4*>(&BCls[l][24]);
      f32x4 C3 = *reinterpret_cast<const f32x4*>(&BCls[l][28]);
      float du = cdt[g] * cu[g];
      float Bsr[D_STATE] = {B0[0],B0[1],B0[2],B0[3], B1[0],B1[1],B1[2],B1[3],
                            B2[0],B2[1],B2[2],B2[3], B3[0],B3[1],B3[2],B3[3]};
      float Csr[D_STATE] = {C0[0],C0[1],C0[2],C0[3], C1[0],C1[1],C1[2],C1[3],
                            C2[0],C2[1],C2[2],C2[3], C3[0],C3[1],C3[2],C3[3]};
      float y = 0.f;
#pragma unroll
      for (int n = 0; n < D_STATE; ++n) {
        float dA = __builtin_amdgcn_exp2f(cdt[g] * Av2[n]);
        h[n] = dA * h[n] + du * Bsr[n];
        y = fmaf(h[n], Csr[n], y);
      }
      y = fmaf(cu[g], Dd, y);
      yrow[(size_t)l * D_INNER] = f2bf(y * (cz[g] * sigmoidf_(cz[g])));
    }
  }
}

extern "C" void kernel_launch(void* const* d_in, const int* in_sizes, int n_in,
                              void* d_out, int out_size, void* d_ws, size_t ws_size,
                              hipStream_t stream) {
  const float* x         = (const float*)d_in[0];
  const float* in_proj_w = (const float*)d_in[1];
  const float* conv_w    = (const float*)d_in[2];
  const float* conv_b    = (const float*)d_in[3];
  const float* x_proj_w  = (const float*)d_in[4];
  const float* dt_proj_w = (const float*)d_in[5];
  const float* dt_proj_b = (const float*)d_in[6];
  const float* A_log     = (const float*)d_in[7];
  const float* Dp        = (const float*)d_in[8];
  const float* out_proj_w= (const float*)d_in[9];
  const float* rms_w     = (const float*)d_in[10];
  const float* ln_w      = (const float*)d_in[11];
  const float* ln_b      = (const float*)d_in[12];
  const float* ff_w1     = (const float*)d_in[13];
  const float* ff_b1     = (const float*)d_in[14];
  const float* ff_w2     = (const float*)d_in[15];
  const float* ff_b2     = (const float*)d_in[16];
  float* out = (float*)d_out;

  float* ws = (float*)d_ws;
  // ---- layout (float-word offsets); total end = 65,536,000 w = 250.0 MiB ----
  float* res     = ws;                              // [0, 4194304)
  float* dtsum   = ws + 4194304;                    // B*NC*D_INNER = 262,144 w
  float* xdbl    = ws + 8388608;                    // [8388608, 8781824)
  ushort_t* hbuf_bf = (ushort_t*)(ws + 8912896);    // 4M ushorts [8912896, 11010048)
  float*    pbuf    = ws + 11010048;                // x_proj partials 3.1M w
  ushort_t* y_bf    = (ushort_t*)(ws + 15204352);   // 8M ushorts [15204352, 19398656)
  ushort_t* glu_bf  = (ushort_t*)(ws + 11010048);   // overlays pbuf+y_bf (FFN phase)
  float* big   = ws + 19398656;                     // [19398656, 52953088)
  ushort_t* xz_bf = (ushort_t*)big;                 // 16.7M ushorts = 8,388,608 w (layer phase)
  ushort_t* xcb   = (ushort_t*)(big + 8388608);     // 8.4M ushorts = 4,194,304 w
  float* delta = big + 16777216;                    // 8,388,608 w
  float* harr  = big + 25165824;                    // B*NC*16*D_INNER = 4,194,304 w
  float* op_out= big;                               // 4M w (overlays xz_bf after scan)
  ushort_t* nrm_bf = (ushort_t*)delta;              // 4M ushorts (dead before dt_proj writes)
  ushort_t* in_w_bf  = (ushort_t*)(ws + 52953088);  // 8M ushorts [52953088, 57147392)
  ushort_t* out_w_bf = (ushort_t*)(ws + 57147392);  // 4M ushorts [57147392, 59244544)
  ushort_t* ff1_bf   = (ushort_t*)(ws + 59244544);  // 8M ushorts [59244544, 63438848)
  ushort_t* ff2_bf   = (ushort_t*)(ws + 63438848);  // 4M ushorts [63438848, 65536000)

  dim3 tb(16, 16);

  // all 4 weight conversions in one launch
  f2b_all<<<24576, 256, 0, stream>>>(in_proj_w, in_w_bf, out_proj_w, out_w_bf,
                                     ff_w1, ff1_bf, ff_w2, ff2_bf);

  // layer 0 input norm
  res_rms_kernel<<<ROWS, 256, 0, stream>>>(x, res, nrm_bf, rms_w);

  for (int i = 0; i < DEPTH; ++i) {
    const float* cw    = conv_w + (size_t)i * D_INNER * D_CONV;
    const float* cb    = conv_b + (size_t)i * D_INNER;
    const float* xp_w  = x_proj_w + (size_t)i * 96 * D_INNER;
    const float* dtp_w = dt_proj_w + (size_t)i * D_INNER * DT_RANK;
    const float* dtp_b = dt_proj_b + (size_t)i * D_INNER;
    const float* Alg   = A_log + (size_t)i * D_INNER * D_STATE;
    const float* Di    = Dp + (size_t)i * D_INNER;

    // in_proj: xz_bf[4096,4096] = nrm * in_w^T  (bf16 MFMA, dbuf+counted-vmcnt)
    gemm_bf16_nt<<<dim3(32, 32), 256, 0, stream>>>(
        nrm_bf, in_w_bf + (size_t)i * 4194304, nullptr, xz_bf, 2 * D_INNER, DIM,
        nullptr, 16);
    conv_silu_kernel<<<(ROWS * D_INNER / 4) / 256, 256, 0, stream>>>(xz_bf, xcb, cw, cb);
    // x_proj: split-K two-stage
    xproj_partial<<<dim3(XP_KS, 64), 256, 0, stream>>>(xcb, xp_w, pbuf);
    xproj_reduce<<<(ROWS * 96) / 256, 256, 0, stream>>>(pbuf, xdbl);
    gemm_nt<<<dim3(32, 64), tb, 0, stream>>>(xdbl, 96, dtp_w, DT_RANK, delta, D_INNER,
                                             D_INNER, DT_RANK, dtp_b, 1);
    scan_pass1<<<(BATCH * NC * D_INNER) / 256, 256, 0, stream>>>(delta, xcb, xdbl, Alg,
                                                                 harr, dtsum);
    scan_pass2<<<(BATCH * D_STATE * D_INNER) / 256, 256, 0, stream>>>(harr, dtsum, Alg);
    scan_pass3<<<(BATCH * NC * D_INNER) / 256, 256, 0, stream>>>(delta, xcb, y_bf, xdbl,
                                                                 xz_bf, Alg, Di, harr);
    // out_proj: op_out[4096,1024] = y * o_w^T  (64x128-tile bf16 MFMA); xz dead now
    gemm_bf16_nt64<<<dim3(8, 64), 256, 0, stream>>>(
        y_bf, out_w_bf + (size_t)i * 2097152, op_out, DIM, D_INNER, nullptr, 8);
    if (i + 1 < DEPTH) {
      ln_res_rms_kernel<<<ROWS, 256, 0, stream>>>(
          op_out, res, ln_w + (size_t)i * DIM, ln_b + (size_t)i * DIM,
          rms_w + (size_t)(i + 1) * DIM, nrm_bf);
    } else {
      ln_final_kernel<<<ROWS, 256, 0, stream>>>(
          op_out, hbuf_bf, ln_w + (size_t)i * DIM, ln_b + (size_t)i * DIM);
    }
  }

  // FFN1 + GEGLU fused (dbuf+counted-vmcnt)
  gemm_ffn1_glu<<<dim3(64, 32), 256, 0, stream>>>(hbuf_bf, ff1_bf, glu_bf, DIM,
                                                  ff_b1, 16);
  // FFN2: out = glu * ff_w2^T + b2  (64x128-tile bf16 MFMA)
  gemm_bf16_nt64<<<dim3(8, 64), 256, 0, stream>>>(glu_bf, ff2_bf, out, DIM, FF,
                                                  ff_b2, 8);
}

// Round 16
// 748.076 us; speedup vs baseline: 1.1596x; 1.0117x over previous
//
#include <hip/hip_runtime.h>
#include <cstdint>
#include <cstddef>

#define DIM     1024
#define SEQ     2048
#define BATCH   2
#define DEPTH   2
#define D_INNER 2048
#define D_STATE 16
#define D_CONV  4
#define DT_RANK 64
#define FF      4096
#define ROWS    (BATCH*SEQ)   // 4096
#define EPS     1e-5f

#define CS      32            // scan chunk size
#define NC      (SEQ/CS)      // 64 chunks
#define NC_LOG  6

#define XP_KS    8            // x_proj k-split
#define XP_KSTEP (D_INNER/XP_KS)  // 256

#define LOG2E 1.44269504088896f

typedef unsigned short ushort_t;
typedef short bf16x8 __attribute__((ext_vector_type(8)));
typedef float f32x4  __attribute__((ext_vector_type(4)));

__device__ __forceinline__ float sigmoidf_(float x) { return 1.f / (1.f + __expf(-x)); }

// bf16 <-> fp32
__device__ __forceinline__ ushort_t f2bf(float x) {
  unsigned int u = __float_as_uint(x);
  u += 0x7fffu + ((u >> 16) & 1u);
  return (ushort_t)(u >> 16);
}
__device__ __forceinline__ float bf2f(ushort_t u) {
  return __uint_as_float((unsigned)u << 16);
}

// async global->LDS 16B (wave-uniform LDS base + lane*16)
__device__ __forceinline__ void async_cp16(const void* g, void* lds) {
  __builtin_amdgcn_global_load_lds(
      (const __attribute__((address_space(1))) unsigned int*)g,
      (__attribute__((address_space(3))) unsigned int*)lds, 16, 0, 0);
}

// ---------------- block-wide reduction ----------------
__device__ __forceinline__ float2 block_sum2(float a, float b) {
#pragma unroll
  for (int off = 32; off > 0; off >>= 1) {
    a += __shfl_down(a, off, 64);
    b += __shfl_down(b, off, 64);
  }
  __shared__ float sa[4], sb[4];
  __syncthreads();
  if ((threadIdx.x & 63) == 0) { int w = threadIdx.x >> 6; sa[w] = a; sb[w] = b; }
  __syncthreads();
  return make_float2(sa[0] + sa[1] + sa[2] + sa[3], sb[0] + sb[1] + sb[2] + sb[3]);
}

// ---------------- residual add + RMSNorm (bf16 normed out) ----------------
__global__ __launch_bounds__(256) void res_rms_kernel(
    const float* __restrict__ xin,
    float* __restrict__ res, ushort_t* __restrict__ nrm, const float* __restrict__ w) {
  int row = blockIdx.x;
  const float* xr = xin + (size_t)row * DIM;
  float* rr = res + (size_t)row * DIM;
  ushort_t* nr = nrm + (size_t)row * DIM;
  float v[4]; float ss = 0.f;
#pragma unroll
  for (int i = 0; i < 4; ++i) {
    int j = threadIdx.x + i * 256;
    float t = xr[j];
    v[i] = t; rr[j] = t; ss += t * t;
  }
  float2 s = block_sum2(ss, 0.f);
  float rstd = rsqrtf(s.x * (1.f / DIM) + EPS);
#pragma unroll
  for (int i = 0; i < 4; ++i) {
    int j = threadIdx.x + i * 256;
    nr[j] = f2bf(v[i] * rstd * w[j]);
  }
}

// ---------------- fused LayerNorm -> residual add -> RMSNorm (bf16 out) ----------------
__global__ __launch_bounds__(256) void ln_res_rms_kernel(
    const float* __restrict__ in, float* __restrict__ res,
    const float* __restrict__ lw, const float* __restrict__ lb,
    const float* __restrict__ rw, ushort_t* __restrict__ nrm) {
  int row = blockIdx.x;
  const float* xr = in + (size_t)row * DIM;
  float* rr = res + (size_t)row * DIM;
  ushort_t* nr = nrm + (size_t)row * DIM;
  float v[4]; float s1 = 0.f, s2 = 0.f;
#pragma unroll
  for (int i = 0; i < 4; ++i) {
    int j = threadIdx.x + i * 256;
    float t = xr[j];
    v[i] = t; s1 += t; s2 += t * t;
  }
  float2 s = block_sum2(s1, s2);
  float mean = s.x * (1.f / DIM);
  float var = s.y * (1.f / DIM) - mean * mean;
  float rstd = rsqrtf(var + EPS);
  float t4[4]; float ss = 0.f;
#pragma unroll
  for (int i = 0; i < 4; ++i) {
    int j = threadIdx.x + i * 256;
    float o = (v[i] - mean) * rstd * lw[j] + lb[j];
    float t = rr[j] + o;
    rr[j] = t;
    t4[i] = t; ss += t * t;
  }
  float2 s2v = block_sum2(ss, 0.f);
  float rstd2 = rsqrtf(s2v.x * (1.f / DIM) + EPS);
#pragma unroll
  for (int i = 0; i < 4; ++i) {
    int j = threadIdx.x + i * 256;
    nr[j] = f2bf(t4[i] * rstd2 * rw[j]);
  }
}

// ---------------- final LayerNorm (bf16 out only) ----------------
__global__ __launch_bounds__(256) void ln_final_kernel(
    const float* __restrict__ in, ushort_t* __restrict__ outb,
    const float* __restrict__ w, const float* __restrict__ b) {
  int row = blockIdx.x;
  const float* xr = in + (size_t)row * DIM;
  ushort_t* obrow = outb + (size_t)row * DIM;
  float v[4]; float s1 = 0.f, s2 = 0.f;
#pragma unroll
  for (int i = 0; i < 4; ++i) {
    int j = threadIdx.x + i * 256;
    float t = xr[j];
    v[i] = t; s1 += t; s2 += t * t;
  }
  float2 s = block_sum2(s1, s2);
  float mean = s.x * (1.f / DIM);
  float var = s.y * (1.f / DIM) - mean * mean;
  float rstd = rsqrtf(var + EPS);
#pragma unroll
  for (int i = 0; i < 4; ++i) {
    int j = threadIdx.x + i * 256;
    obrow[j] = f2bf((v[i] - mean) * rstd * w[j] + b[j]);
  }
}

// ---------------- fused fp32 -> bf16 conversion for all 4 weight tensors ----------------
__global__ __launch_bounds__(256) void f2b_all(
    const float* __restrict__ w0, ushort_t* __restrict__ d0,
    const float* __restrict__ w1, ushort_t* __restrict__ d1,
    const float* __restrict__ w2, ushort_t* __restrict__ d2,
    const float* __restrict__ w3, ushort_t* __restrict__ d3) {
  int i = (blockIdx.x * 256 + threadIdx.x) * 4;
  const float* s; ushort_t* d; int off;
  if (i < 8388608)        { s = w0; d = d0; off = i; }
  else if (i < 12582912)  { s = w1; d = d1; off = i - 8388608; }
  else if (i < 20971520)  { s = w2; d = d2; off = i - 12582912; }
  else                    { s = w3; d = d3; off = i - 20971520; }
  float4 v = *reinterpret_cast<const float4*>(s + off);
  d[off + 0] = f2bf(v.x); d[off + 1] = f2bf(v.y);
  d[off + 2] = f2bf(v.z); d[off + 3] = f2bf(v.w);
}

// ---------------- bf16 MFMA NT GEMM: C = A[M,K] * B[N,K]^T (+bias) ----------------
// 128x128 tile, BK=64, 4 waves (2x2), 16x16x32 MFMA.
// DOUBLE-BUFFERED LDS + counted vmcnt (helps K=1024 in_proj; kept per R15 A/B).
__global__ __launch_bounds__(256) void gemm_bf16_nt(
    const ushort_t* __restrict__ A,
    const ushort_t* __restrict__ B,
    float* __restrict__ C,
    ushort_t* __restrict__ Cb,
    int N, int K,
    const float* __restrict__ bias, int grp) {
  __shared__ ushort_t As[2][128 * 64];
  __shared__ ushort_t Bs[2][128 * 64];
  const int tid = threadIdx.x;
  const int l = tid & 63;
  const int w = tid >> 6;

  const unsigned nwgx = gridDim.x;
  const unsigned nwg = nwgx * gridDim.y;
  const unsigned bid = blockIdx.y * nwgx + blockIdx.x;
  const unsigned cpx = nwg >> 3;
  const unsigned s = (bid & 7u) * cpx + (bid >> 3);
  const unsigned bandw = (unsigned)grp * nwgx;
  const unsigned band = s / bandw;
  const unsigned rem = s % bandw;
  const int m0 = (int)(band * grp + (rem % grp)) * 128;
  const int n0 = (int)(rem / grp) * 128;

  const int wm = (w >> 1) * 64;
  const int wn = (w & 1) * 64;

  const int srow = l >> 3;                      // 0..7 (row within 8-row chunk)
  const int ksrc = 8 * ((l & 7) ^ srow);        // swizzled source k-offset (elements)
  const int kg = l >> 4;                        // 0..3
  const int lr = l & 15;

  f32x4 acc[4][4];
#pragma unroll
  for (int mi = 0; mi < 4; ++mi)
#pragma unroll
    for (int ni = 0; ni < 4; ++ni) acc[mi][ni] = (f32x4)0.f;

  const int nt = K >> 6;

#define STAGE_NT(buf, t)                                                      \
  do {                                                                        \
    int k0_ = (t) << 6;                                                       \
    _Pragma("unroll")                                                         \
    for (int j = 0; j < 4; ++j) {                                             \
      int c = j * 4 + w;                                                      \
      int r = c * 8 + srow;                                                   \
      async_cp16(&A[(size_t)(m0 + r) * K + k0_ + ksrc], &As[buf][c * 512]);   \
    }                                                                         \
    _Pragma("unroll")                                                         \
    for (int j = 0; j < 4; ++j) {                                             \
      int c = j * 4 + w;                                                      \
      int r = c * 8 + srow;                                                   \
      async_cp16(&B[(size_t)(n0 + r) * K + k0_ + ksrc], &Bs[buf][c * 512]);   \
    }                                                                         \
  } while (0)

#define COMPUTE_NT(buf)                                                       \
  do {                                                                        \
    _Pragma("unroll")                                                         \
    for (int ks = 0; ks < 2; ++ks) {                                          \
      bf16x8 af[4], bfr[4];                                                   \
      _Pragma("unroll")                                                       \
      for (int mi = 0; mi < 4; ++mi) {                                        \
        int r = wm + mi * 16 + lr;                                            \
        int boff = r * 128 + ((ks * 64 + kg * 16) ^ ((r & 7) << 4));          \
        af[mi] = *reinterpret_cast<const bf16x8*>(                            \
            reinterpret_cast<const char*>(As[buf]) + boff);                   \
      }                                                                       \
      _Pragma("unroll")                                                       \
      for (int ni = 0; ni < 4; ++ni) {                                        \
        int r = wn + ni * 16 + lr;                                            \
        int boff = r * 128 + ((ks * 64 + kg * 16) ^ ((r & 7) << 4));          \
        bfr[ni] = *reinterpret_cast<const bf16x8*>(                           \
            reinterpret_cast<const char*>(Bs[buf]) + boff);                   \
      }                                                                       \
      _Pragma("unroll")                                                       \
      for (int mi = 0; mi < 4; ++mi)                                          \
        _Pragma("unroll")                                                     \
        for (int ni = 0; ni < 4; ++ni)                                        \
          acc[mi][ni] = __builtin_amdgcn_mfma_f32_16x16x32_bf16(              \
              af[mi], bfr[ni], acc[mi][ni], 0, 0, 0);                         \
    }                                                                         \
  } while (0)

  STAGE_NT(0, 0);
  int cur = 0;
  for (int t = 0; t < nt; ++t) {
    if (t + 1 < nt) {
      STAGE_NT(cur ^ 1, t + 1);
      asm volatile("s_waitcnt vmcnt(8)" ::: "memory");
    } else {
      asm volatile("s_waitcnt vmcnt(0)" ::: "memory");
    }
    asm volatile("s_barrier" ::: "memory");
    COMPUTE_NT(cur);
    asm volatile("s_barrier" ::: "memory");
    cur ^= 1;
  }
#undef STAGE_NT
#undef COMPUTE_NT

  const int crow0 = (l >> 4) * 4;
  const int ccol = l & 15;
#pragma unroll
  for (int mi = 0; mi < 4; ++mi) {
#pragma unroll
    for (int ni = 0; ni < 4; ++ni) {
      int col = n0 + wn + ni * 16 + ccol;
      float bv = bias ? bias[col] : 0.f;
#pragma unroll
      for (int j = 0; j < 4; ++j) {
        int row = m0 + wm + mi * 16 + crow0 + j;
        float v = acc[mi][ni][j] + bv;
        if (Cb) Cb[(size_t)row * N + col] = f2bf(v);
        else    C[(size_t)row * N + col] = v;
      }
    }
  }
}

// ---------------- bf16 MFMA NT GEMM, 64x128 tile (for N=1024 GEMMs) ----------------
__global__ __launch_bounds__(256) void gemm_bf16_nt64(
    const ushort_t* __restrict__ A,
    const ushort_t* __restrict__ B,
    float* __restrict__ C,
    int N, int K,
    const float* __restrict__ bias, int grp) {
  __shared__ ushort_t As[64 * 64];
  __shared__ ushort_t Bs[128 * 64];
  const int tid = threadIdx.x;
  const int l = tid & 63;
  const int w = tid >> 6;

  const unsigned nwgx = gridDim.x;
  const unsigned nwg = nwgx * gridDim.y;
  const unsigned bid = blockIdx.y * nwgx + blockIdx.x;
  const unsigned cpx = nwg >> 3;
  const unsigned s = (bid & 7u) * cpx + (bid >> 3);
  const unsigned bandw = (unsigned)grp * nwgx;
  const unsigned band = s / bandw;
  const unsigned rem = s % bandw;
  const int m0 = (int)(band * grp + (rem % grp)) * 64;
  const int n0 = (int)(rem / grp) * 128;

  const int wm = (w >> 1) * 32;
  const int wn = (w & 1) * 64;

  const int srow = l >> 3;
  const int ksrc = 8 * ((l & 7) ^ srow);
  const int kg = l >> 4;
  const int lr = l & 15;

  f32x4 acc[2][4];
#pragma unroll
  for (int mi = 0; mi < 2; ++mi)
#pragma unroll
    for (int ni = 0; ni < 4; ++ni) acc[mi][ni] = (f32x4)0.f;

  for (int k0 = 0; k0 < K; k0 += 64) {
#pragma unroll
    for (int j = 0; j < 2; ++j) {               // A: 8 chunks (64 rows)
      int c = j * 4 + w;
      int r = c * 8 + srow;
      async_cp16(&A[(size_t)(m0 + r) * K + k0 + ksrc], &As[c * 512]);
    }
#pragma unroll
    for (int j = 0; j < 4; ++j) {               // B: 16 chunks (128 rows)
      int c = j * 4 + w;
      int r = c * 8 + srow;
      async_cp16(&B[(size_t)(n0 + r) * K + k0 + ksrc], &Bs[c * 512]);
    }
    __syncthreads();
#pragma unroll
    for (int ks = 0; ks < 2; ++ks) {
      bf16x8 af[2], bfr[4];
#pragma unroll
      for (int mi = 0; mi < 2; ++mi) {
        int r = wm + mi * 16 + lr;
        int boff = r * 128 + ((ks * 64 + kg * 16) ^ ((r & 7) << 4));
        af[mi] = *reinterpret_cast<const bf16x8*>(reinterpret_cast<const char*>(As) + boff);
      }
#pragma unroll
      for (int ni = 0; ni < 4; ++ni) {
        int r = wn + ni * 16 + lr;
        int boff = r * 128 + ((ks * 64 + kg * 16) ^ ((r & 7) << 4));
        bfr[ni] = *reinterpret_cast<const bf16x8*>(reinterpret_cast<const char*>(Bs) + boff);
      }
#pragma unroll
      for (int mi = 0; mi < 2; ++mi)
#pragma unroll
        for (int ni = 0; ni < 4; ++ni)
          acc[mi][ni] = __builtin_amdgcn_mfma_f32_16x16x32_bf16(af[mi], bfr[ni], acc[mi][ni], 0, 0, 0);
    }
    __syncthreads();
  }

  const int crow0 = (l >> 4) * 4;
  const int ccol = l & 15;
#pragma unroll
  for (int mi = 0; mi < 2; ++mi) {
#pragma unroll
    for (int ni = 0; ni < 4; ++ni) {
      int col = n0 + wn + ni * 16 + ccol;
      float bv = bias ? bias[col] : 0.f;
#pragma unroll
      for (int j = 0; j < 4; ++j) {
        int row = m0 + wm + mi * 16 + crow0 + j;
        C[(size_t)row * N + col] = acc[mi][ni][j] + bv;
      }
    }
  }
}

// ---------------- fused FFN1 + GEGLU: glu = a * gelu(g), bf16 out ----------------
// Single-buffer LDS (R14 body): occupancy-bound, dbuf regresses it (R15 A/B).
__global__ __launch_bounds__(256) void gemm_ffn1_glu(
    const ushort_t* __restrict__ A,
    const ushort_t* __restrict__ B,
    ushort_t* __restrict__ O,
    int K,
    const float* __restrict__ bias, int grp) {
  __shared__ ushort_t As[128 * 64];
  __shared__ ushort_t Bs[128 * 64];
  const int tid = threadIdx.x;
  const int l = tid & 63;
  const int w = tid >> 6;

  const unsigned nwgx = gridDim.x;                // 64 col-panels of width 64
  const unsigned nwg = nwgx * gridDim.y;
  const unsigned bid = blockIdx.y * nwgx + blockIdx.x;
  const unsigned cpx = nwg >> 3;
  const unsigned s = (bid & 7u) * cpx + (bid >> 3);
  const unsigned bandw = (unsigned)grp * nwgx;
  const unsigned band = s / bandw;
  const unsigned rem = s % bandw;
  const int m0 = (int)(band * grp + (rem % grp)) * 128;
  const int n0 = (int)(rem / grp) * 64;

  const int wm = (w >> 1) * 64;
  const int wn2 = (w & 1) * 32;

  const int srow = l >> 3;
  const int ksrc = 8 * ((l & 7) ^ srow);
  const int kg = l >> 4;
  const int lr = l & 15;

  f32x4 acc[4][4];
#pragma unroll
  for (int mi = 0; mi < 4; ++mi)
#pragma unroll
    for (int ni = 0; ni < 4; ++ni) acc[mi][ni] = (f32x4)0.f;

  for (int k0 = 0; k0 < K; k0 += 64) {
#pragma unroll
    for (int j = 0; j < 4; ++j) {
      int c = j * 4 + w;
      int r = c * 8 + srow;
      async_cp16(&A[(size_t)(m0 + r) * K + k0 + ksrc], &As[c * 512]);
    }
#pragma unroll
    for (int j = 0; j < 4; ++j) {
      int c = j * 4 + w;
      int gr = (c < 8) ? (n0 + c * 8 + srow)
                       : (FF + n0 + (c - 8) * 8 + srow);
      async_cp16(&B[(size_t)gr * K + k0 + ksrc], &Bs[c * 512]);
    }
    __syncthreads();
#pragma unroll
    for (int ks = 0; ks < 2; ++ks) {
      bf16x8 af[4], bfr[4];
#pragma unroll
      for (int mi = 0; mi < 4; ++mi) {
        int r = wm + mi * 16 + lr;
        int boff = r * 128 + ((ks * 64 + kg * 16) ^ ((r & 7) << 4));
        af[mi] = *reinterpret_cast<const bf16x8*>(reinterpret_cast<const char*>(As) + boff);
      }
#pragma unroll
      for (int ni = 0; ni < 4; ++ni) {
        int r = (ni < 2 ? wn2 + ni * 16 : 64 + wn2 + (ni - 2) * 16) + lr;
        int boff = r * 128 + ((ks * 64 + kg * 16) ^ ((r & 7) << 4));
        bfr[ni] = *reinterpret_cast<const bf16x8*>(reinterpret_cast<const char*>(Bs) + boff);
      }
#pragma unroll
      for (int mi = 0; mi < 4; ++mi)
#pragma unroll
        for (int ni = 0; ni < 4; ++ni)
          acc[mi][ni] = __builtin_amdgcn_mfma_f32_16x16x32_bf16(af[mi], bfr[ni], acc[mi][ni], 0, 0, 0);
    }
    __syncthreads();
  }

  const int crow0 = (l >> 4) * 4;
  const int ccol = l & 15;
#pragma unroll
  for (int mi = 0; mi < 4; ++mi) {
#pragma unroll
    for (int ni = 0; ni < 2; ++ni) {
      int col = n0 + wn2 + ni * 16 + ccol;
      float ba = bias[col];
      float bg = bias[FF + col];
#pragma unroll
      for (int j = 0; j < 4; ++j) {
        int row = m0 + wm + mi * 16 + crow0 + j;
        float a = acc[mi][ni][j] + ba;
        float g = acc[mi][ni + 2][j] + bg;
        float ge = 0.5f * g * (1.f + erff(g * 0.70710678118654752f));
        O[(size_t)row * FF + col] = f2bf(a * ge);
      }
    }
  }
}

// ---------------- fp32 NT GEMM (dt_proj) ----------------
__global__ __launch_bounds__(256) void gemm_nt(
    const float* __restrict__ A, int lda,
    const float* __restrict__ B, int ldb,
    float* __restrict__ C, int ldc,
    int N, int K,
    const float* __restrict__ bias, int act) {
  __shared__ __align__(16) float Asf[16][68];
  __shared__ __align__(16) float Bsf[16][68];
  const int tx = threadIdx.x;
  const int ty = threadIdx.y;
  const int tid = ty * 16 + tx;
  const int m0 = blockIdx.y * 64;
  const int n0 = blockIdx.x * 64;
  const int lrow = tid >> 2;
  const int lk = (tid & 3) * 4;

  float acc[4][4] = {{0.f}};

  for (int k0 = 0; k0 < K; k0 += 16) {
    float4 av, bv;
    {
      const float* ap = A + (size_t)(m0 + lrow) * lda + k0 + lk;
      av = *reinterpret_cast<const float4*>(ap);
    }
    int brow = n0 + lrow;
    if (brow < N) {
      const float* bp = B + (size_t)brow * ldb + k0 + lk;
      bv = *reinterpret_cast<const float4*>(bp);
    } else {
      bv = make_float4(0.f, 0.f, 0.f, 0.f);
    }
    __syncthreads();
    Asf[lk + 0][lrow] = av.x; Asf[lk + 1][lrow] = av.y;
    Asf[lk + 2][lrow] = av.z; Asf[lk + 3][lrow] = av.w;
    Bsf[lk + 0][lrow] = bv.x; Bsf[lk + 1][lrow] = bv.y;
    Bsf[lk + 2][lrow] = bv.z; Bsf[lk + 3][lrow] = bv.w;
    __syncthreads();
#pragma unroll
    for (int k = 0; k < 16; ++k) {
      const float4 a4 = *reinterpret_cast<const float4*>(&Asf[k][ty * 4]);
      const float4 b4 = *reinterpret_cast<const float4*>(&Bsf[k][tx * 4]);
      float a[4] = {a4.x, a4.y, a4.z, a4.w};
      float bb[4] = {b4.x, b4.y, b4.z, b4.w};
#pragma unroll
      for (int i = 0; i < 4; ++i)
#pragma unroll
        for (int j = 0; j < 4; ++j)
          acc[i][j] = fmaf(a[i], bb[j], acc[i][j]);
    }
  }

#pragma unroll
  for (int i = 0; i < 4; ++i) {
    int m = m0 + ty * 4 + i;
#pragma unroll
    for (int j = 0; j < 4; ++j) {
      int n = n0 + tx * 4 + j;
      if (n < N) {
        float v = acc[i][j];
        if (bias) v += bias[n];
        if (act == 1) v = (v > 20.f) ? v : log1pf(__expf(v));
        C[(size_t)m * ldc + n] = v;
      }
    }
  }
}

// ---------------- x_proj split-K stage 1 (bf16 activations) ----------------
__global__ __launch_bounds__(256) void xproj_partial(
    const ushort_t* __restrict__ A,   // xcb [4096, 2048] bf16
    const float* __restrict__ W,      // [96, 2048]
    float* __restrict__ pbuf) {       // [XP_KS, 4096, 96]
  __shared__ __align__(16) float As[64][68];
  __shared__ __align__(16) float Wsd[96][68];
  const int ks = blockIdx.x;
  const int mb = blockIdx.y;
  const int tid = threadIdx.x;
  const int r0 = (tid >> 4) * 4;        // 0..60
  const int c0 = (tid & 15) * 6;        // 0..90

  float acc[4][6];
#pragma unroll
  for (int i = 0; i < 4; ++i)
#pragma unroll
    for (int j = 0; j < 6; ++j) acc[i][j] = 0.f;

  for (int k0 = 0; k0 < XP_KSTEP; k0 += 64) {
    const int kbase = ks * XP_KSTEP + k0;
    __syncthreads();
    {
      int r = tid >> 2, c = (tid & 3) * 16;
      const ushort_t* src = A + (size_t)(mb * 64 + r) * D_INNER + kbase + c;
#pragma unroll
      for (int q = 0; q < 4; ++q) {
        ushort4 uv = *reinterpret_cast<const ushort4*>(src + q * 4);
        As[r][c + q * 4 + 0] = bf2f(uv.x);
        As[r][c + q * 4 + 1] = bf2f(uv.y);
        As[r][c + q * 4 + 2] = bf2f(uv.z);
        As[r][c + q * 4 + 3] = bf2f(uv.w);
      }
    }
#pragma unroll
    for (int q = 0; q < 6; ++q) {
      int f = q * 256 + tid;
      int wr = f >> 4;
      int wc = (f & 15) * 4;
      *reinterpret_cast<float4*>(&Wsd[wr][wc]) =
          *reinterpret_cast<const float4*>(&W[(size_t)wr * D_INNER + kbase + wc]);
    }
    __syncthreads();
#pragma unroll 16
    for (int k = 0; k < 64; ++k) {
      float a[4], wv[6];
#pragma unroll
      for (int i = 0; i < 4; ++i) a[i] = As[r0 + i][k];
#pragma unroll
      for (int j = 0; j < 6; ++j) wv[j] = Wsd[c0 + j][k];
#pragma unroll
      for (int i = 0; i < 4; ++i)
#pragma unroll
        for (int j = 0; j < 6; ++j)
          acc[i][j] = fmaf(a[i], wv[j], acc[i][j]);
    }
  }

  float* dst = pbuf + ((size_t)ks * ROWS + mb * 64) * 96;
#pragma unroll
  for (int i = 0; i < 4; ++i)
#pragma unroll
    for (int j = 0; j < 6; ++j)
      dst[(size_t)(r0 + i) * 96 + c0 + j] = acc[i][j];
}

// ---------------- x_proj split-K stage 2: reduce ----------------
__global__ __launch_bounds__(256) void xproj_reduce(
    const float* __restrict__ pbuf, float* __restrict__ xdbl) {
  int i = blockIdx.x * 256 + threadIdx.x;   // 0 .. ROWS*96-1
  float s = 0.f;
#pragma unroll
  for (int ks = 0; ks < XP_KS; ++ks)
    s += pbuf[(size_t)ks * (ROWS * 96) + i];
  xdbl[i] = s;
}

// ---------------- causal depthwise conv (k=4) + SiLU, bf16 in / bf16 out ----------------
__global__ __launch_bounds__(256) void conv_silu_kernel(
    const ushort_t* __restrict__ xzb, ushort_t* __restrict__ xcb,
    const float* __restrict__ cw, const float* __restrict__ cb) {
  int t = (blockIdx.x * 256 + threadIdx.x) * 4;
  if (t >= ROWS * D_INNER) return;
  int d = t & (D_INNER - 1);
  int row = t >> 11;
  int l = row & (SEQ - 1);
  float acc[4];
#pragma unroll
  for (int q = 0; q < 4; ++q) acc[q] = cb[d + q];
#pragma unroll
  for (int j = 0; j < 4; ++j) {
    int ls = l - 3 + j;
    if (ls >= 0) {
      ushort4 uv = *reinterpret_cast<const ushort4*>(
          xzb + (size_t)(row - 3 + j) * (2 * D_INNER) + d);
      acc[0] = fmaf(cw[(d + 0) * 4 + j], bf2f(uv.x), acc[0]);
      acc[1] = fmaf(cw[(d + 1) * 4 + j], bf2f(uv.y), acc[1]);
      acc[2] = fmaf(cw[(d + 2) * 4 + j], bf2f(uv.z), acc[2]);
      acc[3] = fmaf(cw[(d + 3) * 4 + j], bf2f(uv.w), acc[3]);
    }
  }
  ushort4 o;
  o.x = f2bf(acc[0] * sigmoidf_(acc[0]));
  o.y = f2bf(acc[1] * sigmoidf_(acc[1]));
  o.z = f2bf(acc[2] * sigmoidf_(acc[2]));
  o.w = f2bf(acc[3] * sigmoidf_(acc[3]));
  *reinterpret_cast<ushort4*>(xcb + t) = o;
}

// ================= chunked selective scan (CS=32, LDS B/C, 4-deep prefetch) =================
__global__ __launch_bounds__(256) void scan_pass1(
    const float* __restrict__ delta,
    const ushort_t* __restrict__ xcb,
    const float* __restrict__ xdbl,
    const float* __restrict__ A_log,
    float* __restrict__ harr,
    float* __restrict__ dtsum) {
  __shared__ __align__(16) float Bls[CS][16];
  int gid = blockIdx.x * 256 + threadIdx.x;
  int d = gid & (D_INNER - 1);
  int bc = gid >> 11;
  int c = bc & (NC - 1);
  int b = bc >> NC_LOG;
  const size_t r0 = (size_t)b * SEQ + (size_t)c * CS;

  if (threadIdx.x < CS * 4) {
    int sl = threadIdx.x >> 2, sf = (threadIdx.x & 3) * 4;
    *reinterpret_cast<f32x4*>(&Bls[sl][sf]) =
        *reinterpret_cast<const f32x4*>(xdbl + (r0 + sl) * 96 + 64 + sf);
  }

  float Av2[D_STATE];
#pragma unroll
  for (int n = 0; n < D_STATE; ++n)
    Av2[n] = -__expf(A_log[(size_t)d * D_STATE + n]) * LOG2E;
  float h[D_STATE];
#pragma unroll
  for (int n = 0; n < D_STATE; ++n) h[n] = 0.f;
  float dts = 0.f;

  const float* drow = delta + r0 * D_INNER + d;
  const ushort_t* urow = xcb + r0 * D_INNER + d;

  float pdt[4], pu[4];
#pragma unroll
  for (int g = 0; g < 4; ++g) {
    pdt[g] = drow[(size_t)g * D_INNER];
    pu[g]  = bf2f(urow[(size_t)g * D_INNER]);
  }
  __syncthreads();

  for (int l0 = 0; l0 < CS; l0 += 4) {
    float cdt[4], cu[4];
#pragma unroll
    for (int g = 0; g < 4; ++g) { cdt[g] = pdt[g]; cu[g] = pu[g]; }
    if (l0 + 4 < CS) {
#pragma unroll
      for (int g = 0; g < 4; ++g) {
        pdt[g] = drow[(size_t)(l0 + 4 + g) * D_INNER];
        pu[g]  = bf2f(urow[(size_t)(l0 + 4 + g) * D_INNER]);
      }
    }
#pragma unroll
    for (int g = 0; g < 4; ++g) {
      int l = l0 + g;
      f32x4 B0 = *reinterpret_cast<const f32x4*>(&Bls[l][0]);
      f32x4 B1 = *reinterpret_cast<const f32x4*>(&Bls[l][4]);
      f32x4 B2 = *reinterpret_cast<const f32x4*>(&Bls[l][8]);
      f32x4 B3 = *reinterpret_cast<const f32x4*>(&Bls[l][12]);
      float du = cdt[g] * cu[g];
      dts += cdt[g];
      float Bsr[D_STATE] = {B0[0],B0[1],B0[2],B0[3], B1[0],B1[1],B1[2],B1[3],
                            B2[0],B2[1],B2[2],B2[3], B3[0],B3[1],B3[2],B3[3]};
#pragma unroll
      for (int n = 0; n < D_STATE; ++n) {
        float dA = __builtin_amdgcn_exp2f(cdt[g] * Av2[n]);
        h[n] = dA * h[n] + du * Bsr[n];
      }
    }
  }
#pragma unroll
  for (int n = 0; n < D_STATE; ++n)
    harr[((size_t)bc * D_STATE + n) * D_INNER + d] = h[n];
  dtsum[(size_t)bc * D_INNER + d] = dts;
}

// pass2: sequential combine over NC chunks; IN-PLACE: harr[c] := h0 for chunk c
__global__ __launch_bounds__(256) void scan_pass2(
    float* __restrict__ harr,
    const float* __restrict__ dtsum,
    const float* __restrict__ A_log) {
  int gid = blockIdx.x * 256 + threadIdx.x;
  int d = gid & (D_INNER - 1);
  int bn = gid >> 11;
  int n = bn & (D_STATE - 1);
  int b = bn >> 4;
  float Av2 = -__expf(A_log[(size_t)d * D_STATE + n]) * LOG2E;
  float h = 0.f;
  for (int c = 0; c < NC; ++c) {
    size_t bc = (size_t)b * NC + c;
    size_t idx = (bc * D_STATE + n) * D_INNER + d;
    float he = harr[idx];
    harr[idx] = h;
    float P = __builtin_amdgcn_exp2f(Av2 * dtsum[bc * D_INNER + d]);
    h = P * h + he;
  }
}

// pass3: rescan with true h0, y = h·C + u*D, gate silu(z) -> bf16
__global__ __launch_bounds__(256) void scan_pass3(
    const float* __restrict__ delta,
    const ushort_t* __restrict__ xcb,
    ushort_t* __restrict__ ybf,
    const float* __restrict__ xdbl,
    const ushort_t* __restrict__ xzb,
    const float* __restrict__ A_log,
    const float* __restrict__ Dp,
    const float* __restrict__ harr) {
  __shared__ __align__(16) float BCls[CS][32];   // B at [0..16), C at [16..32)
  int gid = blockIdx.x * 256 + threadIdx.x;
  int d = gid & (D_INNER - 1);
  int bc = gid >> 11;
  int c = bc & (NC - 1);
  int b = bc >> NC_LOG;
  const size_t r0 = (size_t)b * SEQ + (size_t)c * CS;

  {
    int sl = threadIdx.x >> 3, sf = (threadIdx.x & 7) * 4;
    *reinterpret_cast<f32x4*>(&BCls[sl][sf]) =
        *reinterpret_cast<const f32x4*>(xdbl + (r0 + sl) * 96 + 64 + sf);
  }

  float Av2[D_STATE];
#pragma unroll
  for (int n = 0; n < D_STATE; ++n)
    Av2[n] = -__expf(A_log[(size_t)d * D_STATE + n]) * LOG2E;
  const float Dd = Dp[d];
  float h[D_STATE];
#pragma unroll
  for (int n = 0; n < D_STATE; ++n)
    h[n] = harr[((size_t)bc * D_STATE + n) * D_INNER + d];

  const float* drow = delta + r0 * D_INNER + d;
  const ushort_t* urow = xcb + r0 * D_INNER + d;
  const ushort_t* zrow = xzb + r0 * (2 * D_INNER) + D_INNER + d;
  ushort_t* yrow = ybf + r0 * D_INNER + d;

  float pdt[4], pu[4], pz[4];
#pragma unroll
  for (int g = 0; g < 4; ++g) {
    pdt[g] = drow[(size_t)g * D_INNER];
    pu[g]  = bf2f(urow[(size_t)g * D_INNER]);
    pz[g]  = bf2f(zrow[(size_t)g * (2 * D_INNER)]);
  }
  __syncthreads();

  for (int l0 = 0; l0 < CS; l0 += 4) {
    float cdt[4], cu[4], cz[4];
#pragma unroll
    for (int g = 0; g < 4; ++g) { cdt[g] = pdt[g]; cu[g] = pu[g]; cz[g] = pz[g]; }
    if (l0 + 4 < CS) {
#pragma unroll
      for (int g = 0; g < 4; ++g) {
        pdt[g] = drow[(size_t)(l0 + 4 + g) * D_INNER];
        pu[g]  = bf2f(urow[(size_t)(l0 + 4 + g) * D_INNER]);
        pz[g]  = bf2f(zrow[(size_t)(l0 + 4 + g) * (2 * D_INNER)]);
      }
    }
#pragma unroll
    for (int g = 0; g < 4; ++g) {
      int l = l0 + g;
      f32x4 B0 = *reinterpret_cast<const f32x4*>(&BCls[l][0]);
      f32x4 B1 = *reinterpret_cast<const f32x4*>(&BCls[l][4]);
      f32x4 B2 = *reinterpret_cast<const f32x4*>(&BCls[l][8]);
      f32x4 B3 = *reinterpret_cast<const f32x4*>(&BCls[l][12]);
      f32x4 C0 = *reinterpret_cast<const f32x4*>(&BCls[l][16]);
      f32x4 C1 = *reinterpret_cast<const f32x4*>(&BCls[l][20]);
      f32x4 C2 = *reinterpret_cast<const f32x4*>(&BCls[l][24]);
      f32x4 C3 = *reinterpret_cast<const f32x4*>(&BCls[l][28]);
      float du = cdt[g] * cu[g];
      float Bsr[D_STATE] = {B0[0],B0[1],B0[2],B0[3], B1[0],B1[1],B1[2],B1[3],
                            B2[0],B2[1],B2[2],B2[3], B3[0],B3[1],B3[2],B3[3]};
      float Csr[D_STATE] = {C0[0],C0[1],C0[2],C0[3], C1[0],C1[1],C1[2],C1[3],
                            C2[0],C2[1],C2[2],C2[3], C3[0],C3[1],C3[2],C3[3]};
      float y = 0.f;
#pragma unroll
      for (int n = 0; n < D_STATE; ++n) {
        float dA = __builtin_amdgcn_exp2f(cdt[g] * Av2[n]);
        h[n] = dA * h[n] + du * Bsr[n];
        y = fmaf(h[n], Csr[n], y);
      }
      y = fmaf(cu[g], Dd, y);
      yrow[(size_t)l * D_INNER] = f2bf(y * (cz[g] * sigmoidf_(cz[g])));
    }
  }
}

extern "C" void kernel_launch(void* const* d_in, const int* in_sizes, int n_in,
                              void* d_out, int out_size, void* d_ws, size_t ws_size,
                              hipStream_t stream) {
  const float* x         = (const float*)d_in[0];
  const float* in_proj_w = (const float*)d_in[1];
  const float* conv_w    = (const float*)d_in[2];
  const float* conv_b    = (const float*)d_in[3];
  const float* x_proj_w  = (const float*)d_in[4];
  const float* dt_proj_w = (const float*)d_in[5];
  const float* dt_proj_b = (const float*)d_in[6];
  const float* A_log     = (const float*)d_in[7];
  const float* Dp        = (const float*)d_in[8];
  const float* out_proj_w= (const float*)d_in[9];
  const float* rms_w     = (const float*)d_in[10];
  const float* ln_w      = (const float*)d_in[11];
  const float* ln_b      = (const float*)d_in[12];
  const float* ff_w1     = (const float*)d_in[13];
  const float* ff_b1     = (const float*)d_in[14];
  const float* ff_w2     = (const float*)d_in[15];
  const float* ff_b2     = (const float*)d_in[16];
  float* out = (float*)d_out;

  float* ws = (float*)d_ws;
  // ---- layout (float-word offsets); total end = 65,536,000 w = 250.0 MiB ----
  float* res     = ws;                              // [0, 4194304)
  float* dtsum   = ws + 4194304;                    // B*NC*D_INNER = 262,144 w
  float* xdbl    = ws + 8388608;                    // [8388608, 8781824)
  ushort_t* hbuf_bf = (ushort_t*)(ws + 8912896);    // 4M ushorts [8912896, 11010048)
  float*    pbuf    = ws + 11010048;                // x_proj partials 3.1M w
  ushort_t* y_bf    = (ushort_t*)(ws + 15204352);   // 8M ushorts [15204352, 19398656)
  ushort_t* glu_bf  = (ushort_t*)(ws + 11010048);   // overlays pbuf+y_bf (FFN phase)
  float* big   = ws + 19398656;                     // [19398656, 52953088)
  ushort_t* xz_bf = (ushort_t*)big;                 // 16.7M ushorts = 8,388,608 w (layer phase)
  ushort_t* xcb   = (ushort_t*)(big + 8388608);     // 8.4M ushorts = 4,194,304 w
  float* delta = big + 16777216;                    // 8,388,608 w
  float* harr  = big + 25165824;                    // B*NC*16*D_INNER = 4,194,304 w
  float* op_out= big;                               // 4M w (overlays xz_bf after scan)
  ushort_t* nrm_bf = (ushort_t*)delta;              // 4M ushorts (dead before dt_proj writes)
  ushort_t* in_w_bf  = (ushort_t*)(ws + 52953088);  // 8M ushorts [52953088, 57147392)
  ushort_t* out_w_bf = (ushort_t*)(ws + 57147392);  // 4M ushorts [57147392, 59244544)
  ushort_t* ff1_bf   = (ushort_t*)(ws + 59244544);  // 8M ushorts [59244544, 63438848)
  ushort_t* ff2_bf   = (ushort_t*)(ws + 63438848);  // 4M ushorts [63438848, 65536000)

  dim3 tb(16, 16);

  // all 4 weight conversions in one launch
  f2b_all<<<24576, 256, 0, stream>>>(in_proj_w, in_w_bf, out_proj_w, out_w_bf,
                                     ff_w1, ff1_bf, ff_w2, ff2_bf);

  // layer 0 input norm
  res_rms_kernel<<<ROWS, 256, 0, stream>>>(x, res, nrm_bf, rms_w);

  for (int i = 0; i < DEPTH; ++i) {
    const float* cw    = conv_w + (size_t)i * D_INNER * D_CONV;
    const float* cb    = conv_b + (size_t)i * D_INNER;
    const float* xp_w  = x_proj_w + (size_t)i * 96 * D_INNER;
    const float* dtp_w = dt_proj_w + (size_t)i * D_INNER * DT_RANK;
    const float* dtp_b = dt_proj_b + (size_t)i * D_INNER;
    const float* Alg   = A_log + (size_t)i * D_INNER * D_STATE;
    const float* Di    = Dp + (size_t)i * D_INNER;

    // in_proj: xz_bf[4096,4096] = nrm * in_w^T  (bf16 MFMA, dbuf+counted-vmcnt)
    gemm_bf16_nt<<<dim3(32, 32), 256, 0, stream>>>(
        nrm_bf, in_w_bf + (size_t)i * 4194304, nullptr, xz_bf, 2 * D_INNER, DIM,
        nullptr, 16);
    conv_silu_kernel<<<(ROWS * D_INNER / 4) / 256, 256, 0, stream>>>(xz_bf, xcb, cw, cb);
    // x_proj: split-K two-stage
    xproj_partial<<<dim3(XP_KS, 64), 256, 0, stream>>>(xcb, xp_w, pbuf);
    xproj_reduce<<<(ROWS * 96) / 256, 256, 0, stream>>>(pbuf, xdbl);
    gemm_nt<<<dim3(32, 64), tb, 0, stream>>>(xdbl, 96, dtp_w, DT_RANK, delta, D_INNER,
                                             D_INNER, DT_RANK, dtp_b, 1);
    scan_pass1<<<(BATCH * NC * D_INNER) / 256, 256, 0, stream>>>(delta, xcb, xdbl, Alg,
                                                                 harr, dtsum);
    scan_pass2<<<(BATCH * D_STATE * D_INNER) / 256, 256, 0, stream>>>(harr, dtsum, Alg);
    scan_pass3<<<(BATCH * NC * D_INNER) / 256, 256, 0, stream>>>(delta, xcb, y_bf, xdbl,
                                                                 xz_bf, Alg, Di, harr);
    // out_proj: op_out[4096,1024] = y * o_w^T  (64x128-tile bf16 MFMA); xz dead now
    gemm_bf16_nt64<<<dim3(8, 64), 256, 0, stream>>>(
        y_bf, out_w_bf + (size_t)i * 2097152, op_out, DIM, D_INNER, nullptr, 8);
    if (i + 1 < DEPTH) {
      ln_res_rms_kernel<<<ROWS, 256, 0, stream>>>(
          op_out, res, ln_w + (size_t)i * DIM, ln_b + (size_t)i * DIM,
          rms_w + (size_t)(i + 1) * DIM, nrm_bf);
    } else {
      ln_final_kernel<<<ROWS, 256, 0, stream>>>(
          op_out, hbuf_bf, ln_w + (size_t)i * DIM, ln_b + (size_t)i * DIM);
    }
  }

  // FFN1 + GEGLU fused (single-buffer; dbuf regresses it per R15 A/B)
  gemm_ffn1_glu<<<dim3(64, 32), 256, 0, stream>>>(hbuf_bf, ff1_bf, glu_bf, DIM,
                                                  ff_b1, 16);
  // FFN2: out = glu * ff_w2^T + b2  (64x128-tile bf16 MFMA)
  gemm_bf16_nt64<<<dim3(8, 64), 256, 0, stream>>>(glu_bf, ff2_bf, out, DIM, FF,
                                                  ff_b2, 8);
}

// Round 17
// 740.484 us; speedup vs baseline: 1.1715x; 1.0103x over previous
//
#include <hip/hip_runtime.h>
#include <cstdint>
#include <cstddef>

#define DIM     1024
#define SEQ     2048
#define BATCH   2
#define DEPTH   2
#define D_INNER 2048
#define D_STATE 16
#define D_CONV  4
#define DT_RANK 64
#define FF      4096
#define ROWS    (BATCH*SEQ)   // 4096
#define EPS     1e-5f

#define CS      32            // scan chunk size
#define NC      (SEQ/CS)      // 64 chunks
#define NC_LOG  6

#define XP_KS    8            // x_proj k-split
#define XP_KSTEP (D_INNER/XP_KS)  // 256

#define LOG2E 1.44269504088896f

typedef unsigned short ushort_t;
typedef short bf16x8 __attribute__((ext_vector_type(8)));
typedef float f32x4  __attribute__((ext_vector_type(4)));

__device__ __forceinline__ float sigmoidf_(float x) { return 1.f / (1.f + __expf(-x)); }

// bf16 <-> fp32
__device__ __forceinline__ ushort_t f2bf(float x) {
  unsigned int u = __float_as_uint(x);
  u += 0x7fffu + ((u >> 16) & 1u);
  return (ushort_t)(u >> 16);
}
__device__ __forceinline__ float bf2f(ushort_t u) {
  return __uint_as_float((unsigned)u << 16);
}

// async global->LDS 16B (wave-uniform LDS base + lane*16)
__device__ __forceinline__ void async_cp16(const void* g, void* lds) {
  __builtin_amdgcn_global_load_lds(
      (const __attribute__((address_space(1))) unsigned int*)g,
      (__attribute__((address_space(3))) unsigned int*)lds, 16, 0, 0);
}

// ---------------- block-wide reduction ----------------
__device__ __forceinline__ float2 block_sum2(float a, float b) {
#pragma unroll
  for (int off = 32; off > 0; off >>= 1) {
    a += __shfl_down(a, off, 64);
    b += __shfl_down(b, off, 64);
  }
  __shared__ float sa[4], sb[4];
  __syncthreads();
  if ((threadIdx.x & 63) == 0) { int w = threadIdx.x >> 6; sa[w] = a; sb[w] = b; }
  __syncthreads();
  return make_float2(sa[0] + sa[1] + sa[2] + sa[3], sb[0] + sb[1] + sb[2] + sb[3]);
}

// ---------------- residual add + RMSNorm (bf16 normed out) ----------------
__global__ __launch_bounds__(256) void res_rms_kernel(
    const float* __restrict__ xin,
    float* __restrict__ res, ushort_t* __restrict__ nrm, const float* __restrict__ w) {
  int row = blockIdx.x;
  const float* xr = xin + (size_t)row * DIM;
  float* rr = res + (size_t)row * DIM;
  ushort_t* nr = nrm + (size_t)row * DIM;
  float v[4]; float ss = 0.f;
#pragma unroll
  for (int i = 0; i < 4; ++i) {
    int j = threadIdx.x + i * 256;
    float t = xr[j];
    v[i] = t; rr[j] = t; ss += t * t;
  }
  float2 s = block_sum2(ss, 0.f);
  float rstd = rsqrtf(s.x * (1.f / DIM) + EPS);
#pragma unroll
  for (int i = 0; i < 4; ++i) {
    int j = threadIdx.x + i * 256;
    nr[j] = f2bf(v[i] * rstd * w[j]);
  }
}

// ---------------- fused LayerNorm -> residual add -> RMSNorm (bf16 out) ----------------
__global__ __launch_bounds__(256) void ln_res_rms_kernel(
    const float* __restrict__ in, float* __restrict__ res,
    const float* __restrict__ lw, const float* __restrict__ lb,
    const float* __restrict__ rw, ushort_t* __restrict__ nrm) {
  int row = blockIdx.x;
  const float* xr = in + (size_t)row * DIM;
  float* rr = res + (size_t)row * DIM;
  ushort_t* nr = nrm + (size_t)row * DIM;
  float v[4]; float s1 = 0.f, s2 = 0.f;
#pragma unroll
  for (int i = 0; i < 4; ++i) {
    int j = threadIdx.x + i * 256;
    float t = xr[j];
    v[i] = t; s1 += t; s2 += t * t;
  }
  float2 s = block_sum2(s1, s2);
  float mean = s.x * (1.f / DIM);
  float var = s.y * (1.f / DIM) - mean * mean;
  float rstd = rsqrtf(var + EPS);
  float t4[4]; float ss = 0.f;
#pragma unroll
  for (int i = 0; i < 4; ++i) {
    int j = threadIdx.x + i * 256;
    float o = (v[i] - mean) * rstd * lw[j] + lb[j];
    float t = rr[j] + o;
    rr[j] = t;
    t4[i] = t; ss += t * t;
  }
  float2 s2v = block_sum2(ss, 0.f);
  float rstd2 = rsqrtf(s2v.x * (1.f / DIM) + EPS);
#pragma unroll
  for (int i = 0; i < 4; ++i) {
    int j = threadIdx.x + i * 256;
    nr[j] = f2bf(t4[i] * rstd2 * rw[j]);
  }
}

// ---------------- final LayerNorm (bf16 out only) ----------------
__global__ __launch_bounds__(256) void ln_final_kernel(
    const float* __restrict__ in, ushort_t* __restrict__ outb,
    const float* __restrict__ w, const float* __restrict__ b) {
  int row = blockIdx.x;
  const float* xr = in + (size_t)row * DIM;
  ushort_t* obrow = outb + (size_t)row * DIM;
  float v[4]; float s1 = 0.f, s2 = 0.f;
#pragma unroll
  for (int i = 0; i < 4; ++i) {
    int j = threadIdx.x + i * 256;
    float t = xr[j];
    v[i] = t; s1 += t; s2 += t * t;
  }
  float2 s = block_sum2(s1, s2);
  float mean = s.x * (1.f / DIM);
  float var = s.y * (1.f / DIM) - mean * mean;
  float rstd = rsqrtf(var + EPS);
#pragma unroll
  for (int i = 0; i < 4; ++i) {
    int j = threadIdx.x + i * 256;
    obrow[j] = f2bf((v[i] - mean) * rstd * w[j] + b[j]);
  }
}

// ---------------- fused fp32 -> bf16 conversion for all 4 weight tensors ----------------
__global__ __launch_bounds__(256) void f2b_all(
    const float* __restrict__ w0, ushort_t* __restrict__ d0,
    const float* __restrict__ w1, ushort_t* __restrict__ d1,
    const float* __restrict__ w2, ushort_t* __restrict__ d2,
    const float* __restrict__ w3, ushort_t* __restrict__ d3) {
  int i = (blockIdx.x * 256 + threadIdx.x) * 4;
  const float* s; ushort_t* d; int off;
  if (i < 8388608)        { s = w0; d = d0; off = i; }
  else if (i < 12582912)  { s = w1; d = d1; off = i - 8388608; }
  else if (i < 20971520)  { s = w2; d = d2; off = i - 12582912; }
  else                    { s = w3; d = d3; off = i - 20971520; }
  float4 v = *reinterpret_cast<const float4*>(s + off);
  d[off + 0] = f2bf(v.x); d[off + 1] = f2bf(v.y);
  d[off + 2] = f2bf(v.z); d[off + 3] = f2bf(v.w);
}

// ---------------- bf16 MFMA NT GEMM: C = A[M,K] * B[N,K]^T (+bias) ----------------
// 128x128 tile, BK=64, 4 waves (2x2), 16x16x32 MFMA.
// DOUBLE-BUFFERED LDS + counted vmcnt (helps K=1024 in_proj; kept per R15 A/B).
__global__ __launch_bounds__(256) void gemm_bf16_nt(
    const ushort_t* __restrict__ A,
    const ushort_t* __restrict__ B,
    float* __restrict__ C,
    ushort_t* __restrict__ Cb,
    int N, int K,
    const float* __restrict__ bias, int grp) {
  __shared__ ushort_t As[2][128 * 64];
  __shared__ ushort_t Bs[2][128 * 64];
  const int tid = threadIdx.x;
  const int l = tid & 63;
  const int w = tid >> 6;

  const unsigned nwgx = gridDim.x;
  const unsigned nwg = nwgx * gridDim.y;
  const unsigned bid = blockIdx.y * nwgx + blockIdx.x;
  const unsigned cpx = nwg >> 3;
  const unsigned s = (bid & 7u) * cpx + (bid >> 3);
  const unsigned bandw = (unsigned)grp * nwgx;
  const unsigned band = s / bandw;
  const unsigned rem = s % bandw;
  const int m0 = (int)(band * grp + (rem % grp)) * 128;
  const int n0 = (int)(rem / grp) * 128;

  const int wm = (w >> 1) * 64;
  const int wn = (w & 1) * 64;

  const int srow = l >> 3;                      // 0..7 (row within 8-row chunk)
  const int ksrc = 8 * ((l & 7) ^ srow);        // swizzled source k-offset (elements)
  const int kg = l >> 4;                        // 0..3
  const int lr = l & 15;

  f32x4 acc[4][4];
#pragma unroll
  for (int mi = 0; mi < 4; ++mi)
#pragma unroll
    for (int ni = 0; ni < 4; ++ni) acc[mi][ni] = (f32x4)0.f;

  const int nt = K >> 6;

#define STAGE_NT(buf, t)                                                      \
  do {                                                                        \
    int k0_ = (t) << 6;                                                       \
    _Pragma("unroll")                                                         \
    for (int j = 0; j < 4; ++j) {                                             \
      int c = j * 4 + w;                                                      \
      int r = c * 8 + srow;                                                   \
      async_cp16(&A[(size_t)(m0 + r) * K + k0_ + ksrc], &As[buf][c * 512]);   \
    }                                                                         \
    _Pragma("unroll")                                                         \
    for (int j = 0; j < 4; ++j) {                                             \
      int c = j * 4 + w;                                                      \
      int r = c * 8 + srow;                                                   \
      async_cp16(&B[(size_t)(n0 + r) * K + k0_ + ksrc], &Bs[buf][c * 512]);   \
    }                                                                         \
  } while (0)

#define COMPUTE_NT(buf)                                                       \
  do {                                                                        \
    _Pragma("unroll")                                                         \
    for (int ks = 0; ks < 2; ++ks) {                                          \
      bf16x8 af[4], bfr[4];                                                   \
      _Pragma("unroll")                                                       \
      for (int mi = 0; mi < 4; ++mi) {                                        \
        int r = wm + mi * 16 + lr;                                            \
        int boff = r * 128 + ((ks * 64 + kg * 16) ^ ((r & 7) << 4));          \
        af[mi] = *reinterpret_cast<const bf16x8*>(                            \
            reinterpret_cast<const char*>(As[buf]) + boff);                   \
      }                                                                       \
      _Pragma("unroll")                                                       \
      for (int ni = 0; ni < 4; ++ni) {                                        \
        int r = wn + ni * 16 + lr;                                            \
        int boff = r * 128 + ((ks * 64 + kg * 16) ^ ((r & 7) << 4));          \
        bfr[ni] = *reinterpret_cast<const bf16x8*>(                           \
            reinterpret_cast<const char*>(Bs[buf]) + boff);                   \
      }                                                                       \
      _Pragma("unroll")                                                       \
      for (int mi = 0; mi < 4; ++mi)                                          \
        _Pragma("unroll")                                                     \
        for (int ni = 0; ni < 4; ++ni)                                        \
          acc[mi][ni] = __builtin_amdgcn_mfma_f32_16x16x32_bf16(              \
              af[mi], bfr[ni], acc[mi][ni], 0, 0, 0);                         \
    }                                                                         \
  } while (0)

  STAGE_NT(0, 0);
  int cur = 0;
  for (int t = 0; t < nt; ++t) {
    if (t + 1 < nt) {
      STAGE_NT(cur ^ 1, t + 1);
      asm volatile("s_waitcnt vmcnt(8)" ::: "memory");
    } else {
      asm volatile("s_waitcnt vmcnt(0)" ::: "memory");
    }
    asm volatile("s_barrier" ::: "memory");
    COMPUTE_NT(cur);
    asm volatile("s_barrier" ::: "memory");
    cur ^= 1;
  }
#undef STAGE_NT
#undef COMPUTE_NT

  const int crow0 = (l >> 4) * 4;
  const int ccol = l & 15;
#pragma unroll
  for (int mi = 0; mi < 4; ++mi) {
#pragma unroll
    for (int ni = 0; ni < 4; ++ni) {
      int col = n0 + wn + ni * 16 + ccol;
      float bv = bias ? bias[col] : 0.f;
#pragma unroll
      for (int j = 0; j < 4; ++j) {
        int row = m0 + wm + mi * 16 + crow0 + j;
        float v = acc[mi][ni][j] + bv;
        if (Cb) Cb[(size_t)row * N + col] = f2bf(v);
        else    C[(size_t)row * N + col] = v;
      }
    }
  }
}

// ---------------- bf16 MFMA NT GEMM, 64x128 tile (for N=1024 GEMMs) ----------------
__global__ __launch_bounds__(256) void gemm_bf16_nt64(
    const ushort_t* __restrict__ A,
    const ushort_t* __restrict__ B,
    float* __restrict__ C,
    int N, int K,
    const float* __restrict__ bias, int grp) {
  __shared__ ushort_t As[64 * 64];
  __shared__ ushort_t Bs[128 * 64];
  const int tid = threadIdx.x;
  const int l = tid & 63;
  const int w = tid >> 6;

  const unsigned nwgx = gridDim.x;
  const unsigned nwg = nwgx * gridDim.y;
  const unsigned bid = blockIdx.y * nwgx + blockIdx.x;
  const unsigned cpx = nwg >> 3;
  const unsigned s = (bid & 7u) * cpx + (bid >> 3);
  const unsigned bandw = (unsigned)grp * nwgx;
  const unsigned band = s / bandw;
  const unsigned rem = s % bandw;
  const int m0 = (int)(band * grp + (rem % grp)) * 64;
  const int n0 = (int)(rem / grp) * 128;

  const int wm = (w >> 1) * 32;
  const int wn = (w & 1) * 64;

  const int srow = l >> 3;
  const int ksrc = 8 * ((l & 7) ^ srow);
  const int kg = l >> 4;
  const int lr = l & 15;

  f32x4 acc[2][4];
#pragma unroll
  for (int mi = 0; mi < 2; ++mi)
#pragma unroll
    for (int ni = 0; ni < 4; ++ni) acc[mi][ni] = (f32x4)0.f;

  for (int k0 = 0; k0 < K; k0 += 64) {
#pragma unroll
    for (int j = 0; j < 2; ++j) {               // A: 8 chunks (64 rows)
      int c = j * 4 + w;
      int r = c * 8 + srow;
      async_cp16(&A[(size_t)(m0 + r) * K + k0 + ksrc], &As[c * 512]);
    }
#pragma unroll
    for (int j = 0; j < 4; ++j) {               // B: 16 chunks (128 rows)
      int c = j * 4 + w;
      int r = c * 8 + srow;
      async_cp16(&B[(size_t)(n0 + r) * K + k0 + ksrc], &Bs[c * 512]);
    }
    __syncthreads();
#pragma unroll
    for (int ks = 0; ks < 2; ++ks) {
      bf16x8 af[2], bfr[4];
#pragma unroll
      for (int mi = 0; mi < 2; ++mi) {
        int r = wm + mi * 16 + lr;
        int boff = r * 128 + ((ks * 64 + kg * 16) ^ ((r & 7) << 4));
        af[mi] = *reinterpret_cast<const bf16x8*>(reinterpret_cast<const char*>(As) + boff);
      }
#pragma unroll
      for (int ni = 0; ni < 4; ++ni) {
        int r = wn + ni * 16 + lr;
        int boff = r * 128 + ((ks * 64 + kg * 16) ^ ((r & 7) << 4));
        bfr[ni] = *reinterpret_cast<const bf16x8*>(reinterpret_cast<const char*>(Bs) + boff);
      }
#pragma unroll
      for (int mi = 0; mi < 2; ++mi)
#pragma unroll
        for (int ni = 0; ni < 4; ++ni)
          acc[mi][ni] = __builtin_amdgcn_mfma_f32_16x16x32_bf16(af[mi], bfr[ni], acc[mi][ni], 0, 0, 0);
    }
    __syncthreads();
  }

  const int crow0 = (l >> 4) * 4;
  const int ccol = l & 15;
#pragma unroll
  for (int mi = 0; mi < 2; ++mi) {
#pragma unroll
    for (int ni = 0; ni < 4; ++ni) {
      int col = n0 + wn + ni * 16 + ccol;
      float bv = bias ? bias[col] : 0.f;
#pragma unroll
      for (int j = 0; j < 4; ++j) {
        int row = m0 + wm + mi * 16 + crow0 + j;
        C[(size_t)row * N + col] = acc[mi][ni][j] + bv;
      }
    }
  }
}

// ---------------- fused FFN1 + GEGLU: glu = a * gelu(g), bf16 out ----------------
// Single-buffer LDS (R14 body): occupancy-bound, dbuf regresses it (R15 A/B).
__global__ __launch_bounds__(256) void gemm_ffn1_glu(
    const ushort_t* __restrict__ A,
    const ushort_t* __restrict__ B,
    ushort_t* __restrict__ O,
    int K,
    const float* __restrict__ bias, int grp) {
  __shared__ ushort_t As[128 * 64];
  __shared__ ushort_t Bs[128 * 64];
  const int tid = threadIdx.x;
  const int l = tid & 63;
  const int w = tid >> 6;

  const unsigned nwgx = gridDim.x;                // 64 col-panels of width 64
  const unsigned nwg = nwgx * gridDim.y;
  const unsigned bid = blockIdx.y * nwgx + blockIdx.x;
  const unsigned cpx = nwg >> 3;
  const unsigned s = (bid & 7u) * cpx + (bid >> 3);
  const unsigned bandw = (unsigned)grp * nwgx;
  const unsigned band = s / bandw;
  const unsigned rem = s % bandw;
  const int m0 = (int)(band * grp + (rem % grp)) * 128;
  const int n0 = (int)(rem / grp) * 64;

  const int wm = (w >> 1) * 64;
  const int wn2 = (w & 1) * 32;

  const int srow = l >> 3;
  const int ksrc = 8 * ((l & 7) ^ srow);
  const int kg = l >> 4;
  const int lr = l & 15;

  f32x4 acc[4][4];
#pragma unroll
  for (int mi = 0; mi < 4; ++mi)
#pragma unroll
    for (int ni = 0; ni < 4; ++ni) acc[mi][ni] = (f32x4)0.f;

  for (int k0 = 0; k0 < K; k0 += 64) {
#pragma unroll
    for (int j = 0; j < 4; ++j) {
      int c = j * 4 + w;
      int r = c * 8 + srow;
      async_cp16(&A[(size_t)(m0 + r) * K + k0 + ksrc], &As[c * 512]);
    }
#pragma unroll
    for (int j = 0; j < 4; ++j) {
      int c = j * 4 + w;
      int gr = (c < 8) ? (n0 + c * 8 + srow)
                       : (FF + n0 + (c - 8) * 8 + srow);
      async_cp16(&B[(size_t)gr * K + k0 + ksrc], &Bs[c * 512]);
    }
    __syncthreads();
#pragma unroll
    for (int ks = 0; ks < 2; ++ks) {
      bf16x8 af[4], bfr[4];
#pragma unroll
      for (int mi = 0; mi < 4; ++mi) {
        int r = wm + mi * 16 + lr;
        int boff = r * 128 + ((ks * 64 + kg * 16) ^ ((r & 7) << 4));
        af[mi] = *reinterpret_cast<const bf16x8*>(reinterpret_cast<const char*>(As) + boff);
      }
#pragma unroll
      for (int ni = 0; ni < 4; ++ni) {
        int r = (ni < 2 ? wn2 + ni * 16 : 64 + wn2 + (ni - 2) * 16) + lr;
        int boff = r * 128 + ((ks * 64 + kg * 16) ^ ((r & 7) << 4));
        bfr[ni] = *reinterpret_cast<const bf16x8*>(reinterpret_cast<const char*>(Bs) + boff);
      }
#pragma unroll
      for (int mi = 0; mi < 4; ++mi)
#pragma unroll
        for (int ni = 0; ni < 4; ++ni)
          acc[mi][ni] = __builtin_amdgcn_mfma_f32_16x16x32_bf16(af[mi], bfr[ni], acc[mi][ni], 0, 0, 0);
    }
    __syncthreads();
  }

  const int crow0 = (l >> 4) * 4;
  const int ccol = l & 15;
#pragma unroll
  for (int mi = 0; mi < 4; ++mi) {
#pragma unroll
    for (int ni = 0; ni < 2; ++ni) {
      int col = n0 + wn2 + ni * 16 + ccol;
      float ba = bias[col];
      float bg = bias[FF + col];
#pragma unroll
      for (int j = 0; j < 4; ++j) {
        int row = m0 + wm + mi * 16 + crow0 + j;
        float a = acc[mi][ni][j] + ba;
        float g = acc[mi][ni + 2][j] + bg;
        float ge = 0.5f * g * (1.f + erff(g * 0.70710678118654752f));
        O[(size_t)row * FF + col] = f2bf(a * ge);
      }
    }
  }
}

// ---------------- fp32 NT GEMM (dt_proj): bf16 out when Cb set ----------------
__global__ __launch_bounds__(256) void gemm_nt(
    const float* __restrict__ A, int lda,
    const float* __restrict__ B, int ldb,
    ushort_t* __restrict__ Cb, int ldc,
    int N, int K,
    const float* __restrict__ bias, int act) {
  __shared__ __align__(16) float Asf[16][68];
  __shared__ __align__(16) float Bsf[16][68];
  const int tx = threadIdx.x;
  const int ty = threadIdx.y;
  const int tid = ty * 16 + tx;
  const int m0 = blockIdx.y * 64;
  const int n0 = blockIdx.x * 64;
  const int lrow = tid >> 2;
  const int lk = (tid & 3) * 4;

  float acc[4][4] = {{0.f}};

  for (int k0 = 0; k0 < K; k0 += 16) {
    float4 av, bv;
    {
      const float* ap = A + (size_t)(m0 + lrow) * lda + k0 + lk;
      av = *reinterpret_cast<const float4*>(ap);
    }
    int brow = n0 + lrow;
    if (brow < N) {
      const float* bp = B + (size_t)brow * ldb + k0 + lk;
      bv = *reinterpret_cast<const float4*>(bp);
    } else {
      bv = make_float4(0.f, 0.f, 0.f, 0.f);
    }
    __syncthreads();
    Asf[lk + 0][lrow] = av.x; Asf[lk + 1][lrow] = av.y;
    Asf[lk + 2][lrow] = av.z; Asf[lk + 3][lrow] = av.w;
    Bsf[lk + 0][lrow] = bv.x; Bsf[lk + 1][lrow] = bv.y;
    Bsf[lk + 2][lrow] = bv.z; Bsf[lk + 3][lrow] = bv.w;
    __syncthreads();
#pragma unroll
    for (int k = 0; k < 16; ++k) {
      const float4 a4 = *reinterpret_cast<const float4*>(&Asf[k][ty * 4]);
      const float4 b4 = *reinterpret_cast<const float4*>(&Bsf[k][tx * 4]);
      float a[4] = {a4.x, a4.y, a4.z, a4.w};
      float bb[4] = {b4.x, b4.y, b4.z, b4.w};
#pragma unroll
      for (int i = 0; i < 4; ++i)
#pragma unroll
        for (int j = 0; j < 4; ++j)
          acc[i][j] = fmaf(a[i], bb[j], acc[i][j]);
    }
  }

#pragma unroll
  for (int i = 0; i < 4; ++i) {
    int m = m0 + ty * 4 + i;
    int n = n0 + tx * 4;
    ushort4 ov;
    float v0 = acc[i][0], v1 = acc[i][1], v2 = acc[i][2], v3 = acc[i][3];
    if (bias) { v0 += bias[n]; v1 += bias[n + 1]; v2 += bias[n + 2]; v3 += bias[n + 3]; }
    if (act == 1) {
      v0 = (v0 > 20.f) ? v0 : log1pf(__expf(v0));
      v1 = (v1 > 20.f) ? v1 : log1pf(__expf(v1));
      v2 = (v2 > 20.f) ? v2 : log1pf(__expf(v2));
      v3 = (v3 > 20.f) ? v3 : log1pf(__expf(v3));
    }
    ov.x = f2bf(v0); ov.y = f2bf(v1); ov.z = f2bf(v2); ov.w = f2bf(v3);
    *reinterpret_cast<ushort4*>(Cb + (size_t)m * ldc + n) = ov;
  }
}

// ---------------- x_proj split-K stage 1 (bf16 activations) ----------------
__global__ __launch_bounds__(256) void xproj_partial(
    const ushort_t* __restrict__ A,   // xcb [4096, 2048] bf16
    const float* __restrict__ W,      // [96, 2048]
    float* __restrict__ pbuf) {       // [XP_KS, 4096, 96]
  __shared__ __align__(16) float As[64][68];
  __shared__ __align__(16) float Wsd[96][68];
  const int ks = blockIdx.x;
  const int mb = blockIdx.y;
  const int tid = threadIdx.x;
  const int r0 = (tid >> 4) * 4;        // 0..60
  const int c0 = (tid & 15) * 6;        // 0..90

  float acc[4][6];
#pragma unroll
  for (int i = 0; i < 4; ++i)
#pragma unroll
    for (int j = 0; j < 6; ++j) acc[i][j] = 0.f;

  for (int k0 = 0; k0 < XP_KSTEP; k0 += 64) {
    const int kbase = ks * XP_KSTEP + k0;
    __syncthreads();
    {
      int r = tid >> 2, c = (tid & 3) * 16;
      const ushort_t* src = A + (size_t)(mb * 64 + r) * D_INNER + kbase + c;
#pragma unroll
      for (int q = 0; q < 4; ++q) {
        ushort4 uv = *reinterpret_cast<const ushort4*>(src + q * 4);
        As[r][c + q * 4 + 0] = bf2f(uv.x);
        As[r][c + q * 4 + 1] = bf2f(uv.y);
        As[r][c + q * 4 + 2] = bf2f(uv.z);
        As[r][c + q * 4 + 3] = bf2f(uv.w);
      }
    }
#pragma unroll
    for (int q = 0; q < 6; ++q) {
      int f = q * 256 + tid;
      int wr = f >> 4;
      int wc = (f & 15) * 4;
      *reinterpret_cast<float4*>(&Wsd[wr][wc]) =
          *reinterpret_cast<const float4*>(&W[(size_t)wr * D_INNER + kbase + wc]);
    }
    __syncthreads();
#pragma unroll 16
    for (int k = 0; k < 64; ++k) {
      float a[4], wv[6];
#pragma unroll
      for (int i = 0; i < 4; ++i) a[i] = As[r0 + i][k];
#pragma unroll
      for (int j = 0; j < 6; ++j) wv[j] = Wsd[c0 + j][k];
#pragma unroll
      for (int i = 0; i < 4; ++i)
#pragma unroll
        for (int j = 0; j < 6; ++j)
          acc[i][j] = fmaf(a[i], wv[j], acc[i][j]);
    }
  }

  float* dst = pbuf + ((size_t)ks * ROWS + mb * 64) * 96;
#pragma unroll
  for (int i = 0; i < 4; ++i)
#pragma unroll
    for (int j = 0; j < 6; ++j)
      dst[(size_t)(r0 + i) * 96 + c0 + j] = acc[i][j];
}

// ---------------- x_proj split-K stage 2: reduce ----------------
__global__ __launch_bounds__(256) void xproj_reduce(
    const float* __restrict__ pbuf, float* __restrict__ xdbl) {
  int i = blockIdx.x * 256 + threadIdx.x;   // 0 .. ROWS*96-1
  float s = 0.f;
#pragma unroll
  for (int ks = 0; ks < XP_KS; ++ks)
    s += pbuf[(size_t)ks * (ROWS * 96) + i];
  xdbl[i] = s;
}

// ---------------- causal depthwise conv (k=4) + SiLU, bf16 in / bf16 out ----------------
__global__ __launch_bounds__(256) void conv_silu_kernel(
    const ushort_t* __restrict__ xzb, ushort_t* __restrict__ xcb,
    const float* __restrict__ cw, const float* __restrict__ cb) {
  int t = (blockIdx.x * 256 + threadIdx.x) * 4;
  if (t >= ROWS * D_INNER) return;
  int d = t & (D_INNER - 1);
  int row = t >> 11;
  int l = row & (SEQ - 1);
  float acc[4];
#pragma unroll
  for (int q = 0; q < 4; ++q) acc[q] = cb[d + q];
#pragma unroll
  for (int j = 0; j < 4; ++j) {
    int ls = l - 3 + j;
    if (ls >= 0) {
      ushort4 uv = *reinterpret_cast<const ushort4*>(
          xzb + (size_t)(row - 3 + j) * (2 * D_INNER) + d);
      acc[0] = fmaf(cw[(d + 0) * 4 + j], bf2f(uv.x), acc[0]);
      acc[1] = fmaf(cw[(d + 1) * 4 + j], bf2f(uv.y), acc[1]);
      acc[2] = fmaf(cw[(d + 2) * 4 + j], bf2f(uv.z), acc[2]);
      acc[3] = fmaf(cw[(d + 3) * 4 + j], bf2f(uv.w), acc[3]);
    }
  }
  ushort4 o;
  o.x = f2bf(acc[0] * sigmoidf_(acc[0]));
  o.y = f2bf(acc[1] * sigmoidf_(acc[1]));
  o.z = f2bf(acc[2] * sigmoidf_(acc[2]));
  o.w = f2bf(acc[3] * sigmoidf_(acc[3]));
  *reinterpret_cast<ushort4*>(xcb + t) = o;
}

// ================= chunked selective scan (CS=32, LDS B/C, 4-deep prefetch) =================
__global__ __launch_bounds__(256) void scan_pass1(
    const ushort_t* __restrict__ delta,   // bf16
    const ushort_t* __restrict__ xcb,
    const float* __restrict__ xdbl,
    const float* __restrict__ A_log,
    float* __restrict__ harr,
    float* __restrict__ dtsum) {
  __shared__ __align__(16) float Bls[CS][16];
  int gid = blockIdx.x * 256 + threadIdx.x;
  int d = gid & (D_INNER - 1);
  int bc = gid >> 11;
  int c = bc & (NC - 1);
  int b = bc >> NC_LOG;
  const size_t r0 = (size_t)b * SEQ + (size_t)c * CS;

  if (threadIdx.x < CS * 4) {
    int sl = threadIdx.x >> 2, sf = (threadIdx.x & 3) * 4;
    *reinterpret_cast<f32x4*>(&Bls[sl][sf]) =
        *reinterpret_cast<const f32x4*>(xdbl + (r0 + sl) * 96 + 64 + sf);
  }

  float Av2[D_STATE];
#pragma unroll
  for (int n = 0; n < D_STATE; ++n)
    Av2[n] = -__expf(A_log[(size_t)d * D_STATE + n]) * LOG2E;
  float h[D_STATE];
#pragma unroll
  for (int n = 0; n < D_STATE; ++n) h[n] = 0.f;
  float dts = 0.f;

  const ushort_t* drow = delta + r0 * D_INNER + d;
  const ushort_t* urow = xcb + r0 * D_INNER + d;

  float pdt[4], pu[4];
#pragma unroll
  for (int g = 0; g < 4; ++g) {
    pdt[g] = bf2f(drow[(size_t)g * D_INNER]);
    pu[g]  = bf2f(urow[(size_t)g * D_INNER]);
  }
  __syncthreads();

  for (int l0 = 0; l0 < CS; l0 += 4) {
    float cdt[4], cu[4];
#pragma unroll
    for (int g = 0; g < 4; ++g) { cdt[g] = pdt[g]; cu[g] = pu[g]; }
    if (l0 + 4 < CS) {
#pragma unroll
      for (int g = 0; g < 4; ++g) {
        pdt[g] = bf2f(drow[(size_t)(l0 + 4 + g) * D_INNER]);
        pu[g]  = bf2f(urow[(size_t)(l0 + 4 + g) * D_INNER]);
      }
    }
#pragma unroll
    for (int g = 0; g < 4; ++g) {
      int l = l0 + g;
      f32x4 B0 = *reinterpret_cast<const f32x4*>(&Bls[l][0]);
      f32x4 B1 = *reinterpret_cast<const f32x4*>(&Bls[l][4]);
      f32x4 B2 = *reinterpret_cast<const f32x4*>(&Bls[l][8]);
      f32x4 B3 = *reinterpret_cast<const f32x4*>(&Bls[l][12]);
      float du = cdt[g] * cu[g];
      dts += cdt[g];
      float Bsr[D_STATE] = {B0[0],B0[1],B0[2],B0[3], B1[0],B1[1],B1[2],B1[3],
                            B2[0],B2[1],B2[2],B2[3], B3[0],B3[1],B3[2],B3[3]};
#pragma unroll
      for (int n = 0; n < D_STATE; ++n) {
        float dA = __builtin_amdgcn_exp2f(cdt[g] * Av2[n]);
        h[n] = dA * h[n] + du * Bsr[n];
      }
    }
  }
#pragma unroll
  for (int n = 0; n < D_STATE; ++n)
    harr[((size_t)bc * D_STATE + n) * D_INNER + d] = h[n];
  dtsum[(size_t)bc * D_INNER + d] = dts;
}

// pass2: sequential combine over NC chunks; IN-PLACE: harr[c] := h0 for chunk c
__global__ __launch_bounds__(256) void scan_pass2(
    float* __restrict__ harr,
    const float* __restrict__ dtsum,
    const float* __restrict__ A_log) {
  int gid = blockIdx.x * 256 + threadIdx.x;
  int d = gid & (D_INNER - 1);
  int bn = gid >> 11;
  int n = bn & (D_STATE - 1);
  int b = bn >> 4;
  float Av2 = -__expf(A_log[(size_t)d * D_STATE + n]) * LOG2E;
  float h = 0.f;
  for (int c = 0; c < NC; ++c) {
    size_t bc = (size_t)b * NC + c;
    size_t idx = (bc * D_STATE + n) * D_INNER + d;
    float he = harr[idx];
    harr[idx] = h;
    float P = __builtin_amdgcn_exp2f(Av2 * dtsum[bc * D_INNER + d]);
    h = P * h + he;
  }
}

// pass3: rescan with true h0, y = h·C + u*D, gate silu(z) -> bf16
__global__ __launch_bounds__(256) void scan_pass3(
    const ushort_t* __restrict__ delta,   // bf16
    const ushort_t* __restrict__ xcb,
    ushort_t* __restrict__ ybf,
    const float* __restrict__ xdbl,
    const ushort_t* __restrict__ xzb,
    const float* __restrict__ A_log,
    const float* __restrict__ Dp,
    const float* __restrict__ harr) {
  __shared__ __align__(16) float BCls[CS][32];   // B at [0..16), C at [16..32)
  int gid = blockIdx.x * 256 + threadIdx.x;
  int d = gid & (D_INNER - 1);
  int bc = gid >> 11;
  int c = bc & (NC - 1);
  int b = bc >> NC_LOG;
  const size_t r0 = (size_t)b * SEQ + (size_t)c * CS;

  {
    int sl = threadIdx.x >> 3, sf = (threadIdx.x & 7) * 4;
    *reinterpret_cast<f32x4*>(&BCls[sl][sf]) =
        *reinterpret_cast<const f32x4*>(xdbl + (r0 + sl) * 96 + 64 + sf);
  }

  float Av2[D_STATE];
#pragma unroll
  for (int n = 0; n < D_STATE; ++n)
    Av2[n] = -__expf(A_log[(size_t)d * D_STATE + n]) * LOG2E;
  const float Dd = Dp[d];
  float h[D_STATE];
#pragma unroll
  for (int n = 0; n < D_STATE; ++n)
    h[n] = harr[((size_t)bc * D_STATE + n) * D_INNER + d];

  const ushort_t* drow = delta + r0 * D_INNER + d;
  const ushort_t* urow = xcb + r0 * D_INNER + d;
  const ushort_t* zrow = xzb + r0 * (2 * D_INNER) + D_INNER + d;
  ushort_t* yrow = ybf + r0 * D_INNER + d;

  float pdt[4], pu[4], pz[4];
#pragma unroll
  for (int g = 0; g < 4; ++g) {
    pdt[g] = bf2f(drow[(size_t)g * D_INNER]);
    pu[g]  = bf2f(urow[(size_t)g * D_INNER]);
    pz[g]  = bf2f(zrow[(size_t)g * (2 * D_INNER)]);
  }
  __syncthreads();

  for (int l0 = 0; l0 < CS; l0 += 4) {
    float cdt[4], cu[4], cz[4];
#pragma unroll
    for (int g = 0; g < 4; ++g) { cdt[g] = pdt[g]; cu[g] = pu[g]; cz[g] = pz[g]; }
    if (l0 + 4 < CS) {
#pragma unroll
      for (int g = 0; g < 4; ++g) {
        pdt[g] = bf2f(drow[(size_t)(l0 + 4 + g) * D_INNER]);
        pu[g]  = bf2f(urow[(size_t)(l0 + 4 + g) * D_INNER]);
        pz[g]  = bf2f(zrow[(size_t)(l0 + 4 + g) * (2 * D_INNER)]);
      }
    }
#pragma unroll
    for (int g = 0; g < 4; ++g) {
      int l = l0 + g;
      f32x4 B0 = *reinterpret_cast<const f32x4*>(&BCls[l][0]);
      f32x4 B1 = *reinterpret_cast<const f32x4*>(&BCls[l][4]);
      f32x4 B2 = *reinterpret_cast<const f32x4*>(&BCls[l][8]);
      f32x4 B3 = *reinterpret_cast<const f32x4*>(&BCls[l][12]);
      f32x4 C0 = *reinterpret_cast<const f32x4*>(&BCls[l][16]);
      f32x4 C1 = *reinterpret_cast<const f32x4*>(&BCls[l][20]);
      f32x4 C2 = *reinterpret_cast<const f32x4*>(&BCls[l][24]);
      f32x4 C3 = *reinterpret_cast<const f32x4*>(&BCls[l][28]);
      float du = cdt[g] * cu[g];
      float Bsr[D_STATE] = {B0[0],B0[1],B0[2],B0[3], B1[0],B1[1],B1[2],B1[3],
                            B2[0],B2[1],B2[2],B2[3], B3[0],B3[1],B3[2],B3[3]};
      float Csr[D_STATE] = {C0[0],C0[1],C0[2],C0[3], C1[0],C1[1],C1[2],C1[3],
                            C2[0],C2[1],C2[2],C2[3], C3[0],C3[1],C3[2],C3[3]};
      float y = 0.f;
#pragma unroll
      for (int n = 0; n < D_STATE; ++n) {
        float dA = __builtin_amdgcn_exp2f(cdt[g] * Av2[n]);
        h[n] = dA * h[n] + du * Bsr[n];
        y = fmaf(h[n], Csr[n], y);
      }
      y = fmaf(cu[g], Dd, y);
      yrow[(size_t)l * D_INNER] = f2bf(y * (cz[g] * sigmoidf_(cz[g])));
    }
  }
}

extern "C" void kernel_launch(void* const* d_in, const int* in_sizes, int n_in,
                              void* d_out, int out_size, void* d_ws, size_t ws_size,
                              hipStream_t stream) {
  const float* x         = (const float*)d_in[0];
  const float* in_proj_w = (const float*)d_in[1];
  const float* conv_w    = (const float*)d_in[2];
  const float* conv_b    = (const float*)d_in[3];
  const float* x_proj_w  = (const float*)d_in[4];
  const float* dt_proj_w = (const float*)d_in[5];
  const float* dt_proj_b = (const float*)d_in[6];
  const float* A_log     = (const float*)d_in[7];
  const float* Dp        = (const float*)d_in[8];
  const float* out_proj_w= (const float*)d_in[9];
  const float* rms_w     = (const float*)d_in[10];
  const float* ln_w      = (const float*)d_in[11];
  const float* ln_b      = (const float*)d_in[12];
  const float* ff_w1     = (const float*)d_in[13];
  const float* ff_b1     = (const float*)d_in[14];
  const float* ff_w2     = (const float*)d_in[15];
  const float* ff_b2     = (const float*)d_in[16];
  float* out = (float*)d_out;

  float* ws = (float*)d_ws;
  // ---- layout (float-word offsets); total end = 65,536,000 w = 250.0 MiB ----
  float* res     = ws;                              // [0, 4194304)
  float* dtsum   = ws + 4194304;                    // B*NC*D_INNER = 262,144 w
  float* xdbl    = ws + 8388608;                    // [8388608, 8781824)
  ushort_t* hbuf_bf = (ushort_t*)(ws + 8912896);    // 4M ushorts [8912896, 11010048)
  float*    pbuf    = ws + 11010048;                // x_proj partials 3.1M w
  ushort_t* y_bf    = (ushort_t*)(ws + 15204352);   // 8M ushorts [15204352, 19398656)
  ushort_t* glu_bf  = (ushort_t*)(ws + 11010048);   // overlays pbuf+y_bf (FFN phase)
  float* big   = ws + 19398656;                     // [19398656, 52953088)
  ushort_t* xz_bf = (ushort_t*)big;                 // 16.7M ushorts = 8,388,608 w (layer phase)
  ushort_t* xcb   = (ushort_t*)(big + 8388608);     // 8.4M ushorts = 4,194,304 w
  ushort_t* delta_bf = (ushort_t*)(big + 16777216); // 8.4M ushorts = 4,194,304 w (bf16 delta)
  float* harr  = big + 25165824;                    // B*NC*16*D_INNER = 4,194,304 w
  float* op_out= big;                               // 4M w (overlays xz_bf after scan)
  ushort_t* nrm_bf = (ushort_t*)(big + 16777216 + 4194304); // overlays tail of old delta region (dead before dt_proj writes delta_bf; disjoint from delta_bf)
  ushort_t* in_w_bf  = (ushort_t*)(ws + 52953088);  // 8M ushorts [52953088, 57147392)
  ushort_t* out_w_bf = (ushort_t*)(ws + 57147392);  // 4M ushorts [57147392, 59244544)
  ushort_t* ff1_bf   = (ushort_t*)(ws + 59244544);  // 8M ushorts [59244544, 63438848)
  ushort_t* ff2_bf   = (ushort_t*)(ws + 63438848);  // 4M ushorts [63438848, 65536000)

  dim3 tb(16, 16);

  // all 4 weight conversions in one launch
  f2b_all<<<24576, 256, 0, stream>>>(in_proj_w, in_w_bf, out_proj_w, out_w_bf,
                                     ff_w1, ff1_bf, ff_w2, ff2_bf);

  // layer 0 input norm
  res_rms_kernel<<<ROWS, 256, 0, stream>>>(x, res, nrm_bf, rms_w);

  for (int i = 0; i < DEPTH; ++i) {
    const float* cw    = conv_w + (size_t)i * D_INNER * D_CONV;
    const float* cb    = conv_b + (size_t)i * D_INNER;
    const float* xp_w  = x_proj_w + (size_t)i * 96 * D_INNER;
    const float* dtp_w = dt_proj_w + (size_t)i * D_INNER * DT_RANK;
    const float* dtp_b = dt_proj_b + (size_t)i * D_INNER;
    const float* Alg   = A_log + (size_t)i * D_INNER * D_STATE;
    const float* Di    = Dp + (size_t)i * D_INNER;

    // in_proj: xz_bf[4096,4096] = nrm * in_w^T  (bf16 MFMA, dbuf+counted-vmcnt)
    gemm_bf16_nt<<<dim3(32, 32), 256, 0, stream>>>(
        nrm_bf, in_w_bf + (size_t)i * 4194304, nullptr, xz_bf, 2 * D_INNER, DIM,
        nullptr, 16);
    conv_silu_kernel<<<(ROWS * D_INNER / 4) / 256, 256, 0, stream>>>(xz_bf, xcb, cw, cb);
    // x_proj: split-K two-stage
    xproj_partial<<<dim3(XP_KS, 64), 256, 0, stream>>>(xcb, xp_w, pbuf);
    xproj_reduce<<<(ROWS * 96) / 256, 256, 0, stream>>>(pbuf, xdbl);
    // dt_proj + softplus -> bf16 delta
    gemm_nt<<<dim3(32, 64), tb, 0, stream>>>(xdbl, 96, dtp_w, DT_RANK, delta_bf,
                                             D_INNER, D_INNER, DT_RANK, dtp_b, 1);
    scan_pass1<<<(BATCH * NC * D_INNER) / 256, 256, 0, stream>>>(delta_bf, xcb, xdbl,
                                                                 Alg, harr, dtsum);
    scan_pass2<<<(BATCH * D_STATE * D_INNER) / 256, 256, 0, stream>>>(harr, dtsum, Alg);
    scan_pass3<<<(BATCH * NC * D_INNER) / 256, 256, 0, stream>>>(delta_bf, xcb, y_bf,
                                                                 xdbl, xz_bf, Alg, Di,
                                                                 harr);
    // out_proj: op_out[4096,1024] = y * o_w^T  (64x128-tile bf16 MFMA); xz dead now
    gemm_bf16_nt64<<<dim3(8, 64), 256, 0, stream>>>(
        y_bf, out_w_bf + (size_t)i * 2097152, op_out, DIM, D_INNER, nullptr, 8);
    if (i + 1 < DEPTH) {
      ln_res_rms_kernel<<<ROWS, 256, 0, stream>>>(
          op_out, res, ln_w + (size_t)i * DIM, ln_b + (size_t)i * DIM,
          rms_w + (size_t)(i + 1) * DIM, nrm_bf);
    } else {
      ln_final_kernel<<<ROWS, 256, 0, stream>>>(
          op_out, hbuf_bf, ln_w + (size_t)i * DIM, ln_b + (size_t)i * DIM);
    }
  }

  // FFN1 + GEGLU fused (single-buffer; dbuf regresses it per R15 A/B)
  gemm_ffn1_glu<<<dim3(64, 32), 256, 0, stream>>>(hbuf_bf, ff1_bf, glu_bf, DIM,
                                                  ff_b1, 16);
  // FFN2: out = glu * ff_w2^T + b2  (64x128-tile bf16 MFMA)
  gemm_bf16_nt64<<<dim3(8, 64), 256, 0, stream>>>(glu_bf, ff2_bf, out, DIM, FF,
                                                  ff_b2, 8);
}

// Round 18
// 733.028 us; speedup vs baseline: 1.1834x; 1.0102x over previous
//
#include <hip/hip_runtime.h>
#include <cstdint>
#include <cstddef>

#define DIM     1024
#define SEQ     2048
#define BATCH   2
#define DEPTH   2
#define D_INNER 2048
#define D_STATE 16
#define D_CONV  4
#define DT_RANK 64
#define FF      4096
#define ROWS    (BATCH*SEQ)   // 4096
#define EPS     1e-5f

#define CS      32            // scan chunk size
#define NC      (SEQ/CS)      // 64 chunks
#define NC_LOG  6

#define XP_KS    8            // x_proj k-split
#define XP_KSTEP (D_INNER/XP_KS)  // 256

#define LOG2E 1.44269504088896f

typedef unsigned short ushort_t;
typedef short bf16x8 __attribute__((ext_vector_type(8)));
typedef float f32x4  __attribute__((ext_vector_type(4)));

__device__ __forceinline__ float sigmoidf_(float x) { return 1.f / (1.f + __expf(-x)); }

// bf16 <-> fp32
__device__ __forceinline__ ushort_t f2bf(float x) {
  unsigned int u = __float_as_uint(x);
  u += 0x7fffu + ((u >> 16) & 1u);
  return (ushort_t)(u >> 16);
}
__device__ __forceinline__ float bf2f(ushort_t u) {
  return __uint_as_float((unsigned)u << 16);
}

// async global->LDS 16B (wave-uniform LDS base + lane*16)
__device__ __forceinline__ void async_cp16(const void* g, void* lds) {
  __builtin_amdgcn_global_load_lds(
      (const __attribute__((address_space(1))) unsigned int*)g,
      (__attribute__((address_space(3))) unsigned int*)lds, 16, 0, 0);
}

// ---------------- block-wide reduction ----------------
__device__ __forceinline__ float2 block_sum2(float a, float b) {
#pragma unroll
  for (int off = 32; off > 0; off >>= 1) {
    a += __shfl_down(a, off, 64);
    b += __shfl_down(b, off, 64);
  }
  __shared__ float sa[4], sb[4];
  __syncthreads();
  if ((threadIdx.x & 63) == 0) { int w = threadIdx.x >> 6; sa[w] = a; sb[w] = b; }
  __syncthreads();
  return make_float2(sa[0] + sa[1] + sa[2] + sa[3], sb[0] + sb[1] + sb[2] + sb[3]);
}

// ---------------- residual add + RMSNorm (bf16 normed out) ----------------
__global__ __launch_bounds__(256) void res_rms_kernel(
    const float* __restrict__ xin,
    float* __restrict__ res, ushort_t* __restrict__ nrm, const float* __restrict__ w) {
  int row = blockIdx.x;
  const float* xr = xin + (size_t)row * DIM;
  float* rr = res + (size_t)row * DIM;
  ushort_t* nr = nrm + (size_t)row * DIM;
  float v[4]; float ss = 0.f;
#pragma unroll
  for (int i = 0; i < 4; ++i) {
    int j = threadIdx.x + i * 256;
    float t = xr[j];
    v[i] = t; rr[j] = t; ss += t * t;
  }
  float2 s = block_sum2(ss, 0.f);
  float rstd = rsqrtf(s.x * (1.f / DIM) + EPS);
#pragma unroll
  for (int i = 0; i < 4; ++i) {
    int j = threadIdx.x + i * 256;
    nr[j] = f2bf(v[i] * rstd * w[j]);
  }
}

// ---------------- fused LayerNorm -> residual add -> RMSNorm (bf16 out) ----------------
__global__ __launch_bounds__(256) void ln_res_rms_kernel(
    const float* __restrict__ in, float* __restrict__ res,
    const float* __restrict__ lw, const float* __restrict__ lb,
    const float* __restrict__ rw, ushort_t* __restrict__ nrm) {
  int row = blockIdx.x;
  const float* xr = in + (size_t)row * DIM;
  float* rr = res + (size_t)row * DIM;
  ushort_t* nr = nrm + (size_t)row * DIM;
  float v[4]; float s1 = 0.f, s2 = 0.f;
#pragma unroll
  for (int i = 0; i < 4; ++i) {
    int j = threadIdx.x + i * 256;
    float t = xr[j];
    v[i] = t; s1 += t; s2 += t * t;
  }
  float2 s = block_sum2(s1, s2);
  float mean = s.x * (1.f / DIM);
  float var = s.y * (1.f / DIM) - mean * mean;
  float rstd = rsqrtf(var + EPS);
  float t4[4]; float ss = 0.f;
#pragma unroll
  for (int i = 0; i < 4; ++i) {
    int j = threadIdx.x + i * 256;
    float o = (v[i] - mean) * rstd * lw[j] + lb[j];
    float t = rr[j] + o;
    rr[j] = t;
    t4[i] = t; ss += t * t;
  }
  float2 s2v = block_sum2(ss, 0.f);
  float rstd2 = rsqrtf(s2v.x * (1.f / DIM) + EPS);
#pragma unroll
  for (int i = 0; i < 4; ++i) {
    int j = threadIdx.x + i * 256;
    nr[j] = f2bf(t4[i] * rstd2 * rw[j]);
  }
}

// ---------------- final LayerNorm (bf16 out only) ----------------
__global__ __launch_bounds__(256) void ln_final_kernel(
    const float* __restrict__ in, ushort_t* __restrict__ outb,
    const float* __restrict__ w, const float* __restrict__ b) {
  int row = blockIdx.x;
  const float* xr = in + (size_t)row * DIM;
  ushort_t* obrow = outb + (size_t)row * DIM;
  float v[4]; float s1 = 0.f, s2 = 0.f;
#pragma unroll
  for (int i = 0; i < 4; ++i) {
    int j = threadIdx.x + i * 256;
    float t = xr[j];
    v[i] = t; s1 += t; s2 += t * t;
  }
  float2 s = block_sum2(s1, s2);
  float mean = s.x * (1.f / DIM);
  float var = s.y * (1.f / DIM) - mean * mean;
  float rstd = rsqrtf(var + EPS);
#pragma unroll
  for (int i = 0; i < 4; ++i) {
    int j = threadIdx.x + i * 256;
    obrow[j] = f2bf((v[i] - mean) * rstd * w[j] + b[j]);
  }
}

// ---------------- fused fp32 -> bf16 conversion for all 4 weight tensors ----------------
__global__ __launch_bounds__(256) void f2b_all(
    const float* __restrict__ w0, ushort_t* __restrict__ d0,
    const float* __restrict__ w1, ushort_t* __restrict__ d1,
    const float* __restrict__ w2, ushort_t* __restrict__ d2,
    const float* __restrict__ w3, ushort_t* __restrict__ d3) {
  int i = (blockIdx.x * 256 + threadIdx.x) * 4;
  const float* s; ushort_t* d; int off;
  if (i < 8388608)        { s = w0; d = d0; off = i; }
  else if (i < 12582912)  { s = w1; d = d1; off = i - 8388608; }
  else if (i < 20971520)  { s = w2; d = d2; off = i - 12582912; }
  else                    { s = w3; d = d3; off = i - 20971520; }
  float4 v = *reinterpret_cast<const float4*>(s + off);
  d[off + 0] = f2bf(v.x); d[off + 1] = f2bf(v.y);
  d[off + 2] = f2bf(v.z); d[off + 3] = f2bf(v.w);
}

// ---------------- bf16 MFMA NT GEMM: C = A[M,K] * B[N,K]^T (+bias) ----------------
// 128x128 tile, BK=64, 4 waves (2x2), 16x16x32 MFMA.
// DOUBLE-BUFFERED LDS + counted vmcnt (helps K-deep in_proj; kept per R15/16 A/B).
__global__ __launch_bounds__(256) void gemm_bf16_nt(
    const ushort_t* __restrict__ A,
    const ushort_t* __restrict__ B,
    float* __restrict__ C,
    ushort_t* __restrict__ Cb,
    int N, int K,
    const float* __restrict__ bias, int grp) {
  __shared__ ushort_t As[2][128 * 64];
  __shared__ ushort_t Bs[2][128 * 64];
  const int tid = threadIdx.x;
  const int l = tid & 63;
  const int w = tid >> 6;

  const unsigned nwgx = gridDim.x;
  const unsigned nwg = nwgx * gridDim.y;
  const unsigned bid = blockIdx.y * nwgx + blockIdx.x;
  const unsigned cpx = nwg >> 3;
  const unsigned s = (bid & 7u) * cpx + (bid >> 3);
  const unsigned bandw = (unsigned)grp * nwgx;
  const unsigned band = s / bandw;
  const unsigned rem = s % bandw;
  const int m0 = (int)(band * grp + (rem % grp)) * 128;
  const int n0 = (int)(rem / grp) * 128;

  const int wm = (w >> 1) * 64;
  const int wn = (w & 1) * 64;

  const int srow = l >> 3;                      // 0..7 (row within 8-row chunk)
  const int ksrc = 8 * ((l & 7) ^ srow);        // swizzled source k-offset (elements)
  const int kg = l >> 4;                        // 0..3
  const int lr = l & 15;

  f32x4 acc[4][4];
#pragma unroll
  for (int mi = 0; mi < 4; ++mi)
#pragma unroll
    for (int ni = 0; ni < 4; ++ni) acc[mi][ni] = (f32x4)0.f;

  const int nt = K >> 6;

#define STAGE_NT(buf, t)                                                      \
  do {                                                                        \
    int k0_ = (t) << 6;                                                       \
    _Pragma("unroll")                                                         \
    for (int j = 0; j < 4; ++j) {                                             \
      int c = j * 4 + w;                                                      \
      int r = c * 8 + srow;                                                   \
      async_cp16(&A[(size_t)(m0 + r) * K + k0_ + ksrc], &As[buf][c * 512]);   \
    }                                                                         \
    _Pragma("unroll")                                                         \
    for (int j = 0; j < 4; ++j) {                                             \
      int c = j * 4 + w;                                                      \
      int r = c * 8 + srow;                                                   \
      async_cp16(&B[(size_t)(n0 + r) * K + k0_ + ksrc], &Bs[buf][c * 512]);   \
    }                                                                         \
  } while (0)

#define COMPUTE_NT(buf)                                                       \
  do {                                                                        \
    _Pragma("unroll")                                                         \
    for (int ks = 0; ks < 2; ++ks) {                                          \
      bf16x8 af[4], bfr[4];                                                   \
      _Pragma("unroll")                                                       \
      for (int mi = 0; mi < 4; ++mi) {                                        \
        int r = wm + mi * 16 + lr;                                            \
        int boff = r * 128 + ((ks * 64 + kg * 16) ^ ((r & 7) << 4));          \
        af[mi] = *reinterpret_cast<const bf16x8*>(                            \
            reinterpret_cast<const char*>(As[buf]) + boff);                   \
      }                                                                       \
      _Pragma("unroll")                                                       \
      for (int ni = 0; ni < 4; ++ni) {                                        \
        int r = wn + ni * 16 + lr;                                            \
        int boff = r * 128 + ((ks * 64 + kg * 16) ^ ((r & 7) << 4));          \
        bfr[ni] = *reinterpret_cast<const bf16x8*>(                           \
            reinterpret_cast<const char*>(Bs[buf]) + boff);                   \
      }                                                                       \
      _Pragma("unroll")                                                       \
      for (int mi = 0; mi < 4; ++mi)                                          \
        _Pragma("unroll")                                                     \
        for (int ni = 0; ni < 4; ++ni)                                        \
          acc[mi][ni] = __builtin_amdgcn_mfma_f32_16x16x32_bf16(              \
              af[mi], bfr[ni], acc[mi][ni], 0, 0, 0);                         \
    }                                                                         \
  } while (0)

  STAGE_NT(0, 0);
  int cur = 0;
  for (int t = 0; t < nt; ++t) {
    if (t + 1 < nt) {
      STAGE_NT(cur ^ 1, t + 1);
      asm volatile("s_waitcnt vmcnt(8)" ::: "memory");
    } else {
      asm volatile("s_waitcnt vmcnt(0)" ::: "memory");
    }
    asm volatile("s_barrier" ::: "memory");
    COMPUTE_NT(cur);
    asm volatile("s_barrier" ::: "memory");
    cur ^= 1;
  }
#undef STAGE_NT
#undef COMPUTE_NT

  const int crow0 = (l >> 4) * 4;
  const int ccol = l & 15;
#pragma unroll
  for (int mi = 0; mi < 4; ++mi) {
#pragma unroll
    for (int ni = 0; ni < 4; ++ni) {
      int col = n0 + wn + ni * 16 + ccol;
      float bv = bias ? bias[col] : 0.f;
#pragma unroll
      for (int j = 0; j < 4; ++j) {
        int row = m0 + wm + mi * 16 + crow0 + j;
        float v = acc[mi][ni][j] + bv;
        if (Cb) Cb[(size_t)row * N + col] = f2bf(v);
        else    C[(size_t)row * N + col] = v;
      }
    }
  }
}

// ---------------- bf16 MFMA NT GEMM, 64x128 tile (for N=1024 GEMMs) ----------------
// DOUBLE-BUFFERED + counted vmcnt(6): deep-K (32/64 tiles), grid-limited to
// 2 blocks/CU so the 48KB LDS doesn't cut residency (R15 mechanism can't apply).
__global__ __launch_bounds__(256) void gemm_bf16_nt64(
    const ushort_t* __restrict__ A,
    const ushort_t* __restrict__ B,
    float* __restrict__ C,
    int N, int K,
    const float* __restrict__ bias, int grp) {
  __shared__ ushort_t As[2][64 * 64];
  __shared__ ushort_t Bs[2][128 * 64];
  const int tid = threadIdx.x;
  const int l = tid & 63;
  const int w = tid >> 6;

  const unsigned nwgx = gridDim.x;
  const unsigned nwg = nwgx * gridDim.y;
  const unsigned bid = blockIdx.y * nwgx + blockIdx.x;
  const unsigned cpx = nwg >> 3;
  const unsigned s = (bid & 7u) * cpx + (bid >> 3);
  const unsigned bandw = (unsigned)grp * nwgx;
  const unsigned band = s / bandw;
  const unsigned rem = s % bandw;
  const int m0 = (int)(band * grp + (rem % grp)) * 64;
  const int n0 = (int)(rem / grp) * 128;

  const int wm = (w >> 1) * 32;
  const int wn = (w & 1) * 64;

  const int srow = l >> 3;
  const int ksrc = 8 * ((l & 7) ^ srow);
  const int kg = l >> 4;
  const int lr = l & 15;

  f32x4 acc[2][4];
#pragma unroll
  for (int mi = 0; mi < 2; ++mi)
#pragma unroll
    for (int ni = 0; ni < 4; ++ni) acc[mi][ni] = (f32x4)0.f;

  const int nt = K >> 6;

#define STAGE_64(buf, t)                                                      \
  do {                                                                        \
    int k0_ = (t) << 6;                                                       \
    _Pragma("unroll")                                                         \
    for (int j = 0; j < 2; ++j) {                                             \
      int c = j * 4 + w;                                                      \
      int r = c * 8 + srow;                                                   \
      async_cp16(&A[(size_t)(m0 + r) * K + k0_ + ksrc], &As[buf][c * 512]);   \
    }                                                                         \
    _Pragma("unroll")                                                         \
    for (int j = 0; j < 4; ++j) {                                             \
      int c = j * 4 + w;                                                      \
      int r = c * 8 + srow;                                                   \
      async_cp16(&B[(size_t)(n0 + r) * K + k0_ + ksrc], &Bs[buf][c * 512]);   \
    }                                                                         \
  } while (0)

#define COMPUTE_64(buf)                                                       \
  do {                                                                        \
    _Pragma("unroll")                                                         \
    for (int ks = 0; ks < 2; ++ks) {                                          \
      bf16x8 af[2], bfr[4];                                                   \
      _Pragma("unroll")                                                       \
      for (int mi = 0; mi < 2; ++mi) {                                        \
        int r = wm + mi * 16 + lr;                                            \
        int boff = r * 128 + ((ks * 64 + kg * 16) ^ ((r & 7) << 4));          \
        af[mi] = *reinterpret_cast<const bf16x8*>(                            \
            reinterpret_cast<const char*>(As[buf]) + boff);                   \
      }                                                                       \
      _Pragma("unroll")                                                       \
      for (int ni = 0; ni < 4; ++ni) {                                        \
        int r = wn + ni * 16 + lr;                                            \
        int boff = r * 128 + ((ks * 64 + kg * 16) ^ ((r & 7) << 4));          \
        bfr[ni] = *reinterpret_cast<const bf16x8*>(                           \
            reinterpret_cast<const char*>(Bs[buf]) + boff);                   \
      }                                                                       \
      _Pragma("unroll")                                                       \
      for (int mi = 0; mi < 2; ++mi)                                          \
        _Pragma("unroll")                                                     \
        for (int ni = 0; ni < 4; ++ni)                                        \
          acc[mi][ni] = __builtin_amdgcn_mfma_f32_16x16x32_bf16(              \
              af[mi], bfr[ni], acc[mi][ni], 0, 0, 0);                         \
    }                                                                         \
  } while (0)

  STAGE_64(0, 0);
  int cur = 0;
  for (int t = 0; t < nt; ++t) {
    if (t + 1 < nt) {
      STAGE_64(cur ^ 1, t + 1);
      asm volatile("s_waitcnt vmcnt(6)" ::: "memory");
    } else {
      asm volatile("s_waitcnt vmcnt(0)" ::: "memory");
    }
    asm volatile("s_barrier" ::: "memory");
    COMPUTE_64(cur);
    asm volatile("s_barrier" ::: "memory");
    cur ^= 1;
  }
#undef STAGE_64
#undef COMPUTE_64

  const int crow0 = (l >> 4) * 4;
  const int ccol = l & 15;
#pragma unroll
  for (int mi = 0; mi < 2; ++mi) {
#pragma unroll
    for (int ni = 0; ni < 4; ++ni) {
      int col = n0 + wn + ni * 16 + ccol;
      float bv = bias ? bias[col] : 0.f;
#pragma unroll
      for (int j = 0; j < 4; ++j) {
        int row = m0 + wm + mi * 16 + crow0 + j;
        C[(size_t)row * N + col] = acc[mi][ni][j] + bv;
      }
    }
  }
}

// ---------------- fused FFN1 + GEGLU: glu = a * gelu(g), bf16 out ----------------
// Single-buffer LDS (R14 body): occupancy-bound, dbuf regresses it (R15 A/B).
__global__ __launch_bounds__(256) void gemm_ffn1_glu(
    const ushort_t* __restrict__ A,
    const ushort_t* __restrict__ B,
    ushort_t* __restrict__ O,
    int K,
    const float* __restrict__ bias, int grp) {
  __shared__ ushort_t As[128 * 64];
  __shared__ ushort_t Bs[128 * 64];
  const int tid = threadIdx.x;
  const int l = tid & 63;
  const int w = tid >> 6;

  const unsigned nwgx = gridDim.x;                // 64 col-panels of width 64
  const unsigned nwg = nwgx * gridDim.y;
  const unsigned bid = blockIdx.y * nwgx + blockIdx.x;
  const unsigned cpx = nwg >> 3;
  const unsigned s = (bid & 7u) * cpx + (bid >> 3);
  const unsigned bandw = (unsigned)grp * nwgx;
  const unsigned band = s / bandw;
  const unsigned rem = s % bandw;
  const int m0 = (int)(band * grp + (rem % grp)) * 128;
  const int n0 = (int)(rem / grp) * 64;

  const int wm = (w >> 1) * 64;
  const int wn2 = (w & 1) * 32;

  const int srow = l >> 3;
  const int ksrc = 8 * ((l & 7) ^ srow);
  const int kg = l >> 4;
  const int lr = l & 15;

  f32x4 acc[4][4];
#pragma unroll
  for (int mi = 0; mi < 4; ++mi)
#pragma unroll
    for (int ni = 0; ni < 4; ++ni) acc[mi][ni] = (f32x4)0.f;

  for (int k0 = 0; k0 < K; k0 += 64) {
#pragma unroll
    for (int j = 0; j < 4; ++j) {
      int c = j * 4 + w;
      int r = c * 8 + srow;
      async_cp16(&A[(size_t)(m0 + r) * K + k0 + ksrc], &As[c * 512]);
    }
#pragma unroll
    for (int j = 0; j < 4; ++j) {
      int c = j * 4 + w;
      int gr = (c < 8) ? (n0 + c * 8 + srow)
                       : (FF + n0 + (c - 8) * 8 + srow);
      async_cp16(&B[(size_t)gr * K + k0 + ksrc], &Bs[c * 512]);
    }
    __syncthreads();
#pragma unroll
    for (int ks = 0; ks < 2; ++ks) {
      bf16x8 af[4], bfr[4];
#pragma unroll
      for (int mi = 0; mi < 4; ++mi) {
        int r = wm + mi * 16 + lr;
        int boff = r * 128 + ((ks * 64 + kg * 16) ^ ((r & 7) << 4));
        af[mi] = *reinterpret_cast<const bf16x8*>(reinterpret_cast<const char*>(As) + boff);
      }
#pragma unroll
      for (int ni = 0; ni < 4; ++ni) {
        int r = (ni < 2 ? wn2 + ni * 16 : 64 + wn2 + (ni - 2) * 16) + lr;
        int boff = r * 128 + ((ks * 64 + kg * 16) ^ ((r & 7) << 4));
        bfr[ni] = *reinterpret_cast<const bf16x8*>(reinterpret_cast<const char*>(Bs) + boff);
      }
#pragma unroll
      for (int mi = 0; mi < 4; ++mi)
#pragma unroll
        for (int ni = 0; ni < 4; ++ni)
          acc[mi][ni] = __builtin_amdgcn_mfma_f32_16x16x32_bf16(af[mi], bfr[ni], acc[mi][ni], 0, 0, 0);
    }
    __syncthreads();
  }

  const int crow0 = (l >> 4) * 4;
  const int ccol = l & 15;
#pragma unroll
  for (int mi = 0; mi < 4; ++mi) {
#pragma unroll
    for (int ni = 0; ni < 2; ++ni) {
      int col = n0 + wn2 + ni * 16 + ccol;
      float ba = bias[col];
      float bg = bias[FF + col];
#pragma unroll
      for (int j = 0; j < 4; ++j) {
        int row = m0 + wm + mi * 16 + crow0 + j;
        float a = acc[mi][ni][j] + ba;
        float g = acc[mi][ni + 2][j] + bg;
        float ge = 0.5f * g * (1.f + erff(g * 0.70710678118654752f));
        O[(size_t)row * FF + col] = f2bf(a * ge);
      }
    }
  }
}

// ---------------- fp32 NT GEMM (dt_proj): bf16 out ----------------
__global__ __launch_bounds__(256) void gemm_nt(
    const float* __restrict__ A, int lda,
    const float* __restrict__ B, int ldb,
    ushort_t* __restrict__ Cb, int ldc,
    int N, int K,
    const float* __restrict__ bias, int act) {
  __shared__ __align__(16) float Asf[16][68];
  __shared__ __align__(16) float Bsf[16][68];
  const int tx = threadIdx.x;
  const int ty = threadIdx.y;
  const int tid = ty * 16 + tx;
  const int m0 = blockIdx.y * 64;
  const int n0 = blockIdx.x * 64;
  const int lrow = tid >> 2;
  const int lk = (tid & 3) * 4;

  float acc[4][4] = {{0.f}};

  for (int k0 = 0; k0 < K; k0 += 16) {
    float4 av, bv;
    {
      const float* ap = A + (size_t)(m0 + lrow) * lda + k0 + lk;
      av = *reinterpret_cast<const float4*>(ap);
    }
    int brow = n0 + lrow;
    if (brow < N) {
      const float* bp = B + (size_t)brow * ldb + k0 + lk;
      bv = *reinterpret_cast<const float4*>(bp);
    } else {
      bv = make_float4(0.f, 0.f, 0.f, 0.f);
    }
    __syncthreads();
    Asf[lk + 0][lrow] = av.x; Asf[lk + 1][lrow] = av.y;
    Asf[lk + 2][lrow] = av.z; Asf[lk + 3][lrow] = av.w;
    Bsf[lk + 0][lrow] = bv.x; Bsf[lk + 1][lrow] = bv.y;
    Bsf[lk + 2][lrow] = bv.z; Bsf[lk + 3][lrow] = bv.w;
    __syncthreads();
#pragma unroll
    for (int k = 0; k < 16; ++k) {
      const float4 a4 = *reinterpret_cast<const float4*>(&Asf[k][ty * 4]);
      const float4 b4 = *reinterpret_cast<const float4*>(&Bsf[k][tx * 4]);
      float a[4] = {a4.x, a4.y, a4.z, a4.w};
      float bb[4] = {b4.x, b4.y, b4.z, b4.w};
#pragma unroll
      for (int i = 0; i < 4; ++i)
#pragma unroll
        for (int j = 0; j < 4; ++j)
          acc[i][j] = fmaf(a[i], bb[j], acc[i][j]);
    }
  }

#pragma unroll
  for (int i = 0; i < 4; ++i) {
    int m = m0 + ty * 4 + i;
    int n = n0 + tx * 4;
    ushort4 ov;
    float v0 = acc[i][0], v1 = acc[i][1], v2 = acc[i][2], v3 = acc[i][3];
    if (bias) { v0 += bias[n]; v1 += bias[n + 1]; v2 += bias[n + 2]; v3 += bias[n + 3]; }
    if (act == 1) {
      v0 = (v0 > 20.f) ? v0 : log1pf(__expf(v0));
      v1 = (v1 > 20.f) ? v1 : log1pf(__expf(v1));
      v2 = (v2 > 20.f) ? v2 : log1pf(__expf(v2));
      v3 = (v3 > 20.f) ? v3 : log1pf(__expf(v3));
    }
    ov.x = f2bf(v0); ov.y = f2bf(v1); ov.z = f2bf(v2); ov.w = f2bf(v3);
    *reinterpret_cast<ushort4*>(Cb + (size_t)m * ldc + n) = ov;
  }
}

// ---------------- x_proj split-K stage 1 (bf16 activations) ----------------
__global__ __launch_bounds__(256) void xproj_partial(
    const ushort_t* __restrict__ A,   // xcb [4096, 2048] bf16
    const float* __restrict__ W,      // [96, 2048]
    float* __restrict__ pbuf) {       // [XP_KS, 4096, 96]
  __shared__ __align__(16) float As[64][68];
  __shared__ __align__(16) float Wsd[96][68];
  const int ks = blockIdx.x;
  const int mb = blockIdx.y;
  const int tid = threadIdx.x;
  const int r0 = (tid >> 4) * 4;        // 0..60
  const int c0 = (tid & 15) * 6;        // 0..90

  float acc[4][6];
#pragma unroll
  for (int i = 0; i < 4; ++i)
#pragma unroll
    for (int j = 0; j < 6; ++j) acc[i][j] = 0.f;

  for (int k0 = 0; k0 < XP_KSTEP; k0 += 64) {
    const int kbase = ks * XP_KSTEP + k0;
    __syncthreads();
    {
      int r = tid >> 2, c = (tid & 3) * 16;
      const ushort_t* src = A + (size_t)(mb * 64 + r) * D_INNER + kbase + c;
#pragma unroll
      for (int q = 0; q < 4; ++q) {
        ushort4 uv = *reinterpret_cast<const ushort4*>(src + q * 4);
        As[r][c + q * 4 + 0] = bf2f(uv.x);
        As[r][c + q * 4 + 1] = bf2f(uv.y);
        As[r][c + q * 4 + 2] = bf2f(uv.z);
        As[r][c + q * 4 + 3] = bf2f(uv.w);
      }
    }
#pragma unroll
    for (int q = 0; q < 6; ++q) {
      int f = q * 256 + tid;
      int wr = f >> 4;
      int wc = (f & 15) * 4;
      *reinterpret_cast<float4*>(&Wsd[wr][wc]) =
          *reinterpret_cast<const float4*>(&W[(size_t)wr * D_INNER + kbase + wc]);
    }
    __syncthreads();
#pragma unroll 16
    for (int k = 0; k < 64; ++k) {
      float a[4], wv[6];
#pragma unroll
      for (int i = 0; i < 4; ++i) a[i] = As[r0 + i][k];
#pragma unroll
      for (int j = 0; j < 6; ++j) wv[j] = Wsd[c0 + j][k];
#pragma unroll
      for (int i = 0; i < 4; ++i)
#pragma unroll
        for (int j = 0; j < 6; ++j)
          acc[i][j] = fmaf(a[i], wv[j], acc[i][j]);
    }
  }

  float* dst = pbuf + ((size_t)ks * ROWS + mb * 64) * 96;
#pragma unroll
  for (int i = 0; i < 4; ++i)
#pragma unroll
    for (int j = 0; j < 6; ++j)
      dst[(size_t)(r0 + i) * 96 + c0 + j] = acc[i][j];
}

// ---------------- x_proj split-K stage 2: reduce ----------------
__global__ __launch_bounds__(256) void xproj_reduce(
    const float* __restrict__ pbuf, float* __restrict__ xdbl) {
  int i = blockIdx.x * 256 + threadIdx.x;   // 0 .. ROWS*96-1
  float s = 0.f;
#pragma unroll
  for (int ks = 0; ks < XP_KS; ++ks)
    s += pbuf[(size_t)ks * (ROWS * 96) + i];
  xdbl[i] = s;
}

// ---------------- causal depthwise conv (k=4) + SiLU, bf16 in / bf16 out ----------------
__global__ __launch_bounds__(256) void conv_silu_kernel(
    const ushort_t* __restrict__ xzb, ushort_t* __restrict__ xcb,
    const float* __restrict__ cw, const float* __restrict__ cb) {
  int t = (blockIdx.x * 256 + threadIdx.x) * 4;
  if (t >= ROWS * D_INNER) return;
  int d = t & (D_INNER - 1);
  int row = t >> 11;
  int l = row & (SEQ - 1);
  float acc[4];
#pragma unroll
  for (int q = 0; q < 4; ++q) acc[q] = cb[d + q];
#pragma unroll
  for (int j = 0; j < 4; ++j) {
    int ls = l - 3 + j;
    if (ls >= 0) {
      ushort4 uv = *reinterpret_cast<const ushort4*>(
          xzb + (size_t)(row - 3 + j) * (2 * D_INNER) + d);
      acc[0] = fmaf(cw[(d + 0) * 4 + j], bf2f(uv.x), acc[0]);
      acc[1] = fmaf(cw[(d + 1) * 4 + j], bf2f(uv.y), acc[1]);
      acc[2] = fmaf(cw[(d + 2) * 4 + j], bf2f(uv.z), acc[2]);
      acc[3] = fmaf(cw[(d + 3) * 4 + j], bf2f(uv.w), acc[3]);
    }
  }
  ushort4 o;
  o.x = f2bf(acc[0] * sigmoidf_(acc[0]));
  o.y = f2bf(acc[1] * sigmoidf_(acc[1]));
  o.z = f2bf(acc[2] * sigmoidf_(acc[2]));
  o.w = f2bf(acc[3] * sigmoidf_(acc[3]));
  *reinterpret_cast<ushort4*>(xcb + t) = o;
}

// ================= chunked selective scan (CS=32, LDS B/C, 4-deep prefetch) =================
__global__ __launch_bounds__(256) void scan_pass1(
    const ushort_t* __restrict__ delta,   // bf16
    const ushort_t* __restrict__ xcb,
    const float* __restrict__ xdbl,
    const float* __restrict__ A_log,
    float* __restrict__ harr,
    float* __restrict__ dtsum) {
  __shared__ __align__(16) float Bls[CS][16];
  int gid = blockIdx.x * 256 + threadIdx.x;
  int d = gid & (D_INNER - 1);
  int bc = gid >> 11;
  int c = bc & (NC - 1);
  int b = bc >> NC_LOG;
  const size_t r0 = (size_t)b * SEQ + (size_t)c * CS;

  if (threadIdx.x < CS * 4) {
    int sl = threadIdx.x >> 2, sf = (threadIdx.x & 3) * 4;
    *reinterpret_cast<f32x4*>(&Bls[sl][sf]) =
        *reinterpret_cast<const f32x4*>(xdbl + (r0 + sl) * 96 + 64 + sf);
  }

  float Av2[D_STATE];
#pragma unroll
  for (int n = 0; n < D_STATE; ++n)
    Av2[n] = -__expf(A_log[(size_t)d * D_STATE + n]) * LOG2E;
  float h[D_STATE];
#pragma unroll
  for (int n = 0; n < D_STATE; ++n) h[n] = 0.f;
  float dts = 0.f;

  const ushort_t* drow = delta + r0 * D_INNER + d;
  const ushort_t* urow = xcb + r0 * D_INNER + d;

  float pdt[4], pu[4];
#pragma unroll
  for (int g = 0; g < 4; ++g) {
    pdt[g] = bf2f(drow[(size_t)g * D_INNER]);
    pu[g]  = bf2f(urow[(size_t)g * D_INNER]);
  }
  __syncthreads();

  for (int l0 = 0; l0 < CS; l0 += 4) {
    float cdt[4], cu[4];
#pragma unroll
    for (int g = 0; g < 4; ++g) { cdt[g] = pdt[g]; cu[g] = pu[g]; }
    if (l0 + 4 < CS) {
#pragma unroll
      for (int g = 0; g < 4; ++g) {
        pdt[g] = bf2f(drow[(size_t)(l0 + 4 + g) * D_INNER]);
        pu[g]  = bf2f(urow[(size_t)(l0 + 4 + g) * D_INNER]);
      }
    }
#pragma unroll
    for (int g = 0; g < 4; ++g) {
      int l = l0 + g;
      f32x4 B0 = *reinterpret_cast<const f32x4*>(&Bls[l][0]);
      f32x4 B1 = *reinterpret_cast<const f32x4*>(&Bls[l][4]);
      f32x4 B2 = *reinterpret_cast<const f32x4*>(&Bls[l][8]);
      f32x4 B3 = *reinterpret_cast<const f32x4*>(&Bls[l][12]);
      float du = cdt[g] * cu[g];
      dts += cdt[g];
      float Bsr[D_STATE] = {B0[0],B0[1],B0[2],B0[3], B1[0],B1[1],B1[2],B1[3],
                            B2[0],B2[1],B2[2],B2[3], B3[0],B3[1],B3[2],B3[3]};
#pragma unroll
      for (int n = 0; n < D_STATE; ++n) {
        float dA = __builtin_amdgcn_exp2f(cdt[g] * Av2[n]);
        h[n] = dA * h[n] + du * Bsr[n];
      }
    }
  }
#pragma unroll
  for (int n = 0; n < D_STATE; ++n)
    harr[((size_t)bc * D_STATE + n) * D_INNER + d] = h[n];
  dtsum[(size_t)bc * D_INNER + d] = dts;
}

// pass2: sequential combine over NC chunks; IN-PLACE: harr[c] := h0 for chunk c
__global__ __launch_bounds__(256) void scan_pass2(
    float* __restrict__ harr,
    const float* __restrict__ dtsum,
    const float* __restrict__ A_log) {
  int gid = blockIdx.x * 256 + threadIdx.x;
  int d = gid & (D_INNER - 1);
  int bn = gid >> 11;
  int n = bn & (D_STATE - 1);
  int b = bn >> 4;
  float Av2 = -__expf(A_log[(size_t)d * D_STATE + n]) * LOG2E;
  float h = 0.f;
  for (int c = 0; c < NC; ++c) {
    size_t bc = (size_t)b * NC + c;
    size_t idx = (bc * D_STATE + n) * D_INNER + d;
    float he = harr[idx];
    harr[idx] = h;
    float P = __builtin_amdgcn_exp2f(Av2 * dtsum[bc * D_INNER + d]);
    h = P * h + he;
  }
}

// pass3: rescan with true h0, y = h·C + u*D, gate silu(z) -> bf16
__global__ __launch_bounds__(256) void scan_pass3(
    const ushort_t* __restrict__ delta,   // bf16
    const ushort_t* __restrict__ xcb,
    ushort_t* __restrict__ ybf,
    const float* __restrict__ xdbl,
    const ushort_t* __restrict__ xzb,
    const float* __restrict__ A_log,
    const float* __restrict__ Dp,
    const float* __restrict__ harr) {
  __shared__ __align__(16) float BCls[CS][32];   // B at [0..16), C at [16..32)
  int gid = blockIdx.x * 256 + threadIdx.x;
  int d = gid & (D_INNER - 1);
  int bc = gid >> 11;
  int c = bc & (NC - 1);
  int b = bc >> NC_LOG;
  const size_t r0 = (size_t)b * SEQ + (size_t)c * CS;

  {
    int sl = threadIdx.x >> 3, sf = (threadIdx.x & 7) * 4;
    *reinterpret_cast<f32x4*>(&BCls[sl][sf]) =
        *reinterpret_cast<const f32x4*>(xdbl + (r0 + sl) * 96 + 64 + sf);
  }

  float Av2[D_STATE];
#pragma unroll
  for (int n = 0; n < D_STATE; ++n)
    Av2[n] = -__expf(A_log[(size_t)d * D_STATE + n]) * LOG2E;
  const float Dd = Dp[d];
  float h[D_STATE];
#pragma unroll
  for (int n = 0; n < D_STATE; ++n)
    h[n] = harr[((size_t)bc * D_STATE + n) * D_INNER + d];

  const ushort_t* drow = delta + r0 * D_INNER + d;
  const ushort_t* urow = xcb + r0 * D_INNER + d;
  const ushort_t* zrow = xzb + r0 * (2 * D_INNER) + D_INNER + d;
  ushort_t* yrow = ybf + r0 * D_INNER + d;

  float pdt[4], pu[4], pz[4];
#pragma unroll
  for (int g = 0; g < 4; ++g) {
    pdt[g] = bf2f(drow[(size_t)g * D_INNER]);
    pu[g]  = bf2f(urow[(size_t)g * D_INNER]);
    pz[g]  = bf2f(zrow[(size_t)g * (2 * D_INNER)]);
  }
  __syncthreads();

  for (int l0 = 0; l0 < CS; l0 += 4) {
    float cdt[4], cu[4], cz[4];
#pragma unroll
    for (int g = 0; g < 4; ++g) { cdt[g] = pdt[g]; cu[g] = pu[g]; cz[g] = pz[g]; }
    if (l0 + 4 < CS) {
#pragma unroll
      for (int g = 0; g < 4; ++g) {
        pdt[g] = bf2f(drow[(size_t)(l0 + 4 + g) * D_INNER]);
        pu[g]  = bf2f(urow[(size_t)(l0 + 4 + g) * D_INNER]);
        pz[g]  = bf2f(zrow[(size_t)(l0 + 4 + g) * (2 * D_INNER)]);
      }
    }
#pragma unroll
    for (int g = 0; g < 4; ++g) {
      int l = l0 + g;
      f32x4 B0 = *reinterpret_cast<const f32x4*>(&BCls[l][0]);
      f32x4 B1 = *reinterpret_cast<const f32x4*>(&BCls[l][4]);
      f32x4 B2 = *reinterpret_cast<const f32x4*>(&BCls[l][8]);
      f32x4 B3 = *reinterpret_cast<const f32x4*>(&BCls[l][12]);
      f32x4 C0 = *reinterpret_cast<const f32x4*>(&BCls[l][16]);
      f32x4 C1 = *reinterpret_cast<const f32x4*>(&BCls[l][20]);
      f32x4 C2 = *reinterpret_cast<const f32x4*>(&BCls[l][24]);
      f32x4 C3 = *reinterpret_cast<const f32x4*>(&BCls[l][28]);
      float du = cdt[g] * cu[g];
      float Bsr[D_STATE] = {B0[0],B0[1],B0[2],B0[3], B1[0],B1[1],B1[2],B1[3],
                            B2[0],B2[1],B2[2],B2[3], B3[0],B3[1],B3[2],B3[3]};
      float Csr[D_STATE] = {C0[0],C0[1],C0[2],C0[3], C1[0],C1[1],C1[2],C1[3],
                            C2[0],C2[1],C2[2],C2[3], C3[0],C3[1],C3[2],C3[3]};
      float y = 0.f;
#pragma unroll
      for (int n = 0; n < D_STATE; ++n) {
        float dA = __builtin_amdgcn_exp2f(cdt[g] * Av2[n]);
        h[n] = dA * h[n] + du * Bsr[n];
        y = fmaf(h[n], Csr[n], y);
      }
      y = fmaf(cu[g], Dd, y);
      yrow[(size_t)l * D_INNER] = f2bf(y * (cz[g] * sigmoidf_(cz[g])));
    }
  }
}

extern "C" void kernel_launch(void* const* d_in, const int* in_sizes, int n_in,
                              void* d_out, int out_size, void* d_ws, size_t ws_size,
                              hipStream_t stream) {
  const float* x         = (const float*)d_in[0];
  const float* in_proj_w = (const float*)d_in[1];
  const float* conv_w    = (const float*)d_in[2];
  const float* conv_b    = (const float*)d_in[3];
  const float* x_proj_w  = (const float*)d_in[4];
  const float* dt_proj_w = (const float*)d_in[5];
  const float* dt_proj_b = (const float*)d_in[6];
  const float* A_log     = (const float*)d_in[7];
  const float* Dp        = (const float*)d_in[8];
  const float* out_proj_w= (const float*)d_in[9];
  const float* rms_w     = (const float*)d_in[10];
  const float* ln_w      = (const float*)d_in[11];
  const float* ln_b      = (const float*)d_in[12];
  const float* ff_w1     = (const float*)d_in[13];
  const float* ff_b1     = (const float*)d_in[14];
  const float* ff_w2     = (const float*)d_in[15];
  const float* ff_b2     = (const float*)d_in[16];
  float* out = (float*)d_out;

  float* ws = (float*)d_ws;
  // ---- layout (float-word offsets); total end = 65,536,000 w = 250.0 MiB ----
  float* res     = ws;                              // [0, 4194304)
  float* dtsum   = ws + 4194304;                    // B*NC*D_INNER = 262,144 w
  float* xdbl    = ws + 8388608;                    // [8388608, 8781824)
  ushort_t* hbuf_bf = (ushort_t*)(ws + 8912896);    // 4M ushorts [8912896, 11010048)
  float*    pbuf    = ws + 11010048;                // x_proj partials 3.1M w
  ushort_t* y_bf    = (ushort_t*)(ws + 15204352);   // 8M ushorts [15204352, 19398656)
  ushort_t* glu_bf  = (ushort_t*)(ws + 11010048);   // overlays pbuf+y_bf (FFN phase)
  float* big   = ws + 19398656;                     // [19398656, 52953088)
  ushort_t* xz_bf = (ushort_t*)big;                 // 16.7M ushorts = 8,388,608 w (layer phase)
  ushort_t* xcb   = (ushort_t*)(big + 8388608);     // 8.4M ushorts = 4,194,304 w
  ushort_t* delta_bf = (ushort_t*)(big + 16777216); // 8.4M ushorts = 4,194,304 w (bf16 delta)
  float* harr  = big + 25165824;                    // B*NC*16*D_INNER = 4,194,304 w
  float* op_out= big;                               // 4M w (overlays xz_bf after scan)
  ushort_t* nrm_bf = (ushort_t*)(big + 16777216 + 4194304); // dead before dt_proj writes delta_bf
  ushort_t* in_w_bf  = (ushort_t*)(ws + 52953088);  // 8M ushorts [52953088, 57147392)
  ushort_t* out_w_bf = (ushort_t*)(ws + 57147392);  // 4M ushorts [57147392, 59244544)
  ushort_t* ff1_bf   = (ushort_t*)(ws + 59244544);  // 8M ushorts [59244544, 63438848)
  ushort_t* ff2_bf   = (ushort_t*)(ws + 63438848);  // 4M ushorts [63438848, 65536000)

  dim3 tb(16, 16);

  // all 4 weight conversions in one launch
  f2b_all<<<24576, 256, 0, stream>>>(in_proj_w, in_w_bf, out_proj_w, out_w_bf,
                                     ff_w1, ff1_bf, ff_w2, ff2_bf);

  // layer 0 input norm
  res_rms_kernel<<<ROWS, 256, 0, stream>>>(x, res, nrm_bf, rms_w);

  for (int i = 0; i < DEPTH; ++i) {
    const float* cw    = conv_w + (size_t)i * D_INNER * D_CONV;
    const float* cb    = conv_b + (size_t)i * D_INNER;
    const float* xp_w  = x_proj_w + (size_t)i * 96 * D_INNER;
    const float* dtp_w = dt_proj_w + (size_t)i * D_INNER * DT_RANK;
    const float* dtp_b = dt_proj_b + (size_t)i * D_INNER;
    const float* Alg   = A_log + (size_t)i * D_INNER * D_STATE;
    const float* Di    = Dp + (size_t)i * D_INNER;

    // in_proj: xz_bf[4096,4096] = nrm * in_w^T  (bf16 MFMA, dbuf+counted-vmcnt)
    gemm_bf16_nt<<<dim3(32, 32), 256, 0, stream>>>(
        nrm_bf, in_w_bf + (size_t)i * 4194304, nullptr, xz_bf, 2 * D_INNER, DIM,
        nullptr, 16);
    conv_silu_kernel<<<(ROWS * D_INNER / 4) / 256, 256, 0, stream>>>(xz_bf, xcb, cw, cb);
    // x_proj: split-K two-stage
    xproj_partial<<<dim3(XP_KS, 64), 256, 0, stream>>>(xcb, xp_w, pbuf);
    xproj_reduce<<<(ROWS * 96) / 256, 256, 0, stream>>>(pbuf, xdbl);
    // dt_proj + softplus -> bf16 delta
    gemm_nt<<<dim3(32, 64), tb, 0, stream>>>(xdbl, 96, dtp_w, DT_RANK, delta_bf,
                                             D_INNER, D_INNER, DT_RANK, dtp_b, 1);
    scan_pass1<<<(BATCH * NC * D_INNER) / 256, 256, 0, stream>>>(delta_bf, xcb, xdbl,
                                                                 Alg, harr, dtsum);
    scan_pass2<<<(BATCH * D_STATE * D_INNER) / 256, 256, 0, stream>>>(harr, dtsum, Alg);
    scan_pass3<<<(BATCH * NC * D_INNER) / 256, 256, 0, stream>>>(delta_bf, xcb, y_bf,
                                                                 xdbl, xz_bf, Alg, Di,
                                                                 harr);
    // out_proj: op_out[4096,1024] = y * o_w^T  (64x128 dbuf+counted-vmcnt); xz dead now
    gemm_bf16_nt64<<<dim3(8, 64), 256, 0, stream>>>(
        y_bf, out_w_bf + (size_t)i * 2097152, op_out, DIM, D_INNER, nullptr, 8);
    if (i + 1 < DEPTH) {
      ln_res_rms_kernel<<<ROWS, 256, 0, stream>>>(
          op_out, res, ln_w + (size_t)i * DIM, ln_b + (size_t)i * DIM,
          rms_w + (size_t)(i + 1) * DIM, nrm_bf);
    } else {
      ln_final_kernel<<<ROWS, 256, 0, stream>>>(
          op_out, hbuf_bf, ln_w + (size_t)i * DIM, ln_b + (size_t)i * DIM);
    }
  }

  // FFN1 + GEGLU fused (single-buffer; dbuf regresses it per R15 A/B)
  gemm_ffn1_glu<<<dim3(64, 32), 256, 0, stream>>>(hbuf_bf, ff1_bf, glu_bf, DIM,
                                                  ff_b1, 16);
  // FFN2: out = glu * ff_w2^T + b2  (64x128 dbuf+counted-vmcnt)
  gemm_bf16_nt64<<<dim3(8, 64), 256, 0, stream>>>(glu_bf, ff2_bf, out, DIM, FF,
                                                  ff_b2, 8);
}